// Round 5
// baseline (329.674 us; speedup 1.0000x reference)
//
#include <hip/hip_runtime.h>
#include <stdint.h>

#define SEQ   2048
#define HID   4096
#define NH    32
#define NKV   8
#define KVDIM 1024   // NKV*HD
#define KVCAT 2048   // KVDIM*2

typedef int v4i __attribute__((ext_vector_type(4)));

#define VMCNT0 asm volatile("s_waitcnt vmcnt(0)" ::: "memory")

// async global->LDS 16B: per-lane global source, wave-uniform LDS base + lane*16
__device__ __forceinline__ void gload16(const void* g, void* l) {
    __builtin_amdgcn_global_load_lds(
        (const __attribute__((address_space(1))) void*)(uintptr_t)g,
        (__attribute__((address_space(3))) void*)(uintptr_t)l, 16, 0, 0);
}

// slots live 128 B apart to avoid same-line atomic serialization
__device__ __forceinline__ float slot_scale(const unsigned* slots, int slot) {
    return fmaxf(__uint_as_float(slots[slot << 5]) / 127.0f, 1e-8f);
}

__device__ __forceinline__ int q8v(float x, float s) {
    int v = (int)rintf(x / s);
    return v < -127 ? -127 : (v > 127 ? 127 : v);
}

__device__ __forceinline__ float fexp2(float x) {
    float r; asm("v_exp_f32 %0, %1" : "=v"(r) : "v"(x)); return r;
}

__device__ __forceinline__ float amax4(const float* __restrict__ p, long v) {
    float4 x = *(const float4*)(p + v * 4);
    return fmaxf(fmaxf(fabsf(x.x), fabsf(x.y)), fmaxf(fabsf(x.z), fabsf(x.w)));
}

// block-level reduce (4 waves) then ONE atomic per block
__device__ __forceinline__ void block_amax_atomic(float m, unsigned* slots, int slot) {
    __shared__ float sm[4];
    int lane = threadIdx.x & 63, w = threadIdx.x >> 6;
    for (int off = 32; off; off >>= 1) m = fmaxf(m, __shfl_xor(m, off, 64));
    if (lane == 0) sm[w] = m;
    __syncthreads();
    if (threadIdx.x == 0)
        atomicMax(slots + (slot << 5),
                  __float_as_uint(fmaxf(fmaxf(sm[0], sm[1]), fmaxf(sm[2], sm[3]))));
}

// ---------------- fused absmax: blocks partitioned per tensor, 8-deep MLP ----------------
#define NV0 ((long)SEQ * HID / 4)     // 2M vecs
#define NV1 ((long)HID * HID / 4)     // 4M vecs
#define NV2 ((long)KVDIM * HID / 4)   // 1M vecs
__global__ void k_absmax5(const float* __restrict__ a0, const float* __restrict__ a1,
                          const float* __restrict__ a2, const float* __restrict__ a3,
                          const float* __restrict__ a4, unsigned* slots) {
    int b = blockIdx.x;
    const float* p; long n; int slot, lb, nb;
    if (b < 342)       { p = a0; n = NV0; slot = 0; lb = b;        nb = 342; }
    else if (b < 1025) { p = a1; n = NV1; slot = 1; lb = b - 342;  nb = 683; }
    else if (b < 1196) { p = a2; n = NV2; slot = 2; lb = b - 1025; nb = 171; }
    else if (b < 1367) { p = a3; n = NV2; slot = 3; lb = b - 1196; nb = 171; }
    else               { p = a4; n = NV1; slot = 4; lb = b - 1367; nb = 681; }
    long str = (long)nb * 256;
    float mm[8] = {0.f, 0.f, 0.f, 0.f, 0.f, 0.f, 0.f, 0.f};
    long v = (long)lb * 256 + threadIdx.x;
    for (; v + 7 * str < n; v += 8 * str) {
        #pragma unroll
        for (int j = 0; j < 8; j++) mm[j] = fmaxf(mm[j], amax4(p, v + j * str));
    }
    for (; v < n; v += str) mm[0] = fmaxf(mm[0], amax4(p, v));
    float m = fmaxf(fmaxf(fmaxf(mm[0], mm[1]), fmaxf(mm[2], mm[3])),
                    fmaxf(fmaxf(mm[4], mm[5]), fmaxf(mm[6], mm[7])));
    block_amax_atomic(m, slots, slot);
}

__device__ __forceinline__ void qstore4(const float* __restrict__ src, long v,
                                        int8_t* __restrict__ dst, float s) {
    float4 x = *(const float4*)(src + v * 4);
    unsigned pa = (unsigned)(uint8_t)(int8_t)q8v(x.x, s)
                | ((unsigned)(uint8_t)(int8_t)q8v(x.y, s) << 8)
                | ((unsigned)(uint8_t)(int8_t)q8v(x.z, s) << 16)
                | ((unsigned)(uint8_t)(int8_t)q8v(x.w, s) << 24);
    *(unsigned*)(dst + v * 4) = pa;
}

// ---------------- fused quantize of hid, wq, wk, wv (partitioned, 4-deep MLP) ----------------
__global__ void k_quant4(const float* __restrict__ a0, const float* __restrict__ a1,
                         const float* __restrict__ a2, const float* __restrict__ a3,
                         int8_t* __restrict__ d0, int8_t* __restrict__ d1,
                         int8_t* __restrict__ d2, int8_t* __restrict__ d3,
                         const unsigned* __restrict__ slots) {
    int b = blockIdx.x;
    const float* p; int8_t* d; long n; int slot, lb, nb;
    if (b < 512)       { p = a0; d = d0; n = NV0; slot = 0; lb = b;        nb = 512; }
    else if (b < 1536) { p = a1; d = d1; n = NV1; slot = 1; lb = b - 512;  nb = 1024; }
    else if (b < 1792) { p = a2; d = d2; n = NV2; slot = 2; lb = b - 1536; nb = 256; }
    else               { p = a3; d = d3; n = NV2; slot = 3; lb = b - 1792; nb = 256; }
    float s = slot_scale(slots, slot);
    long str = (long)nb * 256;
    long v = (long)lb * 256 + threadIdx.x;
    for (; v + 3 * str < n; v += 4 * str) {
        #pragma unroll
        for (int j = 0; j < 4; j++) qstore4(p, v + j * str, d, s);
    }
    for (; v < n; v += str) qstore4(p, v, d, s);
}

// ---------------- generic quantize f32 -> int8 (4-deep MLP) ----------------
__global__ void k_quant(const float* __restrict__ x, int8_t* __restrict__ q, long nvec,
                        int rshift, long cmaskv, long ld,
                        const unsigned* __restrict__ slots, int slot) {
    float s = slot_scale(slots, slot);
    long gs = (long)gridDim.x * blockDim.x;
    long v = blockIdx.x * (long)blockDim.x + threadIdx.x;
    for (; v + 3 * gs < nvec; v += 4 * gs) {
        #pragma unroll
        for (int j = 0; j < 4; j++) {
            long vid = v + j * gs;
            long r = vid >> rshift;
            long c = (vid & cmaskv) << 2;
            float4 vv = *(const float4*)(x + r * ld + c);
            unsigned pa = (unsigned)(uint8_t)(int8_t)q8v(vv.x, s)
                        | ((unsigned)(uint8_t)(int8_t)q8v(vv.y, s) << 8)
                        | ((unsigned)(uint8_t)(int8_t)q8v(vv.z, s) << 16)
                        | ((unsigned)(uint8_t)(int8_t)q8v(vv.w, s) << 24);
            *(unsigned*)(q + vid * 4) = pa;
        }
    }
    for (; v < nvec; v += gs) {
        long r = v >> rshift;
        long c = (v & cmaskv) << 2;
        float4 vv = *(const float4*)(x + r * ld + c);
        unsigned pa = (unsigned)(uint8_t)(int8_t)q8v(vv.x, s)
                    | ((unsigned)(uint8_t)(int8_t)q8v(vv.y, s) << 8)
                    | ((unsigned)(uint8_t)(int8_t)q8v(vv.z, s) << 16)
                    | ((unsigned)(uint8_t)(int8_t)q8v(vv.w, s) << 24);
        *(unsigned*)(q + v * 4) = pa;
    }
}

// ---------------- rope cos/sin table ----------------
__global__ void k_ropetab(const int* __restrict__ pos, float* __restrict__ ct,
                          float* __restrict__ st) {
    int tid = blockIdx.x * blockDim.x + threadIdx.x;
    if (tid >= SEQ * 64) return;
    int i = tid & 63, s = tid >> 6;
    double inv = 1.0 / pow(10000.0, (double)((float)(2 * i) * (1.0f / 128.0f)));
    float invf = (float)inv;
    float angf = (float)pos[s] * invf;
    double a = (double)angf;
    ct[tid] = (float)cos(a);
    st[tid] = (float)sin(a);
}

// ---------------- rope in-place (float4, grid-stride) + block absmax ----------------
__global__ void k_rope(float* __restrict__ x, long ld, int hbits, int total,
                       const float* __restrict__ ct, const float* __restrict__ st,
                       unsigned* slots, int slot) {
    float m = 0.f;
    for (int t = blockIdx.x * blockDim.x + threadIdx.x; t < total;
         t += gridDim.x * blockDim.x) {
        int i4 = t & 15;
        int h = (t >> 4) & ((1 << hbits) - 1);
        int s = t >> (4 + hbits);
        long base = (long)s * ld + h * 128 + i4 * 4;
        float4 a = *(float4*)(x + base);
        float4 b = *(float4*)(x + base + 64);
        float4 c = *(const float4*)(ct + s * 64 + i4 * 4);
        float4 sn = *(const float4*)(st + s * 64 + i4 * 4);
        float4 o0, o1;
        o0.x = a.x * c.x - b.x * sn.x;  o1.x = b.x * c.x + a.x * sn.x;
        o0.y = a.y * c.y - b.y * sn.y;  o1.y = b.y * c.y + a.y * sn.y;
        o0.z = a.z * c.z - b.z * sn.z;  o1.z = b.z * c.z + a.z * sn.z;
        o0.w = a.w * c.w - b.w * sn.w;  o1.w = b.w * c.w + a.w * sn.w;
        *(float4*)(x + base) = o0;
        *(float4*)(x + base + 64) = o1;
        m = fmaxf(m,
            fmaxf(fmaxf(fmaxf(fabsf(o0.x), fabsf(o0.y)), fmaxf(fabsf(o0.z), fabsf(o0.w))),
                  fmaxf(fmaxf(fabsf(o1.x), fabsf(o1.y)), fmaxf(fabsf(o1.z), fabsf(o1.w)))));
    }
    block_amax_atomic(m, slots, slot);
}

// ---------------- transpose + quantize (V -> V^T int8) ----------------
__global__ void k_transq(const float* __restrict__ src, long lds_, int8_t* __restrict__ dst,
                         long ldd, const unsigned* __restrict__ slots, int slot) {
    __shared__ float t[32][33];
    float s = slot_scale(slots, slot);
    int bx = blockIdx.x, by = blockIdx.y;
    int tid = threadIdx.x;
    int c = tid & 31, r0 = tid >> 5;
    #pragma unroll
    for (int j = 0; j < 4; j++) {
        int r = r0 + j * 8;
        t[r][c] = src[(long)(by * 32 + r) * lds_ + bx * 32 + c];
    }
    __syncthreads();
    int d = tid >> 3, k4 = (tid & 7) * 4;
    unsigned pa = 0;
    #pragma unroll
    for (int j = 0; j < 4; j++) {
        int iv = q8v(t[k4 + j][d], s);
        pa |= ((unsigned)(uint8_t)(int8_t)iv) << (8 * j);
    }
    *(unsigned*)(dst + (long)(bx * 32 + d) * ldd + by * 32 + k4) = pa;
}

// ---------------- int8 GEMM, gload_lds staging + double-buffered 2-phase ----------------
__global__ __launch_bounds__(256) void k_gemm_i8(
    const int8_t* __restrict__ A, const int8_t* __restrict__ B, float* __restrict__ C,
    int M, int N, int K, unsigned* slots,
    int slotA, int slotB, int slotB2, int nsplit, int am_slot, int am_col0) {
    __shared__ int8_t As[2][128 * 128];
    __shared__ int8_t Bs[2][128 * 128];
    const v4i vzero = {0, 0, 0, 0};
    int tid = threadIdx.x, lane = tid & 63, wid = tid >> 6;
    int nbx = N >> 7;
    int nwg = gridDim.x, wg = blockIdx.x;
    int cpx = nwg >> 3;
    int swz = (wg & 7) * cpx + (wg >> 3);
    int bm = swz / nbx, bn = swz % nbx;
    long rowA0 = (long)bm * 128, colB0 = (long)bn * 128;
    int wrow = (wid >> 1) * 64, wcol = (wid & 1) * 64;
    int lr = lane >> 3;
    int swc = ((lane & 7) ^ lr) * 16;
    const int8_t* ga = A + (rowA0 + wid * 8 + lr) * (long)K + swc;
    const int8_t* gb = B + (colB0 + wid * 8 + lr) * (long)K + swc;
    v4i acc[4][4];
    #pragma unroll
    for (int m = 0; m < 4; m++)
        #pragma unroll
        for (int n = 0; n < 4; n++) acc[m][n] = vzero;

    auto STAGE = [&](int buf, int kt) {
        #pragma unroll
        for (int i = 0; i < 4; i++) {
            gload16(ga + kt + (long)(i * 32) * K, &As[buf][(wid * 8 + i * 32) * 128]);
            gload16(gb + kt + (long)(i * 32) * K, &Bs[buf][(wid * 8 + i * 32) * 128]);
        }
    };
    auto COMPUTE = [&](int buf) {
        #pragma unroll
        for (int ks = 0; ks < 2; ks++) {
            v4i af[4], bf[4];
            #pragma unroll
            for (int m = 0; m < 4; m++) {
                int row = wrow + m * 16 + (lane & 15);
                af[m] = *(const v4i*)(&As[buf][row * 128 + (((ks * 4 + (lane >> 4)) ^ (row & 7)) * 16)]);
            }
            #pragma unroll
            for (int n = 0; n < 4; n++) {
                int row = wcol + n * 16 + (lane & 15);
                bf[n] = *(const v4i*)(&Bs[buf][row * 128 + (((ks * 4 + (lane >> 4)) ^ (row & 7)) * 16)]);
            }
            #pragma unroll
            for (int m = 0; m < 4; m++)
                #pragma unroll
                for (int n = 0; n < 4; n++)
                    acc[m][n] = __builtin_amdgcn_mfma_i32_16x16x64_i8(af[m], bf[n], acc[m][n], 0, 0, 0);
        }
    };

    STAGE(0, 0);
    VMCNT0;
    __syncthreads();
    int nt = K >> 7, cur = 0;
    for (int t = 0; t < nt - 1; t++) {
        STAGE(cur ^ 1, (t + 1) << 7);
        COMPUTE(cur);
        VMCNT0;
        __syncthreads();
        cur ^= 1;
    }
    COMPUTE(cur);

    float sA = slot_scale(slots, slotA);
    float sB1 = slot_scale(slots, slotB);
    float sB2 = slot_scale(slots, slotB2);
    float am = 0.f;
    #pragma unroll
    for (int m = 0; m < 4; m++) {
        long row0 = rowA0 + wrow + m * 16 + ((lane >> 4) << 2);
        #pragma unroll
        for (int n = 0; n < 4; n++) {
            int col = (int)colB0 + wcol + n * 16 + (lane & 15);
            float sc = sA * ((col < nsplit) ? sB1 : sB2);
            float* cp = C + row0 * N + col;
            #pragma unroll
            for (int r = 0; r < 4; r++) {
                float val = sc * (float)acc[m][n][r];
                cp[(long)r * N] = val;
                if (col >= am_col0) am = fmaxf(am, fabsf(val));
            }
        }
    }
    if (am_slot >= 0) block_amax_atomic(am, slots, am_slot);
}

// ---------------- two-pass flash attention: gload_lds + K/V dbuf + mask-split ----------------
__global__ __launch_bounds__(256) void k_attn(
    const int8_t* __restrict__ Qq, const int8_t* __restrict__ Kq, const int8_t* __restrict__ Vtq,
    int* __restrict__ AO, unsigned* slots) {
    __shared__ int8_t Qs[64 * 128];   // reused as packed-P store in pass 2
    __shared__ int8_t Ks[2][64 * 128];
    __shared__ int8_t Vs[2][128 * 64];
    __shared__ int smx[4];
    const v4i vzero = {0, 0, 0, 0};
    const int NEGS = -(1 << 29);
    int tid = threadIdx.x, lane = tid & 63, w = tid >> 6;
    int qlan = lane & 15, g = lane >> 4;
    int idx = blockIdx.x;
    int qb = 31 - (idx >> 5), h = idx & 31, kvh = h >> 2;   // long blocks first
    float sq = slot_scale(slots, 5), sk = slot_scale(slots, 6);
    float c2 = sq * sk * 0.08838834764831845f * 1.4426950408889634f;  // /sqrt(128)*log2(e)
    int lr8 = lane >> 3;
    int swc = ((lane & 7) ^ lr8) * 16;
    int lr4 = lane >> 2;
    int vswc = ((lane & 3) ^ (lr4 & 3)) * 16;
    const int8_t* kbase = Kq + ((long)(w * 8 + lr8)) * KVDIM + kvh * 128 + swc;
    const int8_t* vbase = Vtq + ((long)kvh * 128 + w * 16 + lr4) * SEQ + vswc;
    auto STAGE_K = [&](int buf, int kt) {
        #pragma unroll
        for (int i = 0; i < 2; i++)
            gload16(kbase + ((long)kt * 64 + i * 32) * KVDIM, &Ks[buf][(w * 8 + i * 32) * 128]);
    };
    auto STAGE_V = [&](int buf, int kt) {
        #pragma unroll
        for (int i = 0; i < 2; i++)
            gload16(vbase + (long)(i * 64) * SEQ + kt * 64, &Vs[buf][(w * 16 + i * 64) * 64]);
    };
    {
        const int8_t* qbase = Qq + ((long)qb * 64 + w * 8 + lr8) * HID + h * 128 + swc;
        #pragma unroll
        for (int i = 0; i < 2; i++)
            gload16(qbase + (long)(i * 32) * HID, &Qs[(w * 8 + i * 32) * 128]);
    }
    STAGE_K(0, 0);
    VMCNT0;
    __syncthreads();
    v4i aq[2];
    #pragma unroll
    for (int ks = 0; ks < 2; ks++) {
        int row = w * 16 + qlan;
        aq[ks] = *(const v4i*)(&Qs[row * 128 + (((ks * 4 + g) ^ (row & 7)) * 16)]);
    }
    int mi = -(1 << 30);
    float l = 0.f;
    int buf = 0;
    for (int kt = 0; kt <= qb; kt++) {
        if (kt < qb) STAGE_K(buf ^ 1, kt + 1);
        v4i sf[4] = {vzero, vzero, vzero, vzero};
        __builtin_amdgcn_s_setprio(1);
        #pragma unroll
        for (int ks = 0; ks < 2; ks++)
            #pragma unroll
            for (int f = 0; f < 4; f++) {
                int row = f * 16 + qlan;
                v4i bk = *(const v4i*)(&Ks[buf][row * 128 + (((ks * 4 + g) ^ (row & 7)) * 16)]);
                sf[f] = __builtin_amdgcn_mfma_i32_16x16x64_i8(bk, aq[ks], sf[f], 0, 0, 0);  // C[k][q]
            }
        __builtin_amdgcn_s_setprio(0);
        int sv[16];
        if (kt == qb) {   // only the diagonal tile masks
            int qthr = w * 16 + qlan;
            #pragma unroll
            for (int f = 0; f < 4; f++)
                #pragma unroll
                for (int r = 0; r < 4; r++) {
                    int kl = f * 16 + g * 4 + r;
                    sv[f * 4 + r] = (kl > qthr) ? NEGS : sf[f][r];
                }
        } else {
            #pragma unroll
            for (int f = 0; f < 4; f++)
                #pragma unroll
                for (int r = 0; r < 4; r++) sv[f * 4 + r] = sf[f][r];
        }
        int tm = sv[0];
        #pragma unroll
        for (int e = 1; e < 16; e++) tm = tm > sv[e] ? tm : sv[e];
        tm = max(tm, __shfl_xor(tm, 16, 64));
        tm = max(tm, __shfl_xor(tm, 32, 64));
        int mn = tm > mi ? tm : mi;
        float esc = fexp2(c2 * (float)(mi - mn));
        float es = 0.f;
        #pragma unroll
        for (int e = 0; e < 16; e++) es += fexp2(c2 * (float)(sv[e] - mn));
        es += __shfl_xor(es, 16, 64);
        es += __shfl_xor(es, 32, 64);
        l = l * esc + es;
        mi = mn;
        VMCNT0;
        __syncthreads();
        buf ^= 1;
    }
    float invl = 127.0f / l;
    unsigned* Ps32 = (unsigned*)Qs;
    int pwr = w * 320;
    v4i of[8];
    #pragma unroll
    for (int nf = 0; nf < 8; nf++) of[nf] = vzero;
    STAGE_K(0, 0);
    STAGE_V(0, 0);
    VMCNT0;
    __syncthreads();
    buf = 0;
    for (int kt = 0; kt <= qb; kt++) {
        if (kt < qb) { STAGE_K(buf ^ 1, kt + 1); STAGE_V(buf ^ 1, kt + 1); }
        v4i sf[4] = {vzero, vzero, vzero, vzero};
        __builtin_amdgcn_s_setprio(1);
        #pragma unroll
        for (int ks = 0; ks < 2; ks++)
            #pragma unroll
            for (int f = 0; f < 4; f++) {
                int row = f * 16 + qlan;
                v4i bk = *(const v4i*)(&Ks[buf][row * 128 + (((ks * 4 + g) ^ (row & 7)) * 16)]);
                sf[f] = __builtin_amdgcn_mfma_i32_16x16x64_i8(bk, aq[ks], sf[f], 0, 0, 0);
            }
        __builtin_amdgcn_s_setprio(0);
        if (kt == qb) {
            int qthr = w * 16 + qlan;
            #pragma unroll
            for (int f = 0; f < 4; f++) {
                unsigned pk = 0;
                #pragma unroll
                for (int r = 0; r < 4; r++) {
                    int kl = f * 16 + g * 4 + r;
                    int s = (kl > qthr) ? NEGS : sf[f][r];
                    float t = fexp2(c2 * (float)(s - mi));
                    int pq = (int)rintf(t * invl);
                    pk |= ((unsigned)pq) << (8 * r);
                }
                Ps32[pwr + (4 * f + g) * 20 + qlan] = pk;
            }
        } else {
            #pragma unroll
            for (int f = 0; f < 4; f++) {
                unsigned pk = 0;
                #pragma unroll
                for (int r = 0; r < 4; r++) {
                    float t = fexp2(c2 * (float)(sf[f][r] - mi));
                    int pq = (int)rintf(t * invl);
                    pk |= ((unsigned)pq) << (8 * r);
                }
                Ps32[pwr + (4 * f + g) * 20 + qlan] = pk;
            }
        }
        int rb = pwr + 80 * g + qlan;
        v4i ap;
        ap[0] = (int)Ps32[rb];
        ap[1] = (int)Ps32[rb + 20];
        ap[2] = (int)Ps32[rb + 40];
        ap[3] = (int)Ps32[rb + 60];
        __builtin_amdgcn_s_setprio(1);
        #pragma unroll
        for (int nf = 0; nf < 8; nf++) {
            int row = nf * 16 + qlan;
            v4i bv = *(const v4i*)(&Vs[buf][row * 64 + ((g ^ (row & 3)) * 16)]);
            of[nf] = __builtin_amdgcn_mfma_i32_16x16x64_i8(ap, bv, of[nf], 0, 0, 0);
        }
        __builtin_amdgcn_s_setprio(0);
        VMCNT0;
        __syncthreads();
        buf ^= 1;
    }
    int mymax = 0;
    #pragma unroll
    for (int nf = 0; nf < 8; nf++)
        #pragma unroll
        for (int r = 0; r < 4; r++) {
            int val = of[nf][r];
            int av = val < 0 ? -val : val;
            mymax = av > mymax ? av : mymax;
            int qg = qb * 64 + w * 16 + 4 * g + r;
            AO[(long)qg * HID + h * 128 + nf * 16 + qlan] = val;
        }
    #pragma unroll
    for (int off = 1; off < 64; off <<= 1) {
        int o2 = __shfl_xor(mymax, off, 64);
        mymax = o2 > mymax ? o2 : mymax;
    }
    if (lane == 0) smx[w] = mymax;
    __syncthreads();
    if (tid == 0) {
        int mm = max(max(smx[0], smx[1]), max(smx[2], smx[3]));
        atomicMax(slots + (8 << 5), (unsigned)mm);
    }
}

// ---------------- quantize attn_out (int32 -> int8, 4-deep MLP) ----------------
__global__ void k_quant_ao(const int* __restrict__ a, int8_t* __restrict__ q, unsigned* slots) {
    float sv = slot_scale(slots, 7);
    float spv = (1.0f / 127.0f) * sv;
    float amax = spv * (float)(int)slots[8 << 5];
    float s = fmaxf(amax / 127.0f, 1e-8f);
    long nvec = (long)SEQ * HID / 4;
    long gs = (long)gridDim.x * blockDim.x;
    long v = blockIdx.x * (long)blockDim.x + threadIdx.x;
    for (; v + 3 * gs < nvec; v += 4 * gs) {
        #pragma unroll
        for (int j = 0; j < 4; j++) {
            long vid = v + j * gs;
            int4 x = *(const int4*)(a + vid * 4);
            int a0 = q8v(spv * (float)x.x, s);
            int a1 = q8v(spv * (float)x.y, s);
            int a2 = q8v(spv * (float)x.z, s);
            int a3 = q8v(spv * (float)x.w, s);
            unsigned pa = (unsigned)(uint8_t)(int8_t)a0
                        | ((unsigned)(uint8_t)(int8_t)a1 << 8)
                        | ((unsigned)(uint8_t)(int8_t)a2 << 16)
                        | ((unsigned)(uint8_t)(int8_t)a3 << 24);
            *(unsigned*)(q + vid * 4) = pa;
        }
    }
    for (; v < nvec; v += gs) {
        int4 x = *(const int4*)(a + v * 4);
        int a0 = q8v(spv * (float)x.x, s);
        int a1 = q8v(spv * (float)x.y, s);
        int a2 = q8v(spv * (float)x.z, s);
        int a3 = q8v(spv * (float)x.w, s);
        unsigned pa = (unsigned)(uint8_t)(int8_t)a0
                    | ((unsigned)(uint8_t)(int8_t)a1 << 8)
                    | ((unsigned)(uint8_t)(int8_t)a2 << 16)
                    | ((unsigned)(uint8_t)(int8_t)a3 << 24);
        *(unsigned*)(q + v * 4) = pa;
    }
    if (blockIdx.x == 0 && threadIdx.x == 0) slots[9 << 5] = __float_as_uint(amax);
}

extern "C" void kernel_launch(void* const* d_in, const int* in_sizes, int n_in,
                              void* d_out, int out_size, void* d_ws, size_t ws_size,
                              hipStream_t stream) {
    (void)in_sizes; (void)n_in; (void)out_size;
    const float* hid = (const float*)d_in[0];
    const int* pos = (const int*)d_in[2];
    const float* wqp = (const float*)d_in[3];
    const float* wkp = (const float*)d_in[4];
    const float* wvp = (const float*)d_in[5];
    const float* wop = (const float*)d_in[6];
    float* out = (float*)d_out;
    char* ws = (char*)d_ws;

    size_t o = 0;
    auto alloc = [&](size_t sz) { size_t r = o; o += (sz + 255) & ~(size_t)255; return r; };
    unsigned* slots = (unsigned*)(ws + alloc(2048));
    int8_t* Xq   = (int8_t*)(ws + alloc((size_t)SEQ * HID));      // later reused as AOq
    int8_t* Wqq  = (int8_t*)(ws + alloc((size_t)HID * HID));      // later reused as Woq
    int8_t* Wkvq = (int8_t*)(ws + alloc((size_t)KVCAT * HID));
    float*  Qf   = (float*)(ws + alloc((size_t)SEQ * HID * 4));   // later reused as AOint
    float*  KVf  = (float*)(ws + alloc((size_t)SEQ * KVCAT * 4));
    int8_t* Qq   = (int8_t*)(ws + alloc((size_t)SEQ * HID));
    int8_t* Kq   = (int8_t*)(ws + alloc((size_t)SEQ * KVDIM));
    int8_t* Vtq  = (int8_t*)(ws + alloc((size_t)KVDIM * SEQ));
    float*  ctab = (float*)(ws + alloc((size_t)SEQ * 64 * 4));
    float*  stab = (float*)(ws + alloc((size_t)SEQ * 64 * 4));
    if (ws_size < o) return;
    int8_t* Woq = Wqq;
    int*    AOint = (int*)Qf;
    int8_t* AOq = Xq;

    hipMemsetAsync(slots, 0, 2048, stream);
    k_ropetab<<<SEQ * 64 / 256, 256, 0, stream>>>(pos, ctab, stab);
    k_absmax5<<<2048, 256, 0, stream>>>(hid, wqp, wkp, wvp, wop, slots);
    k_quant4<<<2048, 256, 0, stream>>>(hid, wqp, wkp, wvp,
                                       Xq, Wqq, Wkvq, Wkvq + (size_t)KVDIM * HID, slots);
    k_gemm_i8<<<512, 256, 0, stream>>>(Xq, Wqq, Qf, SEQ, HID, HID, slots,
                                       0, 1, 1, 1 << 30, -1, 1 << 30);
    k_gemm_i8<<<256, 256, 0, stream>>>(Xq, Wkvq, KVf, SEQ, KVCAT, HID, slots,
                                       0, 2, 3, KVDIM, 7, KVDIM);   // fused V absmax -> slot 7
    const long CALL = 0x3FFFFFFFL;
    k_quant<<<2048, 256, 0, stream>>>(wop, Woq, (long)HID * HID / 4, 40, CALL, 0, slots, 4);
    k_rope<<<2048, 256, 0, stream>>>(Qf, HID, 5, SEQ * NH * 16, ctab, stab, slots, 5);
    k_rope<<<1024, 256, 0, stream>>>(KVf, KVCAT, 3, SEQ * NKV * 16, ctab, stab, slots, 6);
    k_quant<<<2048, 256, 0, stream>>>(Qf, Qq, (long)SEQ * HID / 4, 40, CALL, 0, slots, 5);
    k_quant<<<512, 256, 0, stream>>>(KVf, Kq, (long)SEQ * KVDIM / 4, 8, 255, KVCAT, slots, 6);
    k_transq<<<dim3(32, 64), 256, 0, stream>>>(KVf + KVDIM, KVCAT, Vtq, SEQ, slots, 7);
    k_attn<<<1024, 256, 0, stream>>>(Qq, Kq, Vtq, AOint, slots);
    k_quant_ao<<<2048, 256, 0, stream>>>(AOint, AOq, slots);
    k_gemm_i8<<<512, 256, 0, stream>>>(AOq, Woq, out, SEQ, HID, HID, slots,
                                       9, 4, 4, 1 << 30, -1, 1 << 30);
}

// Round 6
// 312.598 us; speedup vs baseline: 1.0546x; 1.0546x over previous
//
#include <hip/hip_runtime.h>
#include <stdint.h>

#define SEQ   2048
#define HID   4096
#define NH    32
#define NKV   8
#define KVDIM 1024   // NKV*HD
#define KVCAT 2048   // KVDIM*2

typedef int v4i __attribute__((ext_vector_type(4)));

#define VMCNT0 asm volatile("s_waitcnt vmcnt(0)" ::: "memory")

// async global->LDS 16B: per-lane global source, wave-uniform LDS base + lane*16
__device__ __forceinline__ void gload16(const void* g, void* l) {
    __builtin_amdgcn_global_load_lds(
        (const __attribute__((address_space(1))) void*)(uintptr_t)g,
        (__attribute__((address_space(3))) void*)(uintptr_t)l, 16, 0, 0);
}

// slots live 128 B apart; scales finalized by tiny reduce kernels (no bursty atomics)
__device__ __forceinline__ float slot_scale(const unsigned* slots, int slot) {
    return fmaxf(__uint_as_float(slots[slot << 5]) / 127.0f, 1e-8f);
}

__device__ __forceinline__ int q8v(float x, float s) {
    int v = (int)rintf(x / s);
    return v < -127 ? -127 : (v > 127 ? 127 : v);
}

__device__ __forceinline__ float fexp2(float x) {
    float r; asm("v_exp_f32 %0, %1" : "=v"(r) : "v"(x)); return r;
}

__device__ __forceinline__ float amax4(const float* __restrict__ p, long v) {
    float4 x = *(const float4*)(p + v * 4);
    return fmaxf(fmaxf(fabsf(x.x), fabsf(x.y)), fmaxf(fabsf(x.z), fabsf(x.w)));
}

// block-level reduce, then ONE plain store to partials[blockIdx.x] (no contention)
__device__ __forceinline__ void block_amax_store(float m, float* part) {
    __shared__ float sm[4];
    int lane = threadIdx.x & 63, w = threadIdx.x >> 6;
    for (int off = 32; off; off >>= 1) m = fmaxf(m, __shfl_xor(m, off, 64));
    if (lane == 0) sm[w] = m;
    __syncthreads();
    if (threadIdx.x == 0)
        part[blockIdx.x] = fmaxf(fmaxf(sm[0], sm[1]), fmaxf(sm[2], sm[3]));
}

// ---------------- fused absmax: blocks partitioned per tensor, partial stores ----------------
#define NV0 ((long)SEQ * HID / 4)     // 2M vecs
#define NV1 ((long)HID * HID / 4)     // 4M vecs
#define NV2 ((long)KVDIM * HID / 4)   // 1M vecs
__global__ void k_absmax5(const float* __restrict__ a0, const float* __restrict__ a1,
                          const float* __restrict__ a2, const float* __restrict__ a3,
                          const float* __restrict__ a4, float* __restrict__ part) {
    int b = blockIdx.x;
    const float* p; long n; int lb, nb;
    if (b < 342)       { p = a0; n = NV0; lb = b;        nb = 342; }
    else if (b < 1025) { p = a1; n = NV1; lb = b - 342;  nb = 683; }
    else if (b < 1196) { p = a2; n = NV2; lb = b - 1025; nb = 171; }
    else if (b < 1367) { p = a3; n = NV2; lb = b - 1196; nb = 171; }
    else               { p = a4; n = NV1; lb = b - 1367; nb = 681; }
    long str = (long)nb * 256;
    float mm[8] = {0.f, 0.f, 0.f, 0.f, 0.f, 0.f, 0.f, 0.f};
    long v = (long)lb * 256 + threadIdx.x;
    for (; v + 7 * str < n; v += 8 * str) {
        #pragma unroll
        for (int j = 0; j < 8; j++) mm[j] = fmaxf(mm[j], amax4(p, v + j * str));
    }
    for (; v < n; v += str) mm[0] = fmaxf(mm[0], amax4(p, v));
    float m = fmaxf(fmaxf(fmaxf(mm[0], mm[1]), fmaxf(mm[2], mm[3])),
                    fmaxf(fmaxf(mm[4], mm[5]), fmaxf(mm[6], mm[7])));
    block_amax_store(m, part);
}

// ---------------- reduce partials -> slots 0..4 ----------------
__global__ void k_reduceA(const float* __restrict__ part, unsigned* slots) {
    __shared__ float sm[4];
    const int lo[5] = {0, 342, 1025, 1196, 1367};
    const int hi[5] = {342, 1025, 1196, 1367, 2048};
    int t = threadIdx.x, lane = t & 63, w = t >> 6;
    for (int s = 0; s < 5; s++) {
        float m = 0.f;
        for (int i = lo[s] + t; i < hi[s]; i += 256) m = fmaxf(m, part[i]);
        for (int off = 32; off; off >>= 1) m = fmaxf(m, __shfl_xor(m, off, 64));
        if (lane == 0) sm[w] = m;
        __syncthreads();
        if (t == 0)
            slots[s << 5] = __float_as_uint(fmaxf(fmaxf(sm[0], sm[1]), fmaxf(sm[2], sm[3])));
        __syncthreads();
    }
}

// ---------------- reduce partials -> slots 5 (q), 6 (k), 7 (v) ----------------
__global__ void k_reduceB(const float* __restrict__ p1, const float* __restrict__ p2,
                          const float* __restrict__ p3, unsigned* slots) {
    __shared__ float sm[4];
    int t = threadIdx.x, lane = t & 63, w = t >> 6;
    const float* ps[3] = {p1, p2, p3};
    const int cnt[3] = {2048, 1024, 256};
    const int sl[3] = {5, 6, 7};
    for (int s = 0; s < 3; s++) {
        float m = 0.f;
        for (int i = t; i < cnt[s]; i += 256) m = fmaxf(m, ps[s][i]);
        for (int off = 32; off; off >>= 1) m = fmaxf(m, __shfl_xor(m, off, 64));
        if (lane == 0) sm[w] = m;
        __syncthreads();
        if (t == 0)
            slots[sl[s] << 5] = __float_as_uint(fmaxf(fmaxf(sm[0], sm[1]), fmaxf(sm[2], sm[3])));
        __syncthreads();
    }
}

__device__ __forceinline__ void qstore4(const float* __restrict__ src, long v,
                                        int8_t* __restrict__ dst, float s) {
    float4 x = *(const float4*)(src + v * 4);
    unsigned pa = (unsigned)(uint8_t)(int8_t)q8v(x.x, s)
                | ((unsigned)(uint8_t)(int8_t)q8v(x.y, s) << 8)
                | ((unsigned)(uint8_t)(int8_t)q8v(x.z, s) << 16)
                | ((unsigned)(uint8_t)(int8_t)q8v(x.w, s) << 24);
    *(unsigned*)(dst + v * 4) = pa;
}

// ---------------- fused quantize of hid, wq, wk, wv (partitioned, 4-deep MLP) ----------------
__global__ void k_quant4(const float* __restrict__ a0, const float* __restrict__ a1,
                         const float* __restrict__ a2, const float* __restrict__ a3,
                         int8_t* __restrict__ d0, int8_t* __restrict__ d1,
                         int8_t* __restrict__ d2, int8_t* __restrict__ d3,
                         const unsigned* __restrict__ slots) {
    int b = blockIdx.x;
    const float* p; int8_t* d; long n; int slot, lb, nb;
    if (b < 512)       { p = a0; d = d0; n = NV0; slot = 0; lb = b;        nb = 512; }
    else if (b < 1536) { p = a1; d = d1; n = NV1; slot = 1; lb = b - 512;  nb = 1024; }
    else if (b < 1792) { p = a2; d = d2; n = NV2; slot = 2; lb = b - 1536; nb = 256; }
    else               { p = a3; d = d3; n = NV2; slot = 3; lb = b - 1792; nb = 256; }
    float s = slot_scale(slots, slot);
    long str = (long)nb * 256;
    long v = (long)lb * 256 + threadIdx.x;
    for (; v + 3 * str < n; v += 4 * str) {
        #pragma unroll
        for (int j = 0; j < 4; j++) qstore4(p, v + j * str, d, s);
    }
    for (; v < n; v += str) qstore4(p, v, d, s);
}

// ---------------- generic quantize f32 -> int8 (4-deep MLP) ----------------
__global__ void k_quant(const float* __restrict__ x, int8_t* __restrict__ q, long nvec,
                        int rshift, long cmaskv, long ld,
                        const unsigned* __restrict__ slots, int slot) {
    float s = slot_scale(slots, slot);
    long gs = (long)gridDim.x * blockDim.x;
    long v = blockIdx.x * (long)blockDim.x + threadIdx.x;
    for (; v + 3 * gs < nvec; v += 4 * gs) {
        #pragma unroll
        for (int j = 0; j < 4; j++) {
            long vid = v + j * gs;
            long r = vid >> rshift;
            long c = (vid & cmaskv) << 2;
            float4 vv = *(const float4*)(x + r * ld + c);
            unsigned pa = (unsigned)(uint8_t)(int8_t)q8v(vv.x, s)
                        | ((unsigned)(uint8_t)(int8_t)q8v(vv.y, s) << 8)
                        | ((unsigned)(uint8_t)(int8_t)q8v(vv.z, s) << 16)
                        | ((unsigned)(uint8_t)(int8_t)q8v(vv.w, s) << 24);
            *(unsigned*)(q + vid * 4) = pa;
        }
    }
    for (; v < nvec; v += gs) {
        long r = v >> rshift;
        long c = (v & cmaskv) << 2;
        float4 vv = *(const float4*)(x + r * ld + c);
        unsigned pa = (unsigned)(uint8_t)(int8_t)q8v(vv.x, s)
                    | ((unsigned)(uint8_t)(int8_t)q8v(vv.y, s) << 8)
                    | ((unsigned)(uint8_t)(int8_t)q8v(vv.z, s) << 16)
                    | ((unsigned)(uint8_t)(int8_t)q8v(vv.w, s) << 24);
        *(unsigned*)(q + v * 4) = pa;
    }
}

// ---------------- rope cos/sin table ----------------
__global__ void k_ropetab(const int* __restrict__ pos, float* __restrict__ ct,
                          float* __restrict__ st) {
    int tid = blockIdx.x * blockDim.x + threadIdx.x;
    if (tid >= SEQ * 64) return;
    int i = tid & 63, s = tid >> 6;
    double inv = 1.0 / pow(10000.0, (double)((float)(2 * i) * (1.0f / 128.0f)));
    float invf = (float)inv;
    float angf = (float)pos[s] * invf;
    double a = (double)angf;
    ct[tid] = (float)cos(a);
    st[tid] = (float)sin(a);
}

// ---------------- rope in-place (float4, grid-stride) + partial absmax ----------------
__global__ void k_rope(float* __restrict__ x, long ld, int hbits, int total,
                       const float* __restrict__ ct, const float* __restrict__ st,
                       float* __restrict__ part) {
    float m = 0.f;
    for (int t = blockIdx.x * blockDim.x + threadIdx.x; t < total;
         t += gridDim.x * blockDim.x) {
        int i4 = t & 15;
        int h = (t >> 4) & ((1 << hbits) - 1);
        int s = t >> (4 + hbits);
        long base = (long)s * ld + h * 128 + i4 * 4;
        float4 a = *(float4*)(x + base);
        float4 b = *(float4*)(x + base + 64);
        float4 c = *(const float4*)(ct + s * 64 + i4 * 4);
        float4 sn = *(const float4*)(st + s * 64 + i4 * 4);
        float4 o0, o1;
        o0.x = a.x * c.x - b.x * sn.x;  o1.x = b.x * c.x + a.x * sn.x;
        o0.y = a.y * c.y - b.y * sn.y;  o1.y = b.y * c.y + a.y * sn.y;
        o0.z = a.z * c.z - b.z * sn.z;  o1.z = b.z * c.z + a.z * sn.z;
        o0.w = a.w * c.w - b.w * sn.w;  o1.w = b.w * c.w + a.w * sn.w;
        *(float4*)(x + base) = o0;
        *(float4*)(x + base + 64) = o1;
        m = fmaxf(m,
            fmaxf(fmaxf(fmaxf(fabsf(o0.x), fabsf(o0.y)), fmaxf(fabsf(o0.z), fabsf(o0.w))),
                  fmaxf(fmaxf(fabsf(o1.x), fabsf(o1.y)), fmaxf(fabsf(o1.z), fabsf(o1.w)))));
    }
    block_amax_store(m, part);
}

// ---------------- transpose + quantize (V -> V^T int8) ----------------
__global__ void k_transq(const float* __restrict__ src, long lds_, int8_t* __restrict__ dst,
                         long ldd, const unsigned* __restrict__ slots, int slot) {
    __shared__ float t[32][33];
    float s = slot_scale(slots, slot);
    int bx = blockIdx.x, by = blockIdx.y;
    int tid = threadIdx.x;
    int c = tid & 31, r0 = tid >> 5;
    #pragma unroll
    for (int j = 0; j < 4; j++) {
        int r = r0 + j * 8;
        t[r][c] = src[(long)(by * 32 + r) * lds_ + bx * 32 + c];
    }
    __syncthreads();
    int d = tid >> 3, k4 = (tid & 7) * 4;
    unsigned pa = 0;
    #pragma unroll
    for (int j = 0; j < 4; j++) {
        int iv = q8v(t[k4 + j][d], s);
        pa |= ((unsigned)(uint8_t)(int8_t)iv) << (8 * j);
    }
    *(unsigned*)(dst + (long)(bx * 32 + d) * ldd + by * 32 + k4) = pa;
}

// ---------------- int8 GEMM, gload_lds staging + double-buffered 2-phase ----------------
__global__ __launch_bounds__(256) void k_gemm_i8(
    const int8_t* __restrict__ A, const int8_t* __restrict__ B, float* __restrict__ C,
    int M, int N, int K, unsigned* slots,
    int slotA, int slotB, int slotB2, int nsplit, float* am_part, int am_col0) {
    __shared__ int8_t As[2][128 * 128];
    __shared__ int8_t Bs[2][128 * 128];
    const v4i vzero = {0, 0, 0, 0};
    int tid = threadIdx.x, lane = tid & 63, wid = tid >> 6;
    int nbx = N >> 7;
    int nwg = gridDim.x, wg = blockIdx.x;
    int cpx = nwg >> 3;
    int swz = (wg & 7) * cpx + (wg >> 3);
    int bm = swz / nbx, bn = swz % nbx;
    long rowA0 = (long)bm * 128, colB0 = (long)bn * 128;
    int wrow = (wid >> 1) * 64, wcol = (wid & 1) * 64;
    int lr = lane >> 3;
    int swc = ((lane & 7) ^ lr) * 16;
    const int8_t* ga = A + (rowA0 + wid * 8 + lr) * (long)K + swc;
    const int8_t* gb = B + (colB0 + wid * 8 + lr) * (long)K + swc;
    v4i acc[4][4];
    #pragma unroll
    for (int m = 0; m < 4; m++)
        #pragma unroll
        for (int n = 0; n < 4; n++) acc[m][n] = vzero;

    auto STAGE = [&](int buf, int kt) {
        #pragma unroll
        for (int i = 0; i < 4; i++) {
            gload16(ga + kt + (long)(i * 32) * K, &As[buf][(wid * 8 + i * 32) * 128]);
            gload16(gb + kt + (long)(i * 32) * K, &Bs[buf][(wid * 8 + i * 32) * 128]);
        }
    };
    auto COMPUTE = [&](int buf) {
        #pragma unroll
        for (int ks = 0; ks < 2; ks++) {
            v4i af[4], bf[4];
            #pragma unroll
            for (int m = 0; m < 4; m++) {
                int row = wrow + m * 16 + (lane & 15);
                af[m] = *(const v4i*)(&As[buf][row * 128 + (((ks * 4 + (lane >> 4)) ^ (row & 7)) * 16)]);
            }
            #pragma unroll
            for (int n = 0; n < 4; n++) {
                int row = wcol + n * 16 + (lane & 15);
                bf[n] = *(const v4i*)(&Bs[buf][row * 128 + (((ks * 4 + (lane >> 4)) ^ (row & 7)) * 16)]);
            }
            #pragma unroll
            for (int m = 0; m < 4; m++)
                #pragma unroll
                for (int n = 0; n < 4; n++)
                    acc[m][n] = __builtin_amdgcn_mfma_i32_16x16x64_i8(af[m], bf[n], acc[m][n], 0, 0, 0);
        }
    };

    STAGE(0, 0);
    VMCNT0;
    __syncthreads();
    int nt = K >> 7, cur = 0;
    for (int t = 0; t < nt - 1; t++) {
        STAGE(cur ^ 1, (t + 1) << 7);
        COMPUTE(cur);
        VMCNT0;
        __syncthreads();
        cur ^= 1;
    }
    COMPUTE(cur);

    float sA = slot_scale(slots, slotA);
    float sB1 = slot_scale(slots, slotB);
    float sB2 = slot_scale(slots, slotB2);
    float am = 0.f;
    #pragma unroll
    for (int m = 0; m < 4; m++) {
        long row0 = rowA0 + wrow + m * 16 + ((lane >> 4) << 2);
        #pragma unroll
        for (int n = 0; n < 4; n++) {
            int col = (int)colB0 + wcol + n * 16 + (lane & 15);
            float sc = sA * ((col < nsplit) ? sB1 : sB2);
            float* cp = C + row0 * N + col;
            #pragma unroll
            for (int r = 0; r < 4; r++) {
                float val = sc * (float)acc[m][n][r];
                cp[(long)r * N] = val;
                if (col >= am_col0) am = fmaxf(am, fabsf(val));
            }
        }
    }
    if (am_part) block_amax_store(am, am_part);
}

// ---------------- two-pass flash attention: gload_lds + K/V dbuf + mask-split ----------------
__global__ __launch_bounds__(256) void k_attn(
    const int8_t* __restrict__ Qq, const int8_t* __restrict__ Kq, const int8_t* __restrict__ Vtq,
    int* __restrict__ AO, unsigned* slots) {
    __shared__ int8_t Qs[64 * 128];   // reused as packed-P store in pass 2
    __shared__ int8_t Ks[2][64 * 128];
    __shared__ int8_t Vs[2][128 * 64];
    __shared__ int smx[4];
    const v4i vzero = {0, 0, 0, 0};
    const int NEGS = -(1 << 29);
    int tid = threadIdx.x, lane = tid & 63, w = tid >> 6;
    int qlan = lane & 15, g = lane >> 4;
    int idx = blockIdx.x;
    int qb = 31 - (idx >> 5), h = idx & 31, kvh = h >> 2;   // long blocks first
    float sq = slot_scale(slots, 5), sk = slot_scale(slots, 6);
    float c2 = sq * sk * 0.08838834764831845f * 1.4426950408889634f;  // /sqrt(128)*log2(e)
    int lr8 = lane >> 3;
    int swc = ((lane & 7) ^ lr8) * 16;
    int lr4 = lane >> 2;
    int vswc = ((lane & 3) ^ (lr4 & 3)) * 16;
    const int8_t* kbase = Kq + ((long)(w * 8 + lr8)) * KVDIM + kvh * 128 + swc;
    const int8_t* vbase = Vtq + ((long)kvh * 128 + w * 16 + lr4) * SEQ + vswc;
    auto STAGE_K = [&](int buf, int kt) {
        #pragma unroll
        for (int i = 0; i < 2; i++)
            gload16(kbase + ((long)kt * 64 + i * 32) * KVDIM, &Ks[buf][(w * 8 + i * 32) * 128]);
    };
    auto STAGE_V = [&](int buf, int kt) {
        #pragma unroll
        for (int i = 0; i < 2; i++)
            gload16(vbase + (long)(i * 64) * SEQ + kt * 64, &Vs[buf][(w * 16 + i * 64) * 64]);
    };
    {
        const int8_t* qbase = Qq + ((long)qb * 64 + w * 8 + lr8) * HID + h * 128 + swc;
        #pragma unroll
        for (int i = 0; i < 2; i++)
            gload16(qbase + (long)(i * 32) * HID, &Qs[(w * 8 + i * 32) * 128]);
    }
    STAGE_K(0, 0);
    VMCNT0;
    __syncthreads();
    v4i aq[2];
    #pragma unroll
    for (int ks = 0; ks < 2; ks++) {
        int row = w * 16 + qlan;
        aq[ks] = *(const v4i*)(&Qs[row * 128 + (((ks * 4 + g) ^ (row & 7)) * 16)]);
    }
    int mi = -(1 << 30);
    float l = 0.f;
    int buf = 0;
    for (int kt = 0; kt <= qb; kt++) {
        if (kt < qb) STAGE_K(buf ^ 1, kt + 1);
        v4i sf[4] = {vzero, vzero, vzero, vzero};
        __builtin_amdgcn_s_setprio(1);
        #pragma unroll
        for (int ks = 0; ks < 2; ks++)
            #pragma unroll
            for (int f = 0; f < 4; f++) {
                int row = f * 16 + qlan;
                v4i bk = *(const v4i*)(&Ks[buf][row * 128 + (((ks * 4 + g) ^ (row & 7)) * 16)]);
                sf[f] = __builtin_amdgcn_mfma_i32_16x16x64_i8(bk, aq[ks], sf[f], 0, 0, 0);  // C[k][q]
            }
        __builtin_amdgcn_s_setprio(0);
        int sv[16];
        if (kt == qb) {   // only the diagonal tile masks
            int qthr = w * 16 + qlan;
            #pragma unroll
            for (int f = 0; f < 4; f++)
                #pragma unroll
                for (int r = 0; r < 4; r++) {
                    int kl = f * 16 + g * 4 + r;
                    sv[f * 4 + r] = (kl > qthr) ? NEGS : sf[f][r];
                }
        } else {
            #pragma unroll
            for (int f = 0; f < 4; f++)
                #pragma unroll
                for (int r = 0; r < 4; r++) sv[f * 4 + r] = sf[f][r];
        }
        int tm = sv[0];
        #pragma unroll
        for (int e = 1; e < 16; e++) tm = tm > sv[e] ? tm : sv[e];
        tm = max(tm, __shfl_xor(tm, 16, 64));
        tm = max(tm, __shfl_xor(tm, 32, 64));
        int mn = tm > mi ? tm : mi;
        float esc = fexp2(c2 * (float)(mi - mn));
        float es = 0.f;
        #pragma unroll
        for (int e = 0; e < 16; e++) es += fexp2(c2 * (float)(sv[e] - mn));
        es += __shfl_xor(es, 16, 64);
        es += __shfl_xor(es, 32, 64);
        l = l * esc + es;
        mi = mn;
        VMCNT0;
        __syncthreads();
        buf ^= 1;
    }
    float invl = 127.0f / l;
    unsigned* Ps32 = (unsigned*)Qs;
    int pwr = w * 320;
    v4i of[8];
    #pragma unroll
    for (int nf = 0; nf < 8; nf++) of[nf] = vzero;
    STAGE_K(0, 0);
    STAGE_V(0, 0);
    VMCNT0;
    __syncthreads();
    buf = 0;
    for (int kt = 0; kt <= qb; kt++) {
        if (kt < qb) { STAGE_K(buf ^ 1, kt + 1); STAGE_V(buf ^ 1, kt + 1); }
        v4i sf[4] = {vzero, vzero, vzero, vzero};
        __builtin_amdgcn_s_setprio(1);
        #pragma unroll
        for (int ks = 0; ks < 2; ks++)
            #pragma unroll
            for (int f = 0; f < 4; f++) {
                int row = f * 16 + qlan;
                v4i bk = *(const v4i*)(&Ks[buf][row * 128 + (((ks * 4 + g) ^ (row & 7)) * 16)]);
                sf[f] = __builtin_amdgcn_mfma_i32_16x16x64_i8(bk, aq[ks], sf[f], 0, 0, 0);
            }
        __builtin_amdgcn_s_setprio(0);
        if (kt == qb) {
            int qthr = w * 16 + qlan;
            #pragma unroll
            for (int f = 0; f < 4; f++) {
                unsigned pk = 0;
                #pragma unroll
                for (int r = 0; r < 4; r++) {
                    int kl = f * 16 + g * 4 + r;
                    int s = (kl > qthr) ? NEGS : sf[f][r];
                    float t = fexp2(c2 * (float)(s - mi));
                    int pq = (int)rintf(t * invl);
                    pk |= ((unsigned)pq) << (8 * r);
                }
                Ps32[pwr + (4 * f + g) * 20 + qlan] = pk;
            }
        } else {
            #pragma unroll
            for (int f = 0; f < 4; f++) {
                unsigned pk = 0;
                #pragma unroll
                for (int r = 0; r < 4; r++) {
                    float t = fexp2(c2 * (float)(sf[f][r] - mi));
                    int pq = (int)rintf(t * invl);
                    pk |= ((unsigned)pq) << (8 * r);
                }
                Ps32[pwr + (4 * f + g) * 20 + qlan] = pk;
            }
        }
        int rb = pwr + 80 * g + qlan;
        v4i ap;
        ap[0] = (int)Ps32[rb];
        ap[1] = (int)Ps32[rb + 20];
        ap[2] = (int)Ps32[rb + 40];
        ap[3] = (int)Ps32[rb + 60];
        __builtin_amdgcn_s_setprio(1);
        #pragma unroll
        for (int nf = 0; nf < 8; nf++) {
            int row = nf * 16 + qlan;
            v4i bv = *(const v4i*)(&Vs[buf][row * 64 + ((g ^ (row & 3)) * 16)]);
            of[nf] = __builtin_amdgcn_mfma_i32_16x16x64_i8(ap, bv, of[nf], 0, 0, 0);
        }
        __builtin_amdgcn_s_setprio(0);
        VMCNT0;
        __syncthreads();
        buf ^= 1;
    }
    int mymax = 0;
    #pragma unroll
    for (int nf = 0; nf < 8; nf++)
        #pragma unroll
        for (int r = 0; r < 4; r++) {
            int val = of[nf][r];
            int av = val < 0 ? -val : val;
            mymax = av > mymax ? av : mymax;
            int qg = qb * 64 + w * 16 + 4 * g + r;
            AO[(long)qg * HID + h * 128 + nf * 16 + qlan] = val;
        }
    #pragma unroll
    for (int off = 1; off < 64; off <<= 1) {
        int o2 = __shfl_xor(mymax, off, 64);
        mymax = o2 > mymax ? o2 : mymax;
    }
    if (lane == 0) smx[w] = mymax;
    __syncthreads();
    if (tid == 0) {
        int mm = max(max(smx[0], smx[1]), max(smx[2], smx[3]));
        atomicMax(slots + (8 << 5), (unsigned)mm);   // staggered retirement: no burst
    }
}

// ---------------- quantize attn_out (int32 -> int8, 4-deep MLP) ----------------
__global__ void k_quant_ao(const int* __restrict__ a, int8_t* __restrict__ q, unsigned* slots) {
    float sv = slot_scale(slots, 7);
    float spv = (1.0f / 127.0f) * sv;
    float amax = spv * (float)(int)slots[8 << 5];
    float s = fmaxf(amax / 127.0f, 1e-8f);
    long nvec = (long)SEQ * HID / 4;
    long gs = (long)gridDim.x * blockDim.x;
    long v = blockIdx.x * (long)blockDim.x + threadIdx.x;
    for (; v + 3 * gs < nvec; v += 4 * gs) {
        #pragma unroll
        for (int j = 0; j < 4; j++) {
            long vid = v + j * gs;
            int4 x = *(const int4*)(a + vid * 4);
            int a0 = q8v(spv * (float)x.x, s);
            int a1 = q8v(spv * (float)x.y, s);
            int a2 = q8v(spv * (float)x.z, s);
            int a3 = q8v(spv * (float)x.w, s);
            unsigned pa = (unsigned)(uint8_t)(int8_t)a0
                        | ((unsigned)(uint8_t)(int8_t)a1 << 8)
                        | ((unsigned)(uint8_t)(int8_t)a2 << 16)
                        | ((unsigned)(uint8_t)(int8_t)a3 << 24);
            *(unsigned*)(q + vid * 4) = pa;
        }
    }
    for (; v < nvec; v += gs) {
        int4 x = *(const int4*)(a + v * 4);
        int a0 = q8v(spv * (float)x.x, s);
        int a1 = q8v(spv * (float)x.y, s);
        int a2 = q8v(spv * (float)x.z, s);
        int a3 = q8v(spv * (float)x.w, s);
        unsigned pa = (unsigned)(uint8_t)(int8_t)a0
                    | ((unsigned)(uint8_t)(int8_t)a1 << 8)
                    | ((unsigned)(uint8_t)(int8_t)a2 << 16)
                    | ((unsigned)(uint8_t)(int8_t)a3 << 24);
        *(unsigned*)(q + v * 4) = pa;
    }
    if (blockIdx.x == 0 && threadIdx.x == 0) slots[9 << 5] = __float_as_uint(amax);
}

extern "C" void kernel_launch(void* const* d_in, const int* in_sizes, int n_in,
                              void* d_out, int out_size, void* d_ws, size_t ws_size,
                              hipStream_t stream) {
    (void)in_sizes; (void)n_in; (void)out_size;
    const float* hid = (const float*)d_in[0];
    const int* pos = (const int*)d_in[2];
    const float* wqp = (const float*)d_in[3];
    const float* wkp = (const float*)d_in[4];
    const float* wvp = (const float*)d_in[5];
    const float* wop = (const float*)d_in[6];
    float* out = (float*)d_out;
    char* ws = (char*)d_ws;

    size_t o = 0;
    auto alloc = [&](size_t sz) { size_t r = o; o += (sz + 255) & ~(size_t)255; return r; };
    unsigned* slots = (unsigned*)(ws + alloc(2048));
    float* P0 = (float*)(ws + alloc(2048 * 4));   // absmax5 partials
    float* P1 = (float*)(ws + alloc(2048 * 4));   // ropeQ partials
    float* P2 = (float*)(ws + alloc(1024 * 4));   // ropeKV partials
    float* P3 = (float*)(ws + alloc(256 * 4));    // gemmKV V-absmax partials
    int8_t* Xq   = (int8_t*)(ws + alloc((size_t)SEQ * HID));      // later reused as AOq
    int8_t* Wqq  = (int8_t*)(ws + alloc((size_t)HID * HID));      // later reused as Woq
    int8_t* Wkvq = (int8_t*)(ws + alloc((size_t)KVCAT * HID));
    float*  Qf   = (float*)(ws + alloc((size_t)SEQ * HID * 4));   // later reused as AOint
    float*  KVf  = (float*)(ws + alloc((size_t)SEQ * KVCAT * 4));
    int8_t* Qq   = (int8_t*)(ws + alloc((size_t)SEQ * HID));
    int8_t* Kq   = (int8_t*)(ws + alloc((size_t)SEQ * KVDIM));
    int8_t* Vtq  = (int8_t*)(ws + alloc((size_t)KVDIM * SEQ));
    float*  ctab = (float*)(ws + alloc((size_t)SEQ * 64 * 4));
    float*  stab = (float*)(ws + alloc((size_t)SEQ * 64 * 4));
    if (ws_size < o) return;
    int8_t* Woq = Wqq;
    int*    AOint = (int*)Qf;
    int8_t* AOq = Xq;

    hipMemsetAsync(slots, 0, 2048, stream);
    k_ropetab<<<SEQ * 64 / 256, 256, 0, stream>>>(pos, ctab, stab);
    k_absmax5<<<2048, 256, 0, stream>>>(hid, wqp, wkp, wvp, wop, P0);
    k_reduceA<<<1, 256, 0, stream>>>(P0, slots);
    k_quant4<<<2048, 256, 0, stream>>>(hid, wqp, wkp, wvp,
                                       Xq, Wqq, Wkvq, Wkvq + (size_t)KVDIM * HID, slots);
    k_gemm_i8<<<512, 256, 0, stream>>>(Xq, Wqq, Qf, SEQ, HID, HID, slots,
                                       0, 1, 1, 1 << 30, nullptr, 1 << 30);
    k_gemm_i8<<<256, 256, 0, stream>>>(Xq, Wkvq, KVf, SEQ, KVCAT, HID, slots,
                                       0, 2, 3, KVDIM, P3, KVDIM);   // V absmax partials
    const long CALL = 0x3FFFFFFFL;
    k_quant<<<2048, 256, 0, stream>>>(wop, Woq, (long)HID * HID / 4, 40, CALL, 0, slots, 4);
    k_rope<<<2048, 256, 0, stream>>>(Qf, HID, 5, SEQ * NH * 16, ctab, stab, P1);
    k_rope<<<1024, 256, 0, stream>>>(KVf, KVCAT, 3, SEQ * NKV * 16, ctab, stab, P2);
    k_reduceB<<<1, 256, 0, stream>>>(P1, P2, P3, slots);
    k_quant<<<2048, 256, 0, stream>>>(Qf, Qq, (long)SEQ * HID / 4, 40, CALL, 0, slots, 5);
    k_quant<<<512, 256, 0, stream>>>(KVf, Kq, (long)SEQ * KVDIM / 4, 8, 255, KVCAT, slots, 6);
    k_transq<<<dim3(32, 64), 256, 0, stream>>>(KVf + KVDIM, KVCAT, Vtq, SEQ, slots, 7);
    k_attn<<<1024, 256, 0, stream>>>(Qq, Kq, Vtq, AOint, slots);
    k_quant_ao<<<2048, 256, 0, stream>>>(AOint, AOq, slots);
    k_gemm_i8<<<512, 256, 0, stream>>>(AOq, Woq, out, SEQ, HID, HID, slots,
                                       9, 4, 4, 1 << 30, nullptr, 1 << 30);
}

// Round 7
// 310.026 us; speedup vs baseline: 1.0634x; 1.0083x over previous
//
#include <hip/hip_runtime.h>
#include <stdint.h>

#define SEQ   2048
#define HID   4096
#define NH    32
#define NKV   8
#define KVDIM 1024   // NKV*HD
#define KVCAT 2048   // KVDIM*2

typedef int v4i __attribute__((ext_vector_type(4)));

#define VMCNT0 asm volatile("s_waitcnt vmcnt(0)" ::: "memory")

// async global->LDS 16B: per-lane global source, wave-uniform LDS base + lane*16
__device__ __forceinline__ void gload16(const void* g, void* l) {
    __builtin_amdgcn_global_load_lds(
        (const __attribute__((address_space(1))) void*)(uintptr_t)g,
        (__attribute__((address_space(3))) void*)(uintptr_t)l, 16, 0, 0);
}

__device__ __forceinline__ float slot_scale(const unsigned* slots, int slot) {
    return fmaxf(__uint_as_float(slots[slot << 5]) / 127.0f, 1e-8f);
}

__device__ __forceinline__ int q8v(float x, float s) {
    int v = (int)rintf(x / s);
    return v < -127 ? -127 : (v > 127 ? 127 : v);
}

__device__ __forceinline__ float fexp2(float x) {
    float r; asm("v_exp_f32 %0, %1" : "=v"(r) : "v"(x)); return r;
}

// block-level reduce (4 waves), ONE plain store, trailing sync (safe to chain)
__device__ __forceinline__ void block_amax_part(float m, float* dst) {
    __shared__ float sm[4];
    int lane = threadIdx.x & 63, w = threadIdx.x >> 6;
    for (int off = 32; off; off >>= 1) m = fmaxf(m, __shfl_xor(m, off, 64));
    if (lane == 0) sm[w] = m;
    __syncthreads();
    if (threadIdx.x == 0)
        *dst = fmaxf(fmaxf(sm[0], sm[1]), fmaxf(sm[2], sm[3]));
    __syncthreads();
}

// ---------------- absmax via gload_lds streaming (per-wave ring, no barriers) ----------------
// 16KB units: [0,2048)=hid [2048,6144)=wq [6144,7168)=wk [7168,8192)=wv [8192,12288)=wo
__global__ __launch_bounds__(256) void k_absmax5(
    const float* __restrict__ a0, const float* __restrict__ a1,
    const float* __restrict__ a2, const float* __restrict__ a3,
    const float* __restrict__ a4, float* __restrict__ part) {
    __shared__ int8_t SB[4][2][4096];
    int lane = threadIdx.x & 63, w = threadIdx.x >> 6;
    const char* bases[5] = {(const char*)a0, (const char*)a1, (const char*)a2,
                            (const char*)a3, (const char*)a4};
    const int lo[5] = {0, 2048, 6144, 7168, 8192};
    float m[5] = {0.f, 0.f, 0.f, 0.f, 0.f};
    int u0 = blockIdx.x * 12;
    auto tensor_of = [&](int u) {
        return (u < 2048) ? 0 : (u < 6144) ? 1 : (u < 7168) ? 2 : (u < 8192) ? 3 : 4; };
    auto stage = [&](int u, int buf) {
        int t = tensor_of(u);
        const char* s = bases[t] + ((long)(u - lo[t]) << 14) + w * 4096 + lane * 16;
        #pragma unroll
        for (int i = 0; i < 4; i++) gload16(s + i * 1024, &SB[w][buf][i * 1024]);
    };
    stage(u0, 0);
    for (int j = 0; j < 12; j++) {
        if (j < 11) {
            stage(u0 + j + 1, (j + 1) & 1);
            asm volatile("s_waitcnt vmcnt(4)" ::: "memory");
        } else {
            asm volatile("s_waitcnt vmcnt(0)" ::: "memory");
        }
        int t = tensor_of(u0 + j);
        #pragma unroll
        for (int i = 0; i < 4; i++) {
            float4 v = *(const float4*)&SB[w][j & 1][i * 1024 + lane * 16];
            m[t] = fmaxf(m[t],
                fmaxf(fmaxf(fabsf(v.x), fabsf(v.y)), fmaxf(fabsf(v.z), fabsf(v.w))));
        }
    }
    __syncthreads();
    for (int t = 0; t < 5; t++) block_amax_part(m[t], part + t * 1024 + blockIdx.x);
}

// ---------------- reduce partials -> slots 0..4 ----------------
__global__ void k_reduceA(const float* __restrict__ part, unsigned* slots) {
    __shared__ float sm[4];
    int t0 = threadIdx.x, lane = t0 & 63, w = t0 >> 6;
    for (int s = 0; s < 5; s++) {
        float m = 0.f;
        for (int i = t0; i < 1024; i += 256) m = fmaxf(m, part[s * 1024 + i]);
        for (int off = 32; off; off >>= 1) m = fmaxf(m, __shfl_xor(m, off, 64));
        if (lane == 0) sm[w] = m;
        __syncthreads();
        if (t0 == 0)
            slots[s << 5] = __float_as_uint(fmaxf(fmaxf(sm[0], sm[1]), fmaxf(sm[2], sm[3])));
        __syncthreads();
    }
}

// ---------------- reduce partials -> slots 5 (q), 6 (k), 7 (v) ----------------
__global__ void k_reduceB(const float* __restrict__ p1, const float* __restrict__ p2,
                          const float* __restrict__ p3, unsigned* slots) {
    __shared__ float sm[4];
    int t0 = threadIdx.x, lane = t0 & 63, w = t0 >> 6;
    const float* ps[3] = {p1, p2, p3};
    const int cnt[3] = {512, 128, 128};
    const int sl[3] = {5, 6, 7};
    for (int s = 0; s < 3; s++) {
        float m = 0.f;
        for (int i = t0; i < cnt[s]; i += 256) m = fmaxf(m, ps[s][i]);
        for (int off = 32; off; off >>= 1) m = fmaxf(m, __shfl_xor(m, off, 64));
        if (lane == 0) sm[w] = m;
        __syncthreads();
        if (t0 == 0)
            slots[sl[s] << 5] = __float_as_uint(fmaxf(fmaxf(sm[0], sm[1]), fmaxf(sm[2], sm[3])));
        __syncthreads();
    }
}

__device__ __forceinline__ void qstore4(const float* __restrict__ src, long v,
                                        int8_t* __restrict__ dst, float s) {
    float4 x = *(const float4*)(src + v * 4);
    unsigned pa = (unsigned)(uint8_t)(int8_t)q8v(x.x, s)
                | ((unsigned)(uint8_t)(int8_t)q8v(x.y, s) << 8)
                | ((unsigned)(uint8_t)(int8_t)q8v(x.z, s) << 16)
                | ((unsigned)(uint8_t)(int8_t)q8v(x.w, s) << 24);
    *(unsigned*)(dst + v * 4) = pa;
}

#define NV0 ((long)SEQ * HID / 4)
#define NV1 ((long)HID * HID / 4)
#define NV2 ((long)KVDIM * HID / 4)
// ---------------- fused quantize of hid, wq, wk, wv ----------------
__global__ void k_quant4(const float* __restrict__ a0, const float* __restrict__ a1,
                         const float* __restrict__ a2, const float* __restrict__ a3,
                         int8_t* __restrict__ d0, int8_t* __restrict__ d1,
                         int8_t* __restrict__ d2, int8_t* __restrict__ d3,
                         const unsigned* __restrict__ slots) {
    int b = blockIdx.x;
    const float* p; int8_t* d; long n; int slot, lb, nb;
    if (b < 512)       { p = a0; d = d0; n = NV0; slot = 0; lb = b;        nb = 512; }
    else if (b < 1536) { p = a1; d = d1; n = NV1; slot = 1; lb = b - 512;  nb = 1024; }
    else if (b < 1792) { p = a2; d = d2; n = NV2; slot = 2; lb = b - 1536; nb = 256; }
    else               { p = a3; d = d3; n = NV2; slot = 3; lb = b - 1792; nb = 256; }
    float s = slot_scale(slots, slot);
    long str = (long)nb * 256;
    long v = (long)lb * 256 + threadIdx.x;
    for (; v + 3 * str < n; v += 4 * str) {
        #pragma unroll
        for (int j = 0; j < 4; j++) qstore4(p, v + j * str, d, s);
    }
    for (; v < n; v += str) qstore4(p, v, d, s);
}

// ---------------- generic quantize f32 -> int8 (4-deep MLP) ----------------
__global__ void k_quant(const float* __restrict__ x, int8_t* __restrict__ q, long nvec,
                        int rshift, long cmaskv, long ld,
                        const unsigned* __restrict__ slots, int slot) {
    float s = slot_scale(slots, slot);
    long gs = (long)gridDim.x * blockDim.x;
    long v = blockIdx.x * (long)blockDim.x + threadIdx.x;
    for (; v + 3 * gs < nvec; v += 4 * gs) {
        #pragma unroll
        for (int j = 0; j < 4; j++) {
            long vid = v + j * gs;
            long r = vid >> rshift;
            long c = (vid & cmaskv) << 2;
            float4 vv = *(const float4*)(x + r * ld + c);
            unsigned pa = (unsigned)(uint8_t)(int8_t)q8v(vv.x, s)
                        | ((unsigned)(uint8_t)(int8_t)q8v(vv.y, s) << 8)
                        | ((unsigned)(uint8_t)(int8_t)q8v(vv.z, s) << 16)
                        | ((unsigned)(uint8_t)(int8_t)q8v(vv.w, s) << 24);
            *(unsigned*)(q + vid * 4) = pa;
        }
    }
    for (; v < nvec; v += gs) {
        long r = v >> rshift;
        long c = (v & cmaskv) << 2;
        float4 vv = *(const float4*)(x + r * ld + c);
        unsigned pa = (unsigned)(uint8_t)(int8_t)q8v(vv.x, s)
                    | ((unsigned)(uint8_t)(int8_t)q8v(vv.y, s) << 8)
                    | ((unsigned)(uint8_t)(int8_t)q8v(vv.z, s) << 16)
                    | ((unsigned)(uint8_t)(int8_t)q8v(vv.w, s) << 24);
        *(unsigned*)(q + v * 4) = pa;
    }
}

// ---------------- rope cos/sin table ----------------
__global__ void k_ropetab(const int* __restrict__ pos, float* __restrict__ ct,
                          float* __restrict__ st) {
    int tid = blockIdx.x * blockDim.x + threadIdx.x;
    if (tid >= SEQ * 64) return;
    int i = tid & 63, s = tid >> 6;
    double inv = 1.0 / pow(10000.0, (double)((float)(2 * i) * (1.0f / 128.0f)));
    float invf = (float)inv;
    float angf = (float)pos[s] * invf;
    double a = (double)angf;
    ct[tid] = (float)cos(a);
    st[tid] = (float)sin(a);
}

// ---------------- transpose + quantize (V -> V^T int8) ----------------
__global__ void k_transq(const float* __restrict__ src, long lds_, int8_t* __restrict__ dst,
                         long ldd, const unsigned* __restrict__ slots, int slot) {
    __shared__ float t[32][33];
    float s = slot_scale(slots, slot);
    int bx = blockIdx.x, by = blockIdx.y;
    int tid = threadIdx.x;
    int c = tid & 31, r0 = tid >> 5;
    #pragma unroll
    for (int j = 0; j < 4; j++) {
        int r = r0 + j * 8;
        t[r][c] = src[(long)(by * 32 + r) * lds_ + bx * 32 + c];
    }
    __syncthreads();
    int d = tid >> 3, k4 = (tid & 7) * 4;
    unsigned pa = 0;
    #pragma unroll
    for (int j = 0; j < 4; j++) {
        int iv = q8v(t[k4 + j][d], s);
        pa |= ((unsigned)(uint8_t)(int8_t)iv) << (8 * j);
    }
    *(unsigned*)(dst + (long)(bx * 32 + d) * ldd + by * 32 + k4) = pa;
}

// ---------------- int8 GEMM + optional fused RoPE/absmax epilogue ----------------
// ropemode: 0 = plain store; 1 = rope all cols (Q), partial->pQ[blockIdx];
//           2 = KV: bn<8 rope (K)->pK[bm*8+bn], bn>=8 absmax (V)->pV[bm*8+bn-8]
__global__ __launch_bounds__(256) void k_gemm_i8(
    const int8_t* __restrict__ A, const int8_t* __restrict__ B, float* __restrict__ C,
    int M, int N, int K, unsigned* slots,
    int slotA, int slotB, int slotB2, int nsplit,
    float* pQ, float* pK, float* pV, int ropemode,
    const float* __restrict__ ct, const float* __restrict__ st) {
    __shared__ int8_t POOL[65536];
    int8_t (*As)[16384] = (int8_t(*)[16384])POOL;
    int8_t (*Bs)[16384] = (int8_t(*)[16384])(POOL + 32768);
    const v4i vzero = {0, 0, 0, 0};
    int tid = threadIdx.x, lane = tid & 63, wid = tid >> 6;
    int nbx = N >> 7;
    int nwg = gridDim.x, wg = blockIdx.x;
    int cpx = nwg >> 3;
    int swz = (wg & 7) * cpx + (wg >> 3);
    int bm = swz / nbx, bn = swz % nbx;
    long rowA0 = (long)bm * 128, colB0 = (long)bn * 128;
    int wrow = (wid >> 1) * 64, wcol = (wid & 1) * 64;
    int lr = lane >> 3;
    int swc = ((lane & 7) ^ lr) * 16;
    const int8_t* ga = A + (rowA0 + wid * 8 + lr) * (long)K + swc;
    const int8_t* gb = B + (colB0 + wid * 8 + lr) * (long)K + swc;
    v4i acc[4][4];
    #pragma unroll
    for (int m = 0; m < 4; m++)
        #pragma unroll
        for (int n = 0; n < 4; n++) acc[m][n] = vzero;

    auto STAGE = [&](int buf, int kt) {
        #pragma unroll
        for (int i = 0; i < 4; i++) {
            gload16(ga + kt + (long)(i * 32) * K, &As[buf][(wid * 8 + i * 32) * 128]);
            gload16(gb + kt + (long)(i * 32) * K, &Bs[buf][(wid * 8 + i * 32) * 128]);
        }
    };
    auto COMPUTE = [&](int buf) {
        #pragma unroll
        for (int ks = 0; ks < 2; ks++) {
            v4i af[4], bf[4];
            #pragma unroll
            for (int m = 0; m < 4; m++) {
                int row = wrow + m * 16 + (lane & 15);
                af[m] = *(const v4i*)(&As[buf][row * 128 + (((ks * 4 + (lane >> 4)) ^ (row & 7)) * 16)]);
            }
            #pragma unroll
            for (int n = 0; n < 4; n++) {
                int row = wcol + n * 16 + (lane & 15);
                bf[n] = *(const v4i*)(&Bs[buf][row * 128 + (((ks * 4 + (lane >> 4)) ^ (row & 7)) * 16)]);
            }
            #pragma unroll
            for (int m = 0; m < 4; m++)
                #pragma unroll
                for (int n = 0; n < 4; n++)
                    acc[m][n] = __builtin_amdgcn_mfma_i32_16x16x64_i8(af[m], bf[n], acc[m][n], 0, 0, 0);
        }
    };

    STAGE(0, 0);
    VMCNT0;
    __syncthreads();
    int nt = K >> 7, cur = 0;
    for (int t = 0; t < nt - 1; t++) {
        STAGE(cur ^ 1, (t + 1) << 7);
        COMPUTE(cur);
        VMCNT0;
        __syncthreads();
        cur ^= 1;
    }
    COMPUTE(cur);

    float sA = slot_scale(slots, slotA);
    float sB1 = slot_scale(slots, slotB);
    float sB2 = slot_scale(slots, slotB2);
    int qc = lane & 15, rgrp = (lane >> 4) << 2;
    if (ropemode == 1 || (ropemode == 2 && bn < 8)) {
        __syncthreads();                      // As/Bs dead for all waves
        float* EX = (float*)POOL;             // 128x128 f32, XOR-swizzled
        #pragma unroll
        for (int m = 0; m < 4; m++)
            #pragma unroll
            for (int n = 0; n < 4; n++) {
                int coll = wcol + n * 16 + qc;
                #pragma unroll
                for (int r = 0; r < 4; r++) {
                    int rowl = wrow + m * 16 + rgrp + r;
                    EX[rowl * 128 + (coll ^ ((rowl & 1) << 4))] = sA * sB1 * (float)acc[m][n][r];
                }
            }
        __syncthreads();
        float am = 0.f;
        #pragma unroll
        for (int m = 0; m < 4; m++)
            #pragma unroll
            for (int n = 0; n < 4; n++) {
                int coll = wcol + n * 16 + qc;
                #pragma unroll
                for (int r = 0; r < 4; r++) {
                    int rowl = wrow + m * 16 + rgrp + r;
                    long srow = rowA0 + rowl;
                    float self = EX[rowl * 128 + (coll ^ ((rowl & 1) << 4))];
                    float pv = EX[rowl * 128 + ((coll ^ 64) ^ ((rowl & 1) << 4))];
                    float c = ct[srow * 64 + (coll & 63)];
                    float sn = st[srow * 64 + (coll & 63)];
                    float o = (coll < 64) ? self * c - pv * sn : self * c + pv * sn;
                    am = fmaxf(am, fabsf(o));
                    C[srow * N + colB0 + coll] = o;
                }
            }
        block_amax_part(am, (ropemode == 1) ? pQ + blockIdx.x : pK + bm * 8 + (bn & 7));
    } else if (ropemode == 2) {               // V tile: scale + store + absmax
        float am = 0.f;
        #pragma unroll
        for (int m = 0; m < 4; m++) {
            long row0 = rowA0 + wrow + m * 16 + rgrp;
            #pragma unroll
            for (int n = 0; n < 4; n++) {
                int col = (int)colB0 + wcol + n * 16 + qc;
                float sc = sA * ((col < nsplit) ? sB1 : sB2);
                float* cp = C + row0 * N + col;
                #pragma unroll
                for (int r = 0; r < 4; r++) {
                    float val = sc * (float)acc[m][n][r];
                    cp[(long)r * N] = val;
                    am = fmaxf(am, fabsf(val));
                }
            }
        }
        block_amax_part(am, pV + bm * 8 + (bn & 7));
    } else {
        #pragma unroll
        for (int m = 0; m < 4; m++) {
            long row0 = rowA0 + wrow + m * 16 + rgrp;
            #pragma unroll
            for (int n = 0; n < 4; n++) {
                int col = (int)colB0 + wcol + n * 16 + qc;
                float sc = sA * ((col < nsplit) ? sB1 : sB2);
                float* cp = C + row0 * N + col;
                #pragma unroll
                for (int r = 0; r < 4; r++) cp[(long)r * N] = sc * (float)acc[m][n][r];
            }
        }
    }
}

// ---------------- two-pass flash attention: single-buffer K/V, T14 reg-staging ----------------
__global__ __launch_bounds__(256) void k_attn(
    const int8_t* __restrict__ Qq, const int8_t* __restrict__ Kq, const int8_t* __restrict__ Vtq,
    int* __restrict__ AO, unsigned* slots) {
    __shared__ int8_t Qs[64 * 128];   // reused as packed-P store in pass 2
    __shared__ int8_t Ks[64 * 128];
    __shared__ int8_t Vs[128 * 64];
    __shared__ int smx[4];
    const v4i vzero = {0, 0, 0, 0};
    const int NEGS = -(1 << 29);
    int tid = threadIdx.x, lane = tid & 63, w = tid >> 6;
    int qlan = lane & 15, g = lane >> 4;
    int idx = blockIdx.x;
    int qb = 31 - (idx >> 5), h = idx & 31, kvh = h >> 2;   // long blocks first
    float sq = slot_scale(slots, 5), sk = slot_scale(slots, 6);
    float c2 = sq * sk * 0.08838834764831845f * 1.4426950408889634f;
    int lr8 = lane >> 3;
    int swc = ((lane & 7) ^ lr8) * 16;
    int lr4 = lane >> 2;
    int vswc = ((lane & 3) ^ (lr4 & 3)) * 16;
    const int8_t* kbase = Kq + ((long)(w * 8 + lr8)) * KVDIM + kvh * 128 + swc;
    const int8_t* vbase = Vtq + ((long)kvh * 128 + w * 16 + lr4) * SEQ + vswc;
    // LDS lane offsets matching gload16 linear placement
    int kds0 = (w * 8) * 128 + lane * 16,  kds1 = (w * 8 + 32) * 128 + lane * 16;
    int vds0 = (w * 16) * 64 + lane * 16,  vds1 = (w * 16 + 64) * 64 + lane * 16;
    auto STAGE_K_g = [&](int kt) {
        gload16(kbase + ((long)kt * 64) * KVDIM, &Ks[(w * 8) * 128]);
        gload16(kbase + ((long)kt * 64 + 32) * KVDIM, &Ks[(w * 8 + 32) * 128]);
    };
    auto STAGE_V_g = [&](int kt) {
        gload16(vbase + kt * 64, &Vs[(w * 16) * 64]);
        gload16(vbase + (long)64 * SEQ + kt * 64, &Vs[(w * 16 + 64) * 64]);
    };
    {   // Q one-shot + K0
        const int8_t* qbase = Qq + ((long)qb * 64 + w * 8 + lr8) * HID + h * 128 + swc;
        gload16(qbase, &Qs[(w * 8) * 128]);
        gload16(qbase + (long)32 * HID, &Qs[(w * 8 + 32) * 128]);
    }
    STAGE_K_g(0);
    VMCNT0;
    __syncthreads();
    v4i aq[2];
    #pragma unroll
    for (int ks = 0; ks < 2; ks++) {
        int row = w * 16 + qlan;
        aq[ks] = *(const v4i*)(&Qs[row * 128 + (((ks * 4 + g) ^ (row & 7)) * 16)]);
    }
    int mi = -(1 << 30);
    float l = 0.f;
    // ---- pass 1 ----
    for (int kt = 0; kt <= qb; kt++) {
        bool pf = kt < qb;
        v4i kr0, kr1;
        if (pf) {
            kr0 = *(const v4i*)(kbase + ((long)(kt + 1) * 64) * KVDIM);
            kr1 = *(const v4i*)(kbase + ((long)(kt + 1) * 64 + 32) * KVDIM);
        }
        v4i sf[4] = {vzero, vzero, vzero, vzero};
        __builtin_amdgcn_s_setprio(1);
        #pragma unroll
        for (int ks = 0; ks < 2; ks++)
            #pragma unroll
            for (int f = 0; f < 4; f++) {
                int row = f * 16 + qlan;
                v4i bk = *(const v4i*)(&Ks[row * 128 + (((ks * 4 + g) ^ (row & 7)) * 16)]);
                sf[f] = __builtin_amdgcn_mfma_i32_16x16x64_i8(bk, aq[ks], sf[f], 0, 0, 0);
            }
        __builtin_amdgcn_s_setprio(0);
        int sv[16];
        if (kt == qb) {
            int qthr = w * 16 + qlan;
            #pragma unroll
            for (int f = 0; f < 4; f++)
                #pragma unroll
                for (int r = 0; r < 4; r++) {
                    int kl = f * 16 + g * 4 + r;
                    sv[f * 4 + r] = (kl > qthr) ? NEGS : sf[f][r];
                }
        } else {
            #pragma unroll
            for (int f = 0; f < 4; f++)
                #pragma unroll
                for (int r = 0; r < 4; r++) sv[f * 4 + r] = sf[f][r];
        }
        int tm = sv[0];
        #pragma unroll
        for (int e = 1; e < 16; e++) tm = tm > sv[e] ? tm : sv[e];
        tm = max(tm, __shfl_xor(tm, 16, 64));
        tm = max(tm, __shfl_xor(tm, 32, 64));
        int mn = tm > mi ? tm : mi;
        float esc = fexp2(c2 * (float)(mi - mn));
        float es = 0.f;
        #pragma unroll
        for (int e = 0; e < 16; e++) es += fexp2(c2 * (float)(sv[e] - mn));
        es += __shfl_xor(es, 16, 64);
        es += __shfl_xor(es, 32, 64);
        l = l * esc + es;
        mi = mn;
        if (pf) {
            __syncthreads();                      // all waves done reading Ks
            *(v4i*)&Ks[kds0] = kr0;
            *(v4i*)&Ks[kds1] = kr1;
            __syncthreads();                      // Ks[kt+1] ready
        }
    }
    float invl = 127.0f / l;
    // ---- pass 2 ----
    unsigned* Ps32 = (unsigned*)Qs;               // 16 kdw x 20-dword stride per warp
    int pwr = w * 320;
    v4i of[8];
    #pragma unroll
    for (int nf = 0; nf < 8; nf++) of[nf] = vzero;
    __syncthreads();                              // pass1 stragglers done with Ks
    STAGE_K_g(0);
    STAGE_V_g(0);
    VMCNT0;
    __syncthreads();
    for (int kt = 0; kt <= qb; kt++) {
        bool pf = kt < qb;
        v4i kr0, kr1, vr0, vr1;
        if (pf) {
            kr0 = *(const v4i*)(kbase + ((long)(kt + 1) * 64) * KVDIM);
            kr1 = *(const v4i*)(kbase + ((long)(kt + 1) * 64 + 32) * KVDIM);
            vr0 = *(const v4i*)(vbase + (kt + 1) * 64);
            vr1 = *(const v4i*)(vbase + (long)64 * SEQ + (kt + 1) * 64);
        }
        v4i sf[4] = {vzero, vzero, vzero, vzero};
        __builtin_amdgcn_s_setprio(1);
        #pragma unroll
        for (int ks = 0; ks < 2; ks++)
            #pragma unroll
            for (int f = 0; f < 4; f++) {
                int row = f * 16 + qlan;
                v4i bk = *(const v4i*)(&Ks[row * 128 + (((ks * 4 + g) ^ (row & 7)) * 16)]);
                sf[f] = __builtin_amdgcn_mfma_i32_16x16x64_i8(bk, aq[ks], sf[f], 0, 0, 0);
            }
        __builtin_amdgcn_s_setprio(0);
        if (kt == qb) {
            int qthr = w * 16 + qlan;
            #pragma unroll
            for (int f = 0; f < 4; f++) {
                unsigned pk = 0;
                #pragma unroll
                for (int r = 0; r < 4; r++) {
                    int kl = f * 16 + g * 4 + r;
                    int s = (kl > qthr) ? NEGS : sf[f][r];
                    float t = fexp2(c2 * (float)(s - mi));
                    int pq = (int)rintf(t * invl);
                    pk |= ((unsigned)pq) << (8 * r);
                }
                Ps32[pwr + (4 * f + g) * 20 + qlan] = pk;
            }
        } else {
            #pragma unroll
            for (int f = 0; f < 4; f++) {
                unsigned pk = 0;
                #pragma unroll
                for (int r = 0; r < 4; r++) {
                    float t = fexp2(c2 * (float)(sf[f][r] - mi));
                    int pq = (int)rintf(t * invl);
                    pk |= ((unsigned)pq) << (8 * r);
                }
                Ps32[pwr + (4 * f + g) * 20 + qlan] = pk;
            }
        }
        int rb = pwr + 80 * g + qlan;
        v4i ap;
        ap[0] = (int)Ps32[rb];
        ap[1] = (int)Ps32[rb + 20];
        ap[2] = (int)Ps32[rb + 40];
        ap[3] = (int)Ps32[rb + 60];
        __builtin_amdgcn_s_setprio(1);
        #pragma unroll
        for (int nf = 0; nf < 8; nf++) {
            int row = nf * 16 + qlan;
            v4i bv = *(const v4i*)(&Vs[row * 64 + ((g ^ (row & 3)) * 16)]);
            of[nf] = __builtin_amdgcn_mfma_i32_16x16x64_i8(ap, bv, of[nf], 0, 0, 0);
        }
        __builtin_amdgcn_s_setprio(0);
        if (pf) {
            __syncthreads();
            *(v4i*)&Ks[kds0] = kr0;
            *(v4i*)&Ks[kds1] = kr1;
            *(v4i*)&Vs[vds0] = vr0;
            *(v4i*)&Vs[vds1] = vr1;
            __syncthreads();
        }
    }
    int mymax = 0;
    #pragma unroll
    for (int nf = 0; nf < 8; nf++)
        #pragma unroll
        for (int r = 0; r < 4; r++) {
            int val = of[nf][r];
            int av = val < 0 ? -val : val;
            mymax = av > mymax ? av : mymax;
            int qg = qb * 64 + w * 16 + 4 * g + r;
            AO[(long)qg * HID + h * 128 + nf * 16 + qlan] = val;
        }
    #pragma unroll
    for (int off = 1; off < 64; off <<= 1) {
        int o2 = __shfl_xor(mymax, off, 64);
        mymax = o2 > mymax ? o2 : mymax;
    }
    if (lane == 0) smx[w] = mymax;
    __syncthreads();
    if (tid == 0) {
        int mm = max(max(smx[0], smx[1]), max(smx[2], smx[3]));
        atomicMax(slots + (8 << 5), (unsigned)mm);   // staggered retirement
    }
}

// ---------------- quantize attn_out (int32 -> int8, 4-deep MLP) ----------------
__global__ void k_quant_ao(const int* __restrict__ a, int8_t* __restrict__ q, unsigned* slots) {
    float sv = slot_scale(slots, 7);
    float spv = (1.0f / 127.0f) * sv;
    float amax = spv * (float)(int)slots[8 << 5];
    float s = fmaxf(amax / 127.0f, 1e-8f);
    long nvec = (long)SEQ * HID / 4;
    long gs = (long)gridDim.x * blockDim.x;
    long v = blockIdx.x * (long)blockDim.x + threadIdx.x;
    for (; v + 3 * gs < nvec; v += 4 * gs) {
        #pragma unroll
        for (int j = 0; j < 4; j++) {
            long vid = v + j * gs;
            int4 x = *(const int4*)(a + vid * 4);
            int a0 = q8v(spv * (float)x.x, s);
            int a1 = q8v(spv * (float)x.y, s);
            int a2 = q8v(spv * (float)x.z, s);
            int a3 = q8v(spv * (float)x.w, s);
            unsigned pa = (unsigned)(uint8_t)(int8_t)a0
                        | ((unsigned)(uint8_t)(int8_t)a1 << 8)
                        | ((unsigned)(uint8_t)(int8_t)a2 << 16)
                        | ((unsigned)(uint8_t)(int8_t)a3 << 24);
            *(unsigned*)(q + vid * 4) = pa;
        }
    }
    for (; v < nvec; v += gs) {
        int4 x = *(const int4*)(a + v * 4);
        int a0 = q8v(spv * (float)x.x, s);
        int a1 = q8v(spv * (float)x.y, s);
        int a2 = q8v(spv * (float)x.z, s);
        int a3 = q8v(spv * (float)x.w, s);
        unsigned pa = (unsigned)(uint8_t)(int8_t)a0
                    | ((unsigned)(uint8_t)(int8_t)a1 << 8)
                    | ((unsigned)(uint8_t)(int8_t)a2 << 16)
                    | ((unsigned)(uint8_t)(int8_t)a3 << 24);
        *(unsigned*)(q + v * 4) = pa;
    }
    if (blockIdx.x == 0 && threadIdx.x == 0) slots[9 << 5] = __float_as_uint(amax);
}

extern "C" void kernel_launch(void* const* d_in, const int* in_sizes, int n_in,
                              void* d_out, int out_size, void* d_ws, size_t ws_size,
                              hipStream_t stream) {
    (void)in_sizes; (void)n_in; (void)out_size;
    const float* hid = (const float*)d_in[0];
    const int* pos = (const int*)d_in[2];
    const float* wqp = (const float*)d_in[3];
    const float* wkp = (const float*)d_in[4];
    const float* wvp = (const float*)d_in[5];
    const float* wop = (const float*)d_in[6];
    float* out = (float*)d_out;
    char* ws = (char*)d_ws;

    size_t o = 0;
    auto alloc = [&](size_t sz) { size_t r = o; o += (sz + 255) & ~(size_t)255; return r; };
    unsigned* slots = (unsigned*)(ws + alloc(2048));
    float* P0 = (float*)(ws + alloc(5 * 1024 * 4));  // absmax5 partials (per tensor x block)
    float* P1 = (float*)(ws + alloc(512 * 4));       // gemm1 Q-rope partials
    float* P2 = (float*)(ws + alloc(128 * 4));       // gemm2 K-rope partials
    float* P3 = (float*)(ws + alloc(128 * 4));       // gemm2 V partials
    int8_t* Xq   = (int8_t*)(ws + alloc((size_t)SEQ * HID));      // later reused as AOq
    int8_t* Wqq  = (int8_t*)(ws + alloc((size_t)HID * HID));      // later reused as Woq
    int8_t* Wkvq = (int8_t*)(ws + alloc((size_t)KVCAT * HID));
    float*  Qf   = (float*)(ws + alloc((size_t)SEQ * HID * 4));   // later reused as AOint
    float*  KVf  = (float*)(ws + alloc((size_t)SEQ * KVCAT * 4));
    int8_t* Qq   = (int8_t*)(ws + alloc((size_t)SEQ * HID));
    int8_t* Kq   = (int8_t*)(ws + alloc((size_t)SEQ * KVDIM));
    int8_t* Vtq  = (int8_t*)(ws + alloc((size_t)KVDIM * SEQ));
    float*  ctab = (float*)(ws + alloc((size_t)SEQ * 64 * 4));
    float*  stab = (float*)(ws + alloc((size_t)SEQ * 64 * 4));
    if (ws_size < o) return;
    int8_t* Woq = Wqq;
    int*    AOint = (int*)Qf;
    int8_t* AOq = Xq;

    hipMemsetAsync(slots, 0, 2048, stream);
    k_ropetab<<<SEQ * 64 / 256, 256, 0, stream>>>(pos, ctab, stab);
    k_absmax5<<<1024, 256, 0, stream>>>(hid, wqp, wkp, wvp, wop, P0);
    k_reduceA<<<1, 256, 0, stream>>>(P0, slots);
    k_quant4<<<2048, 256, 0, stream>>>(hid, wqp, wkp, wvp,
                                       Xq, Wqq, Wkvq, Wkvq + (size_t)KVDIM * HID, slots);
    k_gemm_i8<<<512, 256, 0, stream>>>(Xq, Wqq, Qf, SEQ, HID, HID, slots,
                                       0, 1, 1, 1 << 30, P1, nullptr, nullptr, 1, ctab, stab);
    k_gemm_i8<<<256, 256, 0, stream>>>(Xq, Wkvq, KVf, SEQ, KVCAT, HID, slots,
                                       0, 2, 3, KVDIM, nullptr, P2, P3, 2, ctab, stab);
    const long CALL = 0x3FFFFFFFL;
    k_quant<<<2048, 256, 0, stream>>>(wop, Woq, (long)HID * HID / 4, 40, CALL, 0, slots, 4);
    k_reduceB<<<1, 256, 0, stream>>>(P1, P2, P3, slots);
    k_quant<<<2048, 256, 0, stream>>>(Qf, Qq, (long)SEQ * HID / 4, 40, CALL, 0, slots, 5);
    k_quant<<<512, 256, 0, stream>>>(KVf, Kq, (long)SEQ * KVDIM / 4, 8, 255, KVCAT, slots, 6);
    k_transq<<<dim3(32, 64), 256, 0, stream>>>(KVf + KVDIM, KVCAT, Vtq, SEQ, slots, 7);
    k_attn<<<1024, 256, 0, stream>>>(Qq, Kq, Vtq, AOint, slots);
    k_quant_ao<<<2048, 256, 0, stream>>>(AOint, AOq, slots);
    k_gemm_i8<<<512, 256, 0, stream>>>(AOq, Woq, out, SEQ, HID, HID, slots,
                                       9, 4, 4, 1 << 30, nullptr, nullptr, nullptr, 0,
                                       nullptr, nullptr);
}

// Round 8
// 309.832 us; speedup vs baseline: 1.0640x; 1.0006x over previous
//
#include <hip/hip_runtime.h>
#include <stdint.h>

#define SEQ   2048
#define HID   4096
#define NH    32
#define NKV   8
#define KVDIM 1024   // NKV*HD
#define KVCAT 2048   // KVDIM*2

typedef int v4i __attribute__((ext_vector_type(4)));

#define VMCNT0 asm volatile("s_waitcnt vmcnt(0)" ::: "memory")

// async global->LDS 16B: per-lane global source, wave-uniform LDS base + lane*16
__device__ __forceinline__ void gload16(const void* g, void* l) {
    __builtin_amdgcn_global_load_lds(
        (const __attribute__((address_space(1))) void*)(uintptr_t)g,
        (__attribute__((address_space(3))) void*)(uintptr_t)l, 16, 0, 0);
}

__device__ __forceinline__ float slot_scale(const unsigned* slots, int slot) {
    return fmaxf(__uint_as_float(slots[slot << 5]) / 127.0f, 1e-8f);
}

__device__ __forceinline__ int q8v(float x, float s) {
    int v = (int)rintf(x / s);
    return v < -127 ? -127 : (v > 127 ? 127 : v);
}

__device__ __forceinline__ float fexp2(float x) {
    float r; asm("v_exp_f32 %0, %1" : "=v"(r) : "v"(x)); return r;
}

__device__ __forceinline__ float amax4(const float* __restrict__ p, long v) {
    float4 x = *(const float4*)(p + v * 4);
    return fmaxf(fmaxf(fabsf(x.x), fabsf(x.y)), fmaxf(fabsf(x.z), fabsf(x.w)));
}

// block-level reduce (4 waves), ONE plain store (no atomic contention)
__device__ __forceinline__ void block_amax_part(float m, float* dst) {
    __shared__ float sm[4];
    int lane = threadIdx.x & 63, w = threadIdx.x >> 6;
    for (int off = 32; off; off >>= 1) m = fmaxf(m, __shfl_xor(m, off, 64));
    if (lane == 0) sm[w] = m;
    __syncthreads();
    if (threadIdx.x == 0)
        *dst = fmaxf(fmaxf(sm[0], sm[1]), fmaxf(sm[2], sm[3]));
    __syncthreads();
}

// 8-wave variant (512-thread blocks)
__device__ __forceinline__ void block_amax_part8(float m, float* dst) {
    __shared__ float sm8[8];
    int lane = threadIdx.x & 63, w = threadIdx.x >> 6;
    for (int off = 32; off; off >>= 1) m = fmaxf(m, __shfl_xor(m, off, 64));
    if (lane == 0) sm8[w] = m;
    __syncthreads();
    if (threadIdx.x == 0) {
        float r = sm8[0];
        #pragma unroll
        for (int i = 1; i < 8; i++) r = fmaxf(r, sm8[i]);
        *dst = r;
    }
    __syncthreads();
}

// ---------------- fused absmax: blocks partitioned per tensor, 8-deep MLP ----------------
#define NV0 ((long)SEQ * HID / 4)     // 2M vecs
#define NV1 ((long)HID * HID / 4)     // 4M vecs
#define NV2 ((long)KVDIM * HID / 4)   // 1M vecs
__global__ void k_absmax5(const float* __restrict__ a0, const float* __restrict__ a1,
                          const float* __restrict__ a2, const float* __restrict__ a3,
                          const float* __restrict__ a4, float* __restrict__ part) {
    int b = blockIdx.x;
    const float* p; long n; int lb, nb;
    if (b < 342)       { p = a0; n = NV0; lb = b;        nb = 342; }
    else if (b < 1025) { p = a1; n = NV1; lb = b - 342;  nb = 683; }
    else if (b < 1196) { p = a2; n = NV2; lb = b - 1025; nb = 171; }
    else if (b < 1367) { p = a3; n = NV2; lb = b - 1196; nb = 171; }
    else               { p = a4; n = NV1; lb = b - 1367; nb = 681; }
    long str = (long)nb * 256;
    float mm[8] = {0.f, 0.f, 0.f, 0.f, 0.f, 0.f, 0.f, 0.f};
    long v = (long)lb * 256 + threadIdx.x;
    for (; v + 7 * str < n; v += 8 * str) {
        #pragma unroll
        for (int j = 0; j < 8; j++) mm[j] = fmaxf(mm[j], amax4(p, v + j * str));
    }
    for (; v < n; v += str) mm[0] = fmaxf(mm[0], amax4(p, v));
    float m = fmaxf(fmaxf(fmaxf(mm[0], mm[1]), fmaxf(mm[2], mm[3])),
                    fmaxf(fmaxf(mm[4], mm[5]), fmaxf(mm[6], mm[7])));
    block_amax_part(m, part + blockIdx.x);
}

// ---------------- reduce partials -> slots 0..4 ----------------
__global__ void k_reduceA(const float* __restrict__ part, unsigned* slots) {
    __shared__ float sm[4];
    const int lo[5] = {0, 342, 1025, 1196, 1367};
    const int hi[5] = {342, 1025, 1196, 1367, 2048};
    int t = threadIdx.x, lane = t & 63, w = t >> 6;
    for (int s = 0; s < 5; s++) {
        float m = 0.f;
        for (int i = lo[s] + t; i < hi[s]; i += 256) m = fmaxf(m, part[i]);
        for (int off = 32; off; off >>= 1) m = fmaxf(m, __shfl_xor(m, off, 64));
        if (lane == 0) sm[w] = m;
        __syncthreads();
        if (t == 0)
            slots[s << 5] = __float_as_uint(fmaxf(fmaxf(sm[0], sm[1]), fmaxf(sm[2], sm[3])));
        __syncthreads();
    }
}

// ---------------- reduce partials -> slots 5 (q), 6 (k), 7 (v) ----------------
__global__ void k_reduceB(const float* __restrict__ p1, const float* __restrict__ p2,
                          const float* __restrict__ p3, unsigned* slots) {
    __shared__ float sm[4];
    int t = threadIdx.x, lane = t & 63, w = t >> 6;
    const float* ps[3] = {p1, p2, p3};
    const int cnt[3] = {256, 128, 128};
    const int sl[3] = {5, 6, 7};
    for (int s = 0; s < 3; s++) {
        float m = 0.f;
        for (int i = t; i < cnt[s]; i += 256) m = fmaxf(m, ps[s][i]);
        for (int off = 32; off; off >>= 1) m = fmaxf(m, __shfl_xor(m, off, 64));
        if (lane == 0) sm[w] = m;
        __syncthreads();
        if (t == 0)
            slots[sl[s] << 5] = __float_as_uint(fmaxf(fmaxf(sm[0], sm[1]), fmaxf(sm[2], sm[3])));
        __syncthreads();
    }
}

__device__ __forceinline__ void qstore4(const float* __restrict__ src, long v,
                                        int8_t* __restrict__ dst, float s) {
    float4 x = *(const float4*)(src + v * 4);
    unsigned pa = (unsigned)(uint8_t)(int8_t)q8v(x.x, s)
                | ((unsigned)(uint8_t)(int8_t)q8v(x.y, s) << 8)
                | ((unsigned)(uint8_t)(int8_t)q8v(x.z, s) << 16)
                | ((unsigned)(uint8_t)(int8_t)q8v(x.w, s) << 24);
    *(unsigned*)(dst + v * 4) = pa;
}

// ---------------- fused quantize of hid, wq, wk, wv ----------------
__global__ void k_quant4(const float* __restrict__ a0, const float* __restrict__ a1,
                         const float* __restrict__ a2, const float* __restrict__ a3,
                         int8_t* __restrict__ d0, int8_t* __restrict__ d1,
                         int8_t* __restrict__ d2, int8_t* __restrict__ d3,
                         const unsigned* __restrict__ slots) {
    int b = blockIdx.x;
    const float* p; int8_t* d; long n; int slot, lb, nb;
    if (b < 512)       { p = a0; d = d0; n = NV0; slot = 0; lb = b;        nb = 512; }
    else if (b < 1536) { p = a1; d = d1; n = NV1; slot = 1; lb = b - 512;  nb = 1024; }
    else if (b < 1792) { p = a2; d = d2; n = NV2; slot = 2; lb = b - 1536; nb = 256; }
    else               { p = a3; d = d3; n = NV2; slot = 3; lb = b - 1792; nb = 256; }
    float s = slot_scale(slots, slot);
    long str = (long)nb * 256;
    long v = (long)lb * 256 + threadIdx.x;
    for (; v + 3 * str < n; v += 4 * str) {
        #pragma unroll
        for (int j = 0; j < 4; j++) qstore4(p, v + j * str, d, s);
    }
    for (; v < n; v += str) qstore4(p, v, d, s);
}

// ---------------- generic quantize f32 -> int8 (4-deep MLP) ----------------
__global__ void k_quant(const float* __restrict__ x, int8_t* __restrict__ q, long nvec,
                        int rshift, long cmaskv, long ld,
                        const unsigned* __restrict__ slots, int slot) {
    float s = slot_scale(slots, slot);
    long gs = (long)gridDim.x * blockDim.x;
    long v = blockIdx.x * (long)blockDim.x + threadIdx.x;
    for (; v + 3 * gs < nvec; v += 4 * gs) {
        #pragma unroll
        for (int j = 0; j < 4; j++) {
            long vid = v + j * gs;
            long r = vid >> rshift;
            long c = (vid & cmaskv) << 2;
            float4 vv = *(const float4*)(x + r * ld + c);
            unsigned pa = (unsigned)(uint8_t)(int8_t)q8v(vv.x, s)
                        | ((unsigned)(uint8_t)(int8_t)q8v(vv.y, s) << 8)
                        | ((unsigned)(uint8_t)(int8_t)q8v(vv.z, s) << 16)
                        | ((unsigned)(uint8_t)(int8_t)q8v(vv.w, s) << 24);
            *(unsigned*)(q + vid * 4) = pa;
        }
    }
    for (; v < nvec; v += gs) {
        long r = v >> rshift;
        long c = (v & cmaskv) << 2;
        float4 vv = *(const float4*)(x + r * ld + c);
        unsigned pa = (unsigned)(uint8_t)(int8_t)q8v(vv.x, s)
                    | ((unsigned)(uint8_t)(int8_t)q8v(vv.y, s) << 8)
                    | ((unsigned)(uint8_t)(int8_t)q8v(vv.z, s) << 16)
                    | ((unsigned)(uint8_t)(int8_t)q8v(vv.w, s) << 24);
        *(unsigned*)(q + v * 4) = pa;
    }
}

// ---------------- rope cos/sin table ----------------
__global__ void k_ropetab(const int* __restrict__ pos, float* __restrict__ ct,
                          float* __restrict__ st) {
    int tid = blockIdx.x * blockDim.x + threadIdx.x;
    if (tid >= SEQ * 64) return;
    int i = tid & 63, s = tid >> 6;
    double inv = 1.0 / pow(10000.0, (double)((float)(2 * i) * (1.0f / 128.0f)));
    float invf = (float)inv;
    float angf = (float)pos[s] * invf;
    double a = (double)angf;
    ct[tid] = (float)cos(a);
    st[tid] = (float)sin(a);
}

// ---------------- transpose + quantize (V -> V^T int8) ----------------
__global__ void k_transq(const float* __restrict__ src, long lds_, int8_t* __restrict__ dst,
                         long ldd, const unsigned* __restrict__ slots, int slot) {
    __shared__ float t[32][33];
    float s = slot_scale(slots, slot);
    int bx = blockIdx.x, by = blockIdx.y;
    int tid = threadIdx.x;
    int c = tid & 31, r0 = tid >> 5;
    #pragma unroll
    for (int j = 0; j < 4; j++) {
        int r = r0 + j * 8;
        t[r][c] = src[(long)(by * 32 + r) * lds_ + bx * 32 + c];
    }
    __syncthreads();
    int d = tid >> 3, k4 = (tid & 7) * 4;
    unsigned pa = 0;
    #pragma unroll
    for (int j = 0; j < 4; j++) {
        int iv = q8v(t[k4 + j][d], s);
        pa |= ((unsigned)(uint8_t)(int8_t)iv) << (8 * j);
    }
    *(unsigned*)(dst + (long)(bx * 32 + d) * ldd + by * 32 + k4) = pa;
}

// ---------------- int8 GEMM 128x128 (gemm2/KV): mode2 = K-rope / V-absmax epilogue --------
__global__ __launch_bounds__(256) void k_gemm_i8(
    const int8_t* __restrict__ A, const int8_t* __restrict__ B, float* __restrict__ C,
    int M, int N, int K, unsigned* slots,
    int slotA, int slotB, int slotB2, int nsplit,
    float* pK, float* pV,
    const float* __restrict__ ct, const float* __restrict__ st) {
    __shared__ int8_t POOL[65536];
    int8_t (*As)[16384] = (int8_t(*)[16384])POOL;
    int8_t (*Bs)[16384] = (int8_t(*)[16384])(POOL + 32768);
    const v4i vzero = {0, 0, 0, 0};
    int tid = threadIdx.x, lane = tid & 63, wid = tid >> 6;
    int nbx = N >> 7;
    int nwg = gridDim.x, wg = blockIdx.x;
    int cpx = nwg >> 3;
    int swz = (wg & 7) * cpx + (wg >> 3);
    int bm = swz / nbx, bn = swz % nbx;
    long rowA0 = (long)bm * 128, colB0 = (long)bn * 128;
    int wrow = (wid >> 1) * 64, wcol = (wid & 1) * 64;
    int lr = lane >> 3;
    int swc = ((lane & 7) ^ lr) * 16;
    const int8_t* ga = A + (rowA0 + wid * 8 + lr) * (long)K + swc;
    const int8_t* gb = B + (colB0 + wid * 8 + lr) * (long)K + swc;
    v4i acc[4][4];
    #pragma unroll
    for (int m = 0; m < 4; m++)
        #pragma unroll
        for (int n = 0; n < 4; n++) acc[m][n] = vzero;

    auto STAGE = [&](int buf, int kt) {
        #pragma unroll
        for (int i = 0; i < 4; i++) {
            gload16(ga + kt + (long)(i * 32) * K, &As[buf][(wid * 8 + i * 32) * 128]);
            gload16(gb + kt + (long)(i * 32) * K, &Bs[buf][(wid * 8 + i * 32) * 128]);
        }
    };
    auto COMPUTE = [&](int buf) {
        #pragma unroll
        for (int ks = 0; ks < 2; ks++) {
            v4i af[4], bf[4];
            #pragma unroll
            for (int m = 0; m < 4; m++) {
                int row = wrow + m * 16 + (lane & 15);
                af[m] = *(const v4i*)(&As[buf][row * 128 + (((ks * 4 + (lane >> 4)) ^ (row & 7)) * 16)]);
            }
            #pragma unroll
            for (int n = 0; n < 4; n++) {
                int row = wcol + n * 16 + (lane & 15);
                bf[n] = *(const v4i*)(&Bs[buf][row * 128 + (((ks * 4 + (lane >> 4)) ^ (row & 7)) * 16)]);
            }
            #pragma unroll
            for (int m = 0; m < 4; m++)
                #pragma unroll
                for (int n = 0; n < 4; n++)
                    acc[m][n] = __builtin_amdgcn_mfma_i32_16x16x64_i8(af[m], bf[n], acc[m][n], 0, 0, 0);
        }
    };

    STAGE(0, 0);
    VMCNT0;
    __syncthreads();
    int nt = K >> 7, cur = 0;
    for (int t = 0; t < nt - 1; t++) {
        STAGE(cur ^ 1, (t + 1) << 7);
        COMPUTE(cur);
        VMCNT0;
        __syncthreads();
        cur ^= 1;
    }
    COMPUTE(cur);

    float sA = slot_scale(slots, slotA);
    float sB1 = slot_scale(slots, slotB);
    float sB2 = slot_scale(slots, slotB2);
    int qc = lane & 15, rgrp = (lane >> 4) << 2;
    if (bn < 8) {                              // K half: rope epilogue
        __syncthreads();
        float* EX = (float*)POOL;              // 128x128 f32
        #pragma unroll
        for (int m = 0; m < 4; m++)
            #pragma unroll
            for (int n = 0; n < 4; n++) {
                int coll = wcol + n * 16 + qc;
                #pragma unroll
                for (int r = 0; r < 4; r++) {
                    int rowl = wrow + m * 16 + rgrp + r;
                    EX[rowl * 128 + (coll ^ ((rowl & 1) << 4))] = sA * sB1 * (float)acc[m][n][r];
                }
            }
        __syncthreads();
        float am = 0.f;
        #pragma unroll
        for (int m = 0; m < 4; m++)
            #pragma unroll
            for (int n = 0; n < 4; n++) {
                int coll = wcol + n * 16 + qc;
                #pragma unroll
                for (int r = 0; r < 4; r++) {
                    int rowl = wrow + m * 16 + rgrp + r;
                    long srow = rowA0 + rowl;
                    float self = EX[rowl * 128 + (coll ^ ((rowl & 1) << 4))];
                    float pv = EX[rowl * 128 + ((coll ^ 64) ^ ((rowl & 1) << 4))];
                    float c = ct[srow * 64 + (coll & 63)];
                    float sn = st[srow * 64 + (coll & 63)];
                    float o = (coll < 64) ? self * c - pv * sn : self * c + pv * sn;
                    am = fmaxf(am, fabsf(o));
                    C[srow * N + colB0 + coll] = o;
                }
            }
        block_amax_part(am, pK + bm * 8 + (bn & 7));
    } else {                                   // V half: scale + store + absmax
        float am = 0.f;
        #pragma unroll
        for (int m = 0; m < 4; m++) {
            long row0 = rowA0 + wrow + m * 16 + rgrp;
            #pragma unroll
            for (int n = 0; n < 4; n++) {
                int col = (int)colB0 + wcol + n * 16 + qc;
                float sc = sA * ((col < nsplit) ? sB1 : sB2);
                float* cp = C + row0 * N + col;
                #pragma unroll
                for (int r = 0; r < 4; r++) {
                    float val = sc * (float)acc[m][n][r];
                    cp[(long)r * N] = val;
                    am = fmaxf(am, fabsf(val));
                }
            }
        }
        block_amax_part(am, pV + bm * 8 + (bn & 7));
    }
}

// ---------------- int8 GEMM 256x128 tile, 512 threads (gemm1 Q+rope / gemm3 out) -------
__global__ __launch_bounds__(512) void k_gemm_big(
    const int8_t* __restrict__ A, const int8_t* __restrict__ B, float* __restrict__ C,
    int N, int K, unsigned* slots, int slotA, int slotB,
    float* pQ, int do_rope,
    const float* __restrict__ ct, const float* __restrict__ st) {
    __shared__ int8_t POOL[98304];             // As 2x32K + Bs 2x16K
    int8_t (*As)[32768] = (int8_t(*)[32768])POOL;
    int8_t (*Bs)[16384] = (int8_t(*)[16384])(POOL + 65536);
    const v4i vzero = {0, 0, 0, 0};
    int tid = threadIdx.x, lane = tid & 63, wid = tid >> 6;
    int nbx = N >> 7;
    int nwg = gridDim.x, wg = blockIdx.x;
    int cpx = nwg >> 3;
    int swz = (wg & 7) * cpx + (wg >> 3);
    int bm = swz / nbx, bn = swz % nbx;
    long rowA0 = (long)bm * 256, colB0 = (long)bn * 128;
    int wrow = (wid >> 1) * 64, wcol = (wid & 1) * 64;   // wrow 0..192, wcol 0/64
    int lr = lane >> 3;
    int swc = ((lane & 7) ^ lr) * 16;
    const int8_t* ga = A + (rowA0 + wid * 8 + lr) * (long)K + swc;
    const int8_t* gb = B + (colB0 + wid * 8 + lr) * (long)K + swc;
    v4i acc[4][4];
    #pragma unroll
    for (int m = 0; m < 4; m++)
        #pragma unroll
        for (int n = 0; n < 4; n++) acc[m][n] = vzero;

    auto STAGE = [&](int buf, int kt) {
        #pragma unroll
        for (int i = 0; i < 4; i++)
            gload16(ga + kt + (long)(i * 64) * K, &As[buf][(wid * 8 + i * 64) * 128]);
        #pragma unroll
        for (int i = 0; i < 2; i++)
            gload16(gb + kt + (long)(i * 64) * K, &Bs[buf][(wid * 8 + i * 64) * 128]);
    };
    auto COMPUTE = [&](int buf) {
        #pragma unroll
        for (int ks = 0; ks < 2; ks++) {
            v4i af[4], bf[4];
            #pragma unroll
            for (int m = 0; m < 4; m++) {
                int row = wrow + m * 16 + (lane & 15);
                af[m] = *(const v4i*)(&As[buf][row * 128 + (((ks * 4 + (lane >> 4)) ^ (row & 7)) * 16)]);
            }
            #pragma unroll
            for (int n = 0; n < 4; n++) {
                int row = wcol + n * 16 + (lane & 15);
                bf[n] = *(const v4i*)(&Bs[buf][row * 128 + (((ks * 4 + (lane >> 4)) ^ (row & 7)) * 16)]);
            }
            #pragma unroll
            for (int m = 0; m < 4; m++)
                #pragma unroll
                for (int n = 0; n < 4; n++)
                    acc[m][n] = __builtin_amdgcn_mfma_i32_16x16x64_i8(af[m], bf[n], acc[m][n], 0, 0, 0);
        }
    };

    STAGE(0, 0);
    VMCNT0;
    __syncthreads();
    int nt = K >> 7, cur = 0;
    for (int t = 0; t < nt - 1; t++) {
        STAGE(cur ^ 1, (t + 1) << 7);
        COMPUTE(cur);
        VMCNT0;
        __syncthreads();
        cur ^= 1;
    }
    COMPUTE(cur);

    float sA = slot_scale(slots, slotA);
    float sB1 = slot_scale(slots, slotB);
    int qc = lane & 15, rgrp = (lane >> 4) << 2;
    if (do_rope) {
        float am = 0.f;
        float* EX = (float*)POOL;              // 128x128 f32, used in two halves
        __syncthreads();
        #pragma unroll
        for (int half = 0; half < 2; half++) {
            if ((wid >> 2) == half) {
                #pragma unroll
                for (int m = 0; m < 4; m++)
                    #pragma unroll
                    for (int n = 0; n < 4; n++) {
                        int coll = wcol + n * 16 + qc;
                        #pragma unroll
                        for (int r = 0; r < 4; r++) {
                            int exr = wrow + m * 16 + rgrp + r - half * 128;
                            EX[exr * 128 + (coll ^ (((exr >> 2) & 3) << 4))] =
                                sA * sB1 * (float)acc[m][n][r];
                        }
                    }
            }
            __syncthreads();
            if ((wid >> 2) == half) {
                #pragma unroll
                for (int m = 0; m < 4; m++)
                    #pragma unroll
                    for (int n = 0; n < 4; n++) {
                        int coll = wcol + n * 16 + qc;
                        #pragma unroll
                        for (int r = 0; r < 4; r++) {
                            int exr = wrow + m * 16 + rgrp + r - half * 128;
                            int xm = ((exr >> 2) & 3) << 4;
                            float self = EX[exr * 128 + (coll ^ xm)];
                            float pv = EX[exr * 128 + ((coll ^ 64) ^ xm)];
                            long srow = rowA0 + half * 128 + exr;
                            float c = ct[srow * 64 + (coll & 63)];
                            float sn = st[srow * 64 + (coll & 63)];
                            float o = (coll < 64) ? self * c - pv * sn : self * c + pv * sn;
                            am = fmaxf(am, fabsf(o));
                            C[srow * N + colB0 + coll] = o;
                        }
                    }
            }
            __syncthreads();
        }
        block_amax_part8(am, pQ + blockIdx.x);
    } else {
        #pragma unroll
        for (int m = 0; m < 4; m++) {
            long row0 = rowA0 + wrow + m * 16 + rgrp;
            #pragma unroll
            for (int n = 0; n < 4; n++) {
                int col = (int)colB0 + wcol + n * 16 + qc;
                float* cp = C + row0 * N + col;
                #pragma unroll
                for (int r = 0; r < 4; r++) cp[(long)r * N] = sA * sB1 * (float)acc[m][n][r];
            }
        }
    }
}

// ---------------- two-pass flash attention (dbuf gload, fused-exp softmax) ----------------
__global__ __launch_bounds__(256) void k_attn(
    const int8_t* __restrict__ Qq, const int8_t* __restrict__ Kq, const int8_t* __restrict__ Vtq,
    int* __restrict__ AO, unsigned* slots) {
    __shared__ int8_t Qs[64 * 128];   // reused as packed-P store in pass 2
    __shared__ int8_t Ks[2][64 * 128];
    __shared__ int8_t Vs[2][128 * 64];
    __shared__ int smx[4];
    const v4i vzero = {0, 0, 0, 0};
    const int NEGS = -(1 << 29);
    const float MAGIC = 12582912.0f;  // 1.5*2^23, RNE rounding
    int tid = threadIdx.x, lane = tid & 63, w = tid >> 6;
    int qlan = lane & 15, g = lane >> 4;
    int idx = blockIdx.x;
    int qb = 31 - (idx >> 5), h = idx & 31, kvh = h >> 2;   // long blocks first
    float sq = slot_scale(slots, 5), sk = slot_scale(slots, 6);
    float c2 = sq * sk * 0.08838834764831845f * 1.4426950408889634f;
    int lr8 = lane >> 3;
    int swc = ((lane & 7) ^ lr8) * 16;
    int lr4 = lane >> 2;
    int vswc = ((lane & 3) ^ (lr4 & 3)) * 16;
    const int8_t* kbase = Kq + ((long)(w * 8 + lr8)) * KVDIM + kvh * 128 + swc;
    const int8_t* vbase = Vtq + ((long)kvh * 128 + w * 16 + lr4) * SEQ + vswc;
    auto STAGE_K = [&](int buf, int kt) {
        #pragma unroll
        for (int i = 0; i < 2; i++)
            gload16(kbase + ((long)kt * 64 + i * 32) * KVDIM, &Ks[buf][(w * 8 + i * 32) * 128]);
    };
    auto STAGE_V = [&](int buf, int kt) {
        #pragma unroll
        for (int i = 0; i < 2; i++)
            gload16(vbase + (long)(i * 64) * SEQ + kt * 64, &Vs[buf][(w * 16 + i * 64) * 64]);
    };
    {
        const int8_t* qbase = Qq + ((long)qb * 64 + w * 8 + lr8) * HID + h * 128 + swc;
        #pragma unroll
        for (int i = 0; i < 2; i++)
            gload16(qbase + (long)(i * 32) * HID, &Qs[(w * 8 + i * 32) * 128]);
    }
    STAGE_K(0, 0);
    VMCNT0;
    __syncthreads();
    v4i aq[2];
    #pragma unroll
    for (int ks = 0; ks < 2; ks++) {
        int row = w * 16 + qlan;
        aq[ks] = *(const v4i*)(&Qs[row * 128 + (((ks * 4 + g) ^ (row & 7)) * 16)]);
    }
    int mi = -(1 << 30);
    float l = 0.f;
    int buf = 0;
    // ---- pass 1: int row-max + fused-exp denominator ----
    for (int kt = 0; kt <= qb; kt++) {
        if (kt < qb) STAGE_K(buf ^ 1, kt + 1);
        v4i sf[4] = {vzero, vzero, vzero, vzero};
        __builtin_amdgcn_s_setprio(1);
        #pragma unroll
        for (int ks = 0; ks < 2; ks++)
            #pragma unroll
            for (int f = 0; f < 4; f++) {
                int row = f * 16 + qlan;
                v4i bk = *(const v4i*)(&Ks[buf][row * 128 + (((ks * 4 + g) ^ (row & 7)) * 16)]);
                sf[f] = __builtin_amdgcn_mfma_i32_16x16x64_i8(bk, aq[ks], sf[f], 0, 0, 0);
            }
        __builtin_amdgcn_s_setprio(0);
        int sv[16];
        if (kt == qb) {
            int qthr = w * 16 + qlan;
            #pragma unroll
            for (int f = 0; f < 4; f++)
                #pragma unroll
                for (int r = 0; r < 4; r++) {
                    int kl = f * 16 + g * 4 + r;
                    sv[f * 4 + r] = (kl > qthr) ? NEGS : sf[f][r];
                }
        } else {
            #pragma unroll
            for (int f = 0; f < 4; f++)
                #pragma unroll
                for (int r = 0; r < 4; r++) sv[f * 4 + r] = sf[f][r];
        }
        int tm = sv[0];
        #pragma unroll
        for (int e = 1; e < 16; e++) tm = tm > sv[e] ? tm : sv[e];
        tm = max(tm, __shfl_xor(tm, 16, 64));
        tm = max(tm, __shfl_xor(tm, 32, 64));
        int mn = tm > mi ? tm : mi;
        float fm = (float)mn;
        float nb = -c2 * fm;
        float esc = fexp2(fmaf((float)mi, c2, nb));
        float es = 0.f;
        #pragma unroll
        for (int e = 0; e < 16; e++) es += fexp2(fmaf((float)sv[e], c2, nb));
        es += __shfl_xor(es, 16, 64);
        es += __shfl_xor(es, 32, 64);
        l = l * esc + es;
        mi = mn;
        VMCNT0;
        __syncthreads();
        buf ^= 1;
    }
    // fused quant bias: p_q127 = exp2(c2*s - Bq), Bq = c2*m + log2(l) - log2(127)
    float Bq = fmaf(c2, (float)mi, __log2f(l) - 6.9886846867721655f);
    // ---- pass 2 ----
    unsigned* Ps32 = (unsigned*)Qs;
    int pwr = w * 320;
    v4i of[8];
    #pragma unroll
    for (int nf = 0; nf < 8; nf++) of[nf] = vzero;
    STAGE_K(0, 0);
    STAGE_V(0, 0);
    VMCNT0;
    __syncthreads();
    buf = 0;
    for (int kt = 0; kt <= qb; kt++) {
        if (kt < qb) { STAGE_K(buf ^ 1, kt + 1); STAGE_V(buf ^ 1, kt + 1); }
        v4i sf[4] = {vzero, vzero, vzero, vzero};
        __builtin_amdgcn_s_setprio(1);
        #pragma unroll
        for (int ks = 0; ks < 2; ks++)
            #pragma unroll
            for (int f = 0; f < 4; f++) {
                int row = f * 16 + qlan;
                v4i bk = *(const v4i*)(&Ks[buf][row * 128 + (((ks * 4 + g) ^ (row & 7)) * 16)]);
                sf[f] = __builtin_amdgcn_mfma_i32_16x16x64_i8(bk, aq[ks], sf[f], 0, 0, 0);
            }
        __builtin_amdgcn_s_setprio(0);
        if (kt == qb) {
            int qthr = w * 16 + qlan;
            #pragma unroll
            for (int f = 0; f < 4; f++) {
                unsigned pk = 0;
                #pragma unroll
                for (int r = 0; r < 4; r++) {
                    int kl = f * 16 + g * 4 + r;
                    int s = (kl > qthr) ? NEGS : sf[f][r];
                    float t = fexp2(fmaf((float)s, c2, -Bq));
                    unsigned u = __float_as_uint(t + MAGIC) & 127u;
                    pk |= u << (8 * r);
                }
                Ps32[pwr + (4 * f + g) * 20 + qlan] = pk;
            }
        } else {
            #pragma unroll
            for (int f = 0; f < 4; f++) {
                unsigned pk = 0;
                #pragma unroll
                for (int r = 0; r < 4; r++) {
                    float t = fexp2(fmaf((float)sf[f][r], c2, -Bq));
                    unsigned u = __float_as_uint(t + MAGIC) & 127u;
                    pk |= u << (8 * r);
                }
                Ps32[pwr + (4 * f + g) * 20 + qlan] = pk;
            }
        }
        int rb = pwr + 80 * g + qlan;
        v4i ap;
        ap[0] = (int)Ps32[rb];
        ap[1] = (int)Ps32[rb + 20];
        ap[2] = (int)Ps32[rb + 40];
        ap[3] = (int)Ps32[rb + 60];
        __builtin_amdgcn_s_setprio(1);
        #pragma unroll
        for (int nf = 0; nf < 8; nf++) {
            int row = nf * 16 + qlan;
            v4i bv = *(const v4i*)(&Vs[buf][row * 64 + ((g ^ (row & 3)) * 16)]);
            of[nf] = __builtin_amdgcn_mfma_i32_16x16x64_i8(ap, bv, of[nf], 0, 0, 0);
        }
        __builtin_amdgcn_s_setprio(0);
        VMCNT0;
        __syncthreads();
        buf ^= 1;
    }
    int mymax = 0;
    #pragma unroll
    for (int nf = 0; nf < 8; nf++)
        #pragma unroll
        for (int r = 0; r < 4; r++) {
            int val = of[nf][r];
            int av = val < 0 ? -val : val;
            mymax = av > mymax ? av : mymax;
            int qg = qb * 64 + w * 16 + 4 * g + r;
            AO[(long)qg * HID + h * 128 + nf * 16 + qlan] = val;
        }
    #pragma unroll
    for (int off = 1; off < 64; off <<= 1) {
        int o2 = __shfl_xor(mymax, off, 64);
        mymax = o2 > mymax ? o2 : mymax;
    }
    if (lane == 0) smx[w] = mymax;
    __syncthreads();
    if (tid == 0) {
        int mm = max(max(smx[0], smx[1]), max(smx[2], smx[3]));
        atomicMax(slots + (8 << 5), (unsigned)mm);   // staggered retirement
    }
}

// ---------------- quantize attn_out (int32 -> int8, 4-deep MLP) ----------------
__global__ void k_quant_ao(const int* __restrict__ a, int8_t* __restrict__ q, unsigned* slots) {
    float sv = slot_scale(slots, 7);
    float spv = (1.0f / 127.0f) * sv;
    float amax = spv * (float)(int)slots[8 << 5];
    float s = fmaxf(amax / 127.0f, 1e-8f);
    long nvec = (long)SEQ * HID / 4;
    long gs = (long)gridDim.x * blockDim.x;
    long v = blockIdx.x * (long)blockDim.x + threadIdx.x;
    for (; v + 3 * gs < nvec; v += 4 * gs) {
        #pragma unroll
        for (int j = 0; j < 4; j++) {
            long vid = v + j * gs;
            int4 x = *(const int4*)(a + vid * 4);
            int a0 = q8v(spv * (float)x.x, s);
            int a1 = q8v(spv * (float)x.y, s);
            int a2 = q8v(spv * (float)x.z, s);
            int a3 = q8v(spv * (float)x.w, s);
            unsigned pa = (unsigned)(uint8_t)(int8_t)a0
                        | ((unsigned)(uint8_t)(int8_t)a1 << 8)
                        | ((unsigned)(uint8_t)(int8_t)a2 << 16)
                        | ((unsigned)(uint8_t)(int8_t)a3 << 24);
            *(unsigned*)(q + vid * 4) = pa;
        }
    }
    for (; v < nvec; v += gs) {
        int4 x = *(const int4*)(a + v * 4);
        int a0 = q8v(spv * (float)x.x, s);
        int a1 = q8v(spv * (float)x.y, s);
        int a2 = q8v(spv * (float)x.z, s);
        int a3 = q8v(spv * (float)x.w, s);
        unsigned pa = (unsigned)(uint8_t)(int8_t)a0
                    | ((unsigned)(uint8_t)(int8_t)a1 << 8)
                    | ((unsigned)(uint8_t)(int8_t)a2 << 16)
                    | ((unsigned)(uint8_t)(int8_t)a3 << 24);
        *(unsigned*)(q + v * 4) = pa;
    }
    if (blockIdx.x == 0 && threadIdx.x == 0) slots[9 << 5] = __float_as_uint(amax);
}

extern "C" void kernel_launch(void* const* d_in, const int* in_sizes, int n_in,
                              void* d_out, int out_size, void* d_ws, size_t ws_size,
                              hipStream_t stream) {
    (void)in_sizes; (void)n_in; (void)out_size;
    const float* hid = (const float*)d_in[0];
    const int* pos = (const int*)d_in[2];
    const float* wqp = (const float*)d_in[3];
    const float* wkp = (const float*)d_in[4];
    const float* wvp = (const float*)d_in[5];
    const float* wop = (const float*)d_in[6];
    float* out = (float*)d_out;
    char* ws = (char*)d_ws;

    size_t o = 0;
    auto alloc = [&](size_t sz) { size_t r = o; o += (sz + 255) & ~(size_t)255; return r; };
    unsigned* slots = (unsigned*)(ws + alloc(2048));
    float* P0 = (float*)(ws + alloc(2048 * 4));      // absmax5 partials
    float* P1 = (float*)(ws + alloc(256 * 4));       // gemm1 Q-rope partials
    float* P2 = (float*)(ws + alloc(128 * 4));       // gemm2 K-rope partials
    float* P3 = (float*)(ws + alloc(128 * 4));       // gemm2 V partials
    int8_t* Xq   = (int8_t*)(ws + alloc((size_t)SEQ * HID));      // later reused as AOq
    int8_t* Wqq  = (int8_t*)(ws + alloc((size_t)HID * HID));      // later reused as Woq
    int8_t* Wkvq = (int8_t*)(ws + alloc((size_t)KVCAT * HID));
    float*  Qf   = (float*)(ws + alloc((size_t)SEQ * HID * 4));   // later reused as AOint
    float*  KVf  = (float*)(ws + alloc((size_t)SEQ * KVCAT * 4));
    int8_t* Qq   = (int8_t*)(ws + alloc((size_t)SEQ * HID));
    int8_t* Kq   = (int8_t*)(ws + alloc((size_t)SEQ * KVDIM));
    int8_t* Vtq  = (int8_t*)(ws + alloc((size_t)KVDIM * SEQ));
    float*  ctab = (float*)(ws + alloc((size_t)SEQ * 64 * 4));
    float*  stab = (float*)(ws + alloc((size_t)SEQ * 64 * 4));
    if (ws_size < o) return;
    int8_t* Woq = Wqq;
    int*    AOint = (int*)Qf;
    int8_t* AOq = Xq;

    hipMemsetAsync(slots, 0, 2048, stream);
    k_ropetab<<<SEQ * 64 / 256, 256, 0, stream>>>(pos, ctab, stab);
    k_absmax5<<<2048, 256, 0, stream>>>(hid, wqp, wkp, wvp, wop, P0);
    k_reduceA<<<1, 256, 0, stream>>>(P0, slots);
    k_quant4<<<2048, 256, 0, stream>>>(hid, wqp, wkp, wvp,
                                       Xq, Wqq, Wkvq, Wkvq + (size_t)KVDIM * HID, slots);
    k_gemm_big<<<256, 512, 0, stream>>>(Xq, Wqq, Qf, HID, HID, slots,
                                        0, 1, P1, 1, ctab, stab);
    k_gemm_i8<<<256, 256, 0, stream>>>(Xq, Wkvq, KVf, SEQ, KVCAT, HID, slots,
                                       0, 2, 3, KVDIM, P2, P3, ctab, stab);
    const long CALL = 0x3FFFFFFFL;
    k_quant<<<2048, 256, 0, stream>>>(wop, Woq, (long)HID * HID / 4, 40, CALL, 0, slots, 4);
    k_reduceB<<<1, 256, 0, stream>>>(P1, P2, P3, slots);
    k_quant<<<2048, 256, 0, stream>>>(Qf, Qq, (long)SEQ * HID / 4, 40, CALL, 0, slots, 5);
    k_quant<<<512, 256, 0, stream>>>(KVf, Kq, (long)SEQ * KVDIM / 4, 8, 255, KVCAT, slots, 6);
    k_transq<<<dim3(32, 64), 256, 0, stream>>>(KVf + KVDIM, KVCAT, Vtq, SEQ, slots, 7);
    k_attn<<<1024, 256, 0, stream>>>(Qq, Kq, Vtq, AOint, slots);
    k_quant_ao<<<2048, 256, 0, stream>>>(AOint, AOq, slots);
    k_gemm_big<<<256, 512, 0, stream>>>(AOq, Woq, out, HID, HID, slots,
                                        9, 4, nullptr, 0, nullptr, nullptr);
}

// Round 9
// 300.981 us; speedup vs baseline: 1.0953x; 1.0294x over previous
//
#include <hip/hip_runtime.h>
#include <stdint.h>

#define SEQ   2048
#define HID   4096
#define NH    32
#define NKV   8
#define KVDIM 1024   // NKV*HD
#define KVCAT 2048   // KVDIM*2

typedef int v4i __attribute__((ext_vector_type(4)));

#define VMCNT0 asm volatile("s_waitcnt vmcnt(0)" ::: "memory")

// async global->LDS 16B: per-lane global source, wave-uniform LDS base + lane*16
__device__ __forceinline__ void gload16(const void* g, void* l) {
    __builtin_amdgcn_global_load_lds(
        (const __attribute__((address_space(1))) void*)(uintptr_t)g,
        (__attribute__((address_space(3))) void*)(uintptr_t)l, 16, 0, 0);
}

__device__ __forceinline__ float slot_scale(const unsigned* slots, int slot) {
    return fmaxf(__uint_as_float(slots[slot << 5]) / 127.0f, 1e-8f);
}

__device__ __forceinline__ int q8v(float x, float s) {
    int v = (int)rintf(x / s);
    return v < -127 ? -127 : (v > 127 ? 127 : v);
}

__device__ __forceinline__ float fexp2(float x) {
    float r; asm("v_exp_f32 %0, %1" : "=v"(r) : "v"(x)); return r;
}

__device__ __forceinline__ float amax4(const float* __restrict__ p, long v) {
    float4 x = *(const float4*)(p + v * 4);
    return fmaxf(fmaxf(fabsf(x.x), fabsf(x.y)), fmaxf(fabsf(x.z), fabsf(x.w)));
}

// block-level reduce (4 waves), ONE plain store (no atomic contention)
__device__ __forceinline__ void block_amax_part(float m, float* dst) {
    __shared__ float sm[4];
    int lane = threadIdx.x & 63, w = threadIdx.x >> 6;
    for (int off = 32; off; off >>= 1) m = fmaxf(m, __shfl_xor(m, off, 64));
    if (lane == 0) sm[w] = m;
    __syncthreads();
    if (threadIdx.x == 0)
        *dst = fmaxf(fmaxf(sm[0], sm[1]), fmaxf(sm[2], sm[3]));
    __syncthreads();
}

// ---------------- fused absmax: blocks partitioned per tensor, 8-deep MLP ----------------
#define NV0 ((long)SEQ * HID / 4)     // 2M vecs
#define NV1 ((long)HID * HID / 4)     // 4M vecs
#define NV2 ((long)KVDIM * HID / 4)   // 1M vecs
__global__ void k_absmax5(const float* __restrict__ a0, const float* __restrict__ a1,
                          const float* __restrict__ a2, const float* __restrict__ a3,
                          const float* __restrict__ a4, float* __restrict__ part) {
    int b = blockIdx.x;
    const float* p; long n; int lb, nb;
    if (b < 342)       { p = a0; n = NV0; lb = b;        nb = 342; }
    else if (b < 1025) { p = a1; n = NV1; lb = b - 342;  nb = 683; }
    else if (b < 1196) { p = a2; n = NV2; lb = b - 1025; nb = 171; }
    else if (b < 1367) { p = a3; n = NV2; lb = b - 1196; nb = 171; }
    else               { p = a4; n = NV1; lb = b - 1367; nb = 681; }
    long str = (long)nb * 256;
    float mm[8] = {0.f, 0.f, 0.f, 0.f, 0.f, 0.f, 0.f, 0.f};
    long v = (long)lb * 256 + threadIdx.x;
    for (; v + 7 * str < n; v += 8 * str) {
        #pragma unroll
        for (int j = 0; j < 8; j++) mm[j] = fmaxf(mm[j], amax4(p, v + j * str));
    }
    for (; v < n; v += str) mm[0] = fmaxf(mm[0], amax4(p, v));
    float m = fmaxf(fmaxf(fmaxf(mm[0], mm[1]), fmaxf(mm[2], mm[3])),
                    fmaxf(fmaxf(mm[4], mm[5]), fmaxf(mm[6], mm[7])));
    block_amax_part(m, part + blockIdx.x);
}

// ---------------- reduce partials -> slots 0..4 ----------------
__global__ void k_reduceA(const float* __restrict__ part, unsigned* slots) {
    __shared__ float sm[4];
    const int lo[5] = {0, 342, 1025, 1196, 1367};
    const int hi[5] = {342, 1025, 1196, 1367, 2048};
    int t = threadIdx.x, lane = t & 63, w = t >> 6;
    for (int s = 0; s < 5; s++) {
        float m = 0.f;
        for (int i = lo[s] + t; i < hi[s]; i += 256) m = fmaxf(m, part[i]);
        for (int off = 32; off; off >>= 1) m = fmaxf(m, __shfl_xor(m, off, 64));
        if (lane == 0) sm[w] = m;
        __syncthreads();
        if (t == 0)
            slots[s << 5] = __float_as_uint(fmaxf(fmaxf(sm[0], sm[1]), fmaxf(sm[2], sm[3])));
        __syncthreads();
    }
}

// ---------------- reduce partials -> slots 5 (q), 6 (k), 7 (v) ----------------
__global__ void k_reduceB(const float* __restrict__ p1, const float* __restrict__ p2,
                          const float* __restrict__ p3, unsigned* slots) {
    __shared__ float sm[4];
    int t = threadIdx.x, lane = t & 63, w = t >> 6;
    const float* ps[3] = {p1, p2, p3};
    const int cnt[3] = {512, 128, 128};
    const int sl[3] = {5, 6, 7};
    for (int s = 0; s < 3; s++) {
        float m = 0.f;
        for (int i = t; i < cnt[s]; i += 256) m = fmaxf(m, ps[s][i]);
        for (int off = 32; off; off >>= 1) m = fmaxf(m, __shfl_xor(m, off, 64));
        if (lane == 0) sm[w] = m;
        __syncthreads();
        if (t == 0)
            slots[sl[s] << 5] = __float_as_uint(fmaxf(fmaxf(sm[0], sm[1]), fmaxf(sm[2], sm[3])));
        __syncthreads();
    }
}

__device__ __forceinline__ void qstore4(const float* __restrict__ src, long v,
                                        int8_t* __restrict__ dst, float s) {
    float4 x = *(const float4*)(src + v * 4);
    unsigned pa = (unsigned)(uint8_t)(int8_t)q8v(x.x, s)
                | ((unsigned)(uint8_t)(int8_t)q8v(x.y, s) << 8)
                | ((unsigned)(uint8_t)(int8_t)q8v(x.z, s) << 16)
                | ((unsigned)(uint8_t)(int8_t)q8v(x.w, s) << 24);
    *(unsigned*)(dst + v * 4) = pa;
}

// ---------------- fused quantize of hid, wq, wk, wv ----------------
__global__ void k_quant4(const float* __restrict__ a0, const float* __restrict__ a1,
                         const float* __restrict__ a2, const float* __restrict__ a3,
                         int8_t* __restrict__ d0, int8_t* __restrict__ d1,
                         int8_t* __restrict__ d2, int8_t* __restrict__ d3,
                         const unsigned* __restrict__ slots) {
    int b = blockIdx.x;
    const float* p; int8_t* d; long n; int slot, lb, nb;
    if (b < 512)       { p = a0; d = d0; n = NV0; slot = 0; lb = b;        nb = 512; }
    else if (b < 1536) { p = a1; d = d1; n = NV1; slot = 1; lb = b - 512;  nb = 1024; }
    else if (b < 1792) { p = a2; d = d2; n = NV2; slot = 2; lb = b - 1536; nb = 256; }
    else               { p = a3; d = d3; n = NV2; slot = 3; lb = b - 1792; nb = 256; }
    float s = slot_scale(slots, slot);
    long str = (long)nb * 256;
    long v = (long)lb * 256 + threadIdx.x;
    for (; v + 3 * str < n; v += 4 * str) {
        #pragma unroll
        for (int j = 0; j < 4; j++) qstore4(p, v + j * str, d, s);
    }
    for (; v < n; v += str) qstore4(p, v, d, s);
}

// ---------------- generic quantize f32 -> int8 (4-deep MLP) ----------------
__global__ void k_quant(const float* __restrict__ x, int8_t* __restrict__ q, long nvec,
                        int rshift, long cmaskv, long ld,
                        const unsigned* __restrict__ slots, int slot) {
    float s = slot_scale(slots, slot);
    long gs = (long)gridDim.x * blockDim.x;
    long v = blockIdx.x * (long)blockDim.x + threadIdx.x;
    for (; v + 3 * gs < nvec; v += 4 * gs) {
        #pragma unroll
        for (int j = 0; j < 4; j++) {
            long vid = v + j * gs;
            long r = vid >> rshift;
            long c = (vid & cmaskv) << 2;
            float4 vv = *(const float4*)(x + r * ld + c);
            unsigned pa = (unsigned)(uint8_t)(int8_t)q8v(vv.x, s)
                        | ((unsigned)(uint8_t)(int8_t)q8v(vv.y, s) << 8)
                        | ((unsigned)(uint8_t)(int8_t)q8v(vv.z, s) << 16)
                        | ((unsigned)(uint8_t)(int8_t)q8v(vv.w, s) << 24);
            *(unsigned*)(q + vid * 4) = pa;
        }
    }
    for (; v < nvec; v += gs) {
        long r = v >> rshift;
        long c = (v & cmaskv) << 2;
        float4 vv = *(const float4*)(x + r * ld + c);
        unsigned pa = (unsigned)(uint8_t)(int8_t)q8v(vv.x, s)
                    | ((unsigned)(uint8_t)(int8_t)q8v(vv.y, s) << 8)
                    | ((unsigned)(uint8_t)(int8_t)q8v(vv.z, s) << 16)
                    | ((unsigned)(uint8_t)(int8_t)q8v(vv.w, s) << 24);
        *(unsigned*)(q + v * 4) = pa;
    }
}

// ---------------- rope cos/sin table ----------------
__global__ void k_ropetab(const int* __restrict__ pos, float* __restrict__ ct,
                          float* __restrict__ st) {
    int tid = blockIdx.x * blockDim.x + threadIdx.x;
    if (tid >= SEQ * 64) return;
    int i = tid & 63, s = tid >> 6;
    double inv = 1.0 / pow(10000.0, (double)((float)(2 * i) * (1.0f / 128.0f)));
    float invf = (float)inv;
    float angf = (float)pos[s] * invf;
    double a = (double)angf;
    ct[tid] = (float)cos(a);
    st[tid] = (float)sin(a);
}

// ---------------- transpose + quantize (V -> V^T int8) ----------------
__global__ void k_transq(const float* __restrict__ src, long lds_, int8_t* __restrict__ dst,
                         long ldd, const unsigned* __restrict__ slots, int slot) {
    __shared__ float t[32][33];
    float s = slot_scale(slots, slot);
    int bx = blockIdx.x, by = blockIdx.y;
    int tid = threadIdx.x;
    int c = tid & 31, r0 = tid >> 5;
    #pragma unroll
    for (int j = 0; j < 4; j++) {
        int r = r0 + j * 8;
        t[r][c] = src[(long)(by * 32 + r) * lds_ + bx * 32 + c];
    }
    __syncthreads();
    int d = tid >> 3, k4 = (tid & 7) * 4;
    unsigned pa = 0;
    #pragma unroll
    for (int j = 0; j < 4; j++) {
        int iv = q8v(t[k4 + j][d], s);
        pa |= ((unsigned)(uint8_t)(int8_t)iv) << (8 * j);
    }
    *(unsigned*)(dst + (long)(bx * 32 + d) * ldd + by * 32 + k4) = pa;
}

// ---------------- int8 GEMM 128x128 + optional fused RoPE/absmax epilogue ----------------
// ropemode: 0 = plain store; 1 = rope all cols (Q), partial->pQ[blockIdx];
//           2 = KV: bn<8 rope (K)->pK[bm*8+bn], bn>=8 absmax (V)->pV[bm*8+bn-8]
__global__ __launch_bounds__(256) void k_gemm_i8(
    const int8_t* __restrict__ A, const int8_t* __restrict__ B, float* __restrict__ C,
    int M, int N, int K, unsigned* slots,
    int slotA, int slotB, int slotB2, int nsplit,
    float* pQ, float* pK, float* pV, int ropemode,
    const float* __restrict__ ct, const float* __restrict__ st) {
    __shared__ int8_t POOL[65536];
    int8_t (*As)[16384] = (int8_t(*)[16384])POOL;
    int8_t (*Bs)[16384] = (int8_t(*)[16384])(POOL + 32768);
    const v4i vzero = {0, 0, 0, 0};
    int tid = threadIdx.x, lane = tid & 63, wid = tid >> 6;
    int nbx = N >> 7;
    int nwg = gridDim.x, wg = blockIdx.x;
    int cpx = nwg >> 3;
    int swz = (wg & 7) * cpx + (wg >> 3);
    int bm = swz / nbx, bn = swz % nbx;
    long rowA0 = (long)bm * 128, colB0 = (long)bn * 128;
    int wrow = (wid >> 1) * 64, wcol = (wid & 1) * 64;
    int lr = lane >> 3;
    int swc = ((lane & 7) ^ lr) * 16;
    const int8_t* ga = A + (rowA0 + wid * 8 + lr) * (long)K + swc;
    const int8_t* gb = B + (colB0 + wid * 8 + lr) * (long)K + swc;
    v4i acc[4][4];
    #pragma unroll
    for (int m = 0; m < 4; m++)
        #pragma unroll
        for (int n = 0; n < 4; n++) acc[m][n] = vzero;

    auto STAGE = [&](int buf, int kt) {
        #pragma unroll
        for (int i = 0; i < 4; i++) {
            gload16(ga + kt + (long)(i * 32) * K, &As[buf][(wid * 8 + i * 32) * 128]);
            gload16(gb + kt + (long)(i * 32) * K, &Bs[buf][(wid * 8 + i * 32) * 128]);
        }
    };
    auto COMPUTE = [&](int buf) {
        #pragma unroll
        for (int ks = 0; ks < 2; ks++) {
            v4i af[4], bf[4];
            #pragma unroll
            for (int m = 0; m < 4; m++) {
                int row = wrow + m * 16 + (lane & 15);
                af[m] = *(const v4i*)(&As[buf][row * 128 + (((ks * 4 + (lane >> 4)) ^ (row & 7)) * 16)]);
            }
            #pragma unroll
            for (int n = 0; n < 4; n++) {
                int row = wcol + n * 16 + (lane & 15);
                bf[n] = *(const v4i*)(&Bs[buf][row * 128 + (((ks * 4 + (lane >> 4)) ^ (row & 7)) * 16)]);
            }
            #pragma unroll
            for (int m = 0; m < 4; m++)
                #pragma unroll
                for (int n = 0; n < 4; n++)
                    acc[m][n] = __builtin_amdgcn_mfma_i32_16x16x64_i8(af[m], bf[n], acc[m][n], 0, 0, 0);
        }
    };

    STAGE(0, 0);
    VMCNT0;
    __syncthreads();
    int nt = K >> 7, cur = 0;
    for (int t = 0; t < nt - 1; t++) {
        STAGE(cur ^ 1, (t + 1) << 7);
        COMPUTE(cur);
        VMCNT0;
        __syncthreads();
        cur ^= 1;
    }
    COMPUTE(cur);

    float sA = slot_scale(slots, slotA);
    float sB1 = slot_scale(slots, slotB);
    float sB2 = slot_scale(slots, slotB2);
    int qc = lane & 15, rgrp = (lane >> 4) << 2;
    if (ropemode == 1 || (ropemode == 2 && bn < 8)) {
        __syncthreads();                      // As/Bs dead for all waves
        float* EX = (float*)POOL;             // 128x128 f32, XOR-swizzled
        #pragma unroll
        for (int m = 0; m < 4; m++)
            #pragma unroll
            for (int n = 0; n < 4; n++) {
                int coll = wcol + n * 16 + qc;
                #pragma unroll
                for (int r = 0; r < 4; r++) {
                    int rowl = wrow + m * 16 + rgrp + r;
                    EX[rowl * 128 + (coll ^ ((rowl & 1) << 4))] = sA * sB1 * (float)acc[m][n][r];
                }
            }
        __syncthreads();
        float am = 0.f;
        #pragma unroll
        for (int m = 0; m < 4; m++)
            #pragma unroll
            for (int n = 0; n < 4; n++) {
                int coll = wcol + n * 16 + qc;
                #pragma unroll
                for (int r = 0; r < 4; r++) {
                    int rowl = wrow + m * 16 + rgrp + r;
                    long srow = rowA0 + rowl;
                    float self = EX[rowl * 128 + (coll ^ ((rowl & 1) << 4))];
                    float pv = EX[rowl * 128 + ((coll ^ 64) ^ ((rowl & 1) << 4))];
                    float c = ct[srow * 64 + (coll & 63)];
                    float sn = st[srow * 64 + (coll & 63)];
                    float o = (coll < 64) ? self * c - pv * sn : self * c + pv * sn;
                    am = fmaxf(am, fabsf(o));
                    C[srow * N + colB0 + coll] = o;
                }
            }
        block_amax_part(am, (ropemode == 1) ? pQ + blockIdx.x : pK + bm * 8 + (bn & 7));
    } else if (ropemode == 2) {               // V tile: scale + store + absmax
        float am = 0.f;
        #pragma unroll
        for (int m = 0; m < 4; m++) {
            long row0 = rowA0 + wrow + m * 16 + rgrp;
            #pragma unroll
            for (int n = 0; n < 4; n++) {
                int col = (int)colB0 + wcol + n * 16 + qc;
                float sc = sA * ((col < nsplit) ? sB1 : sB2);
                float* cp = C + row0 * N + col;
                #pragma unroll
                for (int r = 0; r < 4; r++) {
                    float val = sc * (float)acc[m][n][r];
                    cp[(long)r * N] = val;
                    am = fmaxf(am, fabsf(val));
                }
            }
        }
        block_amax_part(am, pV + bm * 8 + (bn & 7));
    } else {
        #pragma unroll
        for (int m = 0; m < 4; m++) {
            long row0 = rowA0 + wrow + m * 16 + rgrp;
            #pragma unroll
            for (int n = 0; n < 4; n++) {
                int col = (int)colB0 + wcol + n * 16 + qc;
                float sc = sA * ((col < nsplit) ? sB1 : sB2);
                float* cp = C + row0 * N + col;
                #pragma unroll
                for (int r = 0; r < 4; r++) cp[(long)r * N] = sc * (float)acc[m][n][r];
            }
        }
    }
}

// ---------------- two-pass flash attention (dbuf gload, fused-exp softmax) ----------------
__global__ __launch_bounds__(256) void k_attn(
    const int8_t* __restrict__ Qq, const int8_t* __restrict__ Kq, const int8_t* __restrict__ Vtq,
    int* __restrict__ AO, unsigned* slots) {
    __shared__ int8_t Qs[64 * 128];   // reused as packed-P store in pass 2
    __shared__ int8_t Ks[2][64 * 128];
    __shared__ int8_t Vs[2][128 * 64];
    __shared__ int smx[4];
    const v4i vzero = {0, 0, 0, 0};
    const int NEGS = -(1 << 29);
    const float MAGIC = 12582912.0f;  // 1.5*2^23, RNE rounding
    int tid = threadIdx.x, lane = tid & 63, w = tid >> 6;
    int qlan = lane & 15, g = lane >> 4;
    int idx = blockIdx.x;
    int qb = 31 - (idx >> 5), h = idx & 31, kvh = h >> 2;   // long blocks first
    float sq = slot_scale(slots, 5), sk = slot_scale(slots, 6);
    float c2 = sq * sk * 0.08838834764831845f * 1.4426950408889634f;
    int lr8 = lane >> 3;
    int swc = ((lane & 7) ^ lr8) * 16;
    int lr4 = lane >> 2;
    int vswc = ((lane & 3) ^ (lr4 & 3)) * 16;
    const int8_t* kbase = Kq + ((long)(w * 8 + lr8)) * KVDIM + kvh * 128 + swc;
    const int8_t* vbase = Vtq + ((long)kvh * 128 + w * 16 + lr4) * SEQ + vswc;
    auto STAGE_K = [&](int buf, int kt) {
        #pragma unroll
        for (int i = 0; i < 2; i++)
            gload16(kbase + ((long)kt * 64 + i * 32) * KVDIM, &Ks[buf][(w * 8 + i * 32) * 128]);
    };
    auto STAGE_V = [&](int buf, int kt) {
        #pragma unroll
        for (int i = 0; i < 2; i++)
            gload16(vbase + (long)(i * 64) * SEQ + kt * 64, &Vs[buf][(w * 16 + i * 64) * 64]);
    };
    {
        const int8_t* qbase = Qq + ((long)qb * 64 + w * 8 + lr8) * HID + h * 128 + swc;
        #pragma unroll
        for (int i = 0; i < 2; i++)
            gload16(qbase + (long)(i * 32) * HID, &Qs[(w * 8 + i * 32) * 128]);
    }
    STAGE_K(0, 0);
    VMCNT0;
    __syncthreads();
    v4i aq[2];
    #pragma unroll
    for (int ks = 0; ks < 2; ks++) {
        int row = w * 16 + qlan;
        aq[ks] = *(const v4i*)(&Qs[row * 128 + (((ks * 4 + g) ^ (row & 7)) * 16)]);
    }
    int mi = -(1 << 30);
    float l = 0.f;
    int buf = 0;
    // ---- pass 1: int row-max + fused-exp denominator ----
    for (int kt = 0; kt <= qb; kt++) {
        if (kt < qb) STAGE_K(buf ^ 1, kt + 1);
        v4i sf[4] = {vzero, vzero, vzero, vzero};
        __builtin_amdgcn_s_setprio(1);
        #pragma unroll
        for (int ks = 0; ks < 2; ks++)
            #pragma unroll
            for (int f = 0; f < 4; f++) {
                int row = f * 16 + qlan;
                v4i bk = *(const v4i*)(&Ks[buf][row * 128 + (((ks * 4 + g) ^ (row & 7)) * 16)]);
                sf[f] = __builtin_amdgcn_mfma_i32_16x16x64_i8(bk, aq[ks], sf[f], 0, 0, 0);
            }
        __builtin_amdgcn_s_setprio(0);
        int sv[16];
        if (kt == qb) {
            int qthr = w * 16 + qlan;
            #pragma unroll
            for (int f = 0; f < 4; f++)
                #pragma unroll
                for (int r = 0; r < 4; r++) {
                    int kl = f * 16 + g * 4 + r;
                    sv[f * 4 + r] = (kl > qthr) ? NEGS : sf[f][r];
                }
        } else {
            #pragma unroll
            for (int f = 0; f < 4; f++)
                #pragma unroll
                for (int r = 0; r < 4; r++) sv[f * 4 + r] = sf[f][r];
        }
        int tm = sv[0];
        #pragma unroll
        for (int e = 1; e < 16; e++) tm = tm > sv[e] ? tm : sv[e];
        tm = max(tm, __shfl_xor(tm, 16, 64));
        tm = max(tm, __shfl_xor(tm, 32, 64));
        int mn = tm > mi ? tm : mi;
        float nb = -c2 * (float)mn;
        float esc = fexp2(fmaf((float)mi, c2, nb));
        float es = 0.f;
        #pragma unroll
        for (int e = 0; e < 16; e++) es += fexp2(fmaf((float)sv[e], c2, nb));
        es += __shfl_xor(es, 16, 64);
        es += __shfl_xor(es, 32, 64);
        l = l * esc + es;
        mi = mn;
        VMCNT0;
        __syncthreads();
        buf ^= 1;
    }
    // fused quant bias: p_q127 = exp2(c2*s - Bq), Bq = c2*m + log2(l) - log2(127)
    float Bq = fmaf(c2, (float)mi, __log2f(l) - 6.9886846867721655f);
    // ---- pass 2 ----
    unsigned* Ps32 = (unsigned*)Qs;
    int pwr = w * 320;
    v4i of[8];
    #pragma unroll
    for (int nf = 0; nf < 8; nf++) of[nf] = vzero;
    STAGE_K(0, 0);
    STAGE_V(0, 0);
    VMCNT0;
    __syncthreads();
    buf = 0;
    for (int kt = 0; kt <= qb; kt++) {
        if (kt < qb) { STAGE_K(buf ^ 1, kt + 1); STAGE_V(buf ^ 1, kt + 1); }
        v4i sf[4] = {vzero, vzero, vzero, vzero};
        __builtin_amdgcn_s_setprio(1);
        #pragma unroll
        for (int ks = 0; ks < 2; ks++)
            #pragma unroll
            for (int f = 0; f < 4; f++) {
                int row = f * 16 + qlan;
                v4i bk = *(const v4i*)(&Ks[buf][row * 128 + (((ks * 4 + g) ^ (row & 7)) * 16)]);
                sf[f] = __builtin_amdgcn_mfma_i32_16x16x64_i8(bk, aq[ks], sf[f], 0, 0, 0);
            }
        __builtin_amdgcn_s_setprio(0);
        if (kt == qb) {
            int qthr = w * 16 + qlan;
            #pragma unroll
            for (int f = 0; f < 4; f++) {
                unsigned pk = 0;
                #pragma unroll
                for (int r = 0; r < 4; r++) {
                    int kl = f * 16 + g * 4 + r;
                    int s = (kl > qthr) ? NEGS : sf[f][r];
                    float t = fexp2(fmaf((float)s, c2, -Bq));
                    unsigned u = __float_as_uint(t + MAGIC) & 127u;
                    pk |= u << (8 * r);
                }
                Ps32[pwr + (4 * f + g) * 20 + qlan] = pk;
            }
        } else {
            #pragma unroll
            for (int f = 0; f < 4; f++) {
                unsigned pk = 0;
                #pragma unroll
                for (int r = 0; r < 4; r++) {
                    float t = fexp2(fmaf((float)sf[f][r], c2, -Bq));
                    unsigned u = __float_as_uint(t + MAGIC) & 127u;
                    pk |= u << (8 * r);
                }
                Ps32[pwr + (4 * f + g) * 20 + qlan] = pk;
            }
        }
        int rb = pwr + 80 * g + qlan;
        v4i ap;
        ap[0] = (int)Ps32[rb];
        ap[1] = (int)Ps32[rb + 20];
        ap[2] = (int)Ps32[rb + 40];
        ap[3] = (int)Ps32[rb + 60];
        __builtin_amdgcn_s_setprio(1);
        #pragma unroll
        for (int nf = 0; nf < 8; nf++) {
            int row = nf * 16 + qlan;
            v4i bv = *(const v4i*)(&Vs[buf][row * 64 + ((g ^ (row & 3)) * 16)]);
            of[nf] = __builtin_amdgcn_mfma_i32_16x16x64_i8(ap, bv, of[nf], 0, 0, 0);
        }
        __builtin_amdgcn_s_setprio(0);
        VMCNT0;
        __syncthreads();
        buf ^= 1;
    }
    int mymax = 0;
    #pragma unroll
    for (int nf = 0; nf < 8; nf++)
        #pragma unroll
        for (int r = 0; r < 4; r++) {
            int val = of[nf][r];
            int av = val < 0 ? -val : val;
            mymax = av > mymax ? av : mymax;
            int qg = qb * 64 + w * 16 + 4 * g + r;
            AO[(long)qg * HID + h * 128 + nf * 16 + qlan] = val;
        }
    #pragma unroll
    for (int off = 1; off < 64; off <<= 1) {
        int o2 = __shfl_xor(mymax, off, 64);
        mymax = o2 > mymax ? o2 : mymax;
    }
    if (lane == 0) smx[w] = mymax;
    __syncthreads();
    if (tid == 0) {
        int mm = max(max(smx[0], smx[1]), max(smx[2], smx[3]));
        atomicMax(slots + (8 << 5), (unsigned)mm);   // staggered retirement
    }
}

// ---------------- quantize attn_out (int32 -> int8, 4-deep MLP) ----------------
__global__ void k_quant_ao(const int* __restrict__ a, int8_t* __restrict__ q, unsigned* slots) {
    float sv = slot_scale(slots, 7);
    float spv = (1.0f / 127.0f) * sv;
    float amax = spv * (float)(int)slots[8 << 5];
    float s = fmaxf(amax / 127.0f, 1e-8f);
    long nvec = (long)SEQ * HID / 4;
    long gs = (long)gridDim.x * blockDim.x;
    long v = blockIdx.x * (long)blockDim.x + threadIdx.x;
    for (; v + 3 * gs < nvec; v += 4 * gs) {
        #pragma unroll
        for (int j = 0; j < 4; j++) {
            long vid = v + j * gs;
            int4 x = *(const int4*)(a + vid * 4);
            int a0 = q8v(spv * (float)x.x, s);
            int a1 = q8v(spv * (float)x.y, s);
            int a2 = q8v(spv * (float)x.z, s);
            int a3 = q8v(spv * (float)x.w, s);
            unsigned pa = (unsigned)(uint8_t)(int8_t)a0
                        | ((unsigned)(uint8_t)(int8_t)a1 << 8)
                        | ((unsigned)(uint8_t)(int8_t)a2 << 16)
                        | ((unsigned)(uint8_t)(int8_t)a3 << 24);
            *(unsigned*)(q + vid * 4) = pa;
        }
    }
    for (; v < nvec; v += gs) {
        int4 x = *(const int4*)(a + v * 4);
        int a0 = q8v(spv * (float)x.x, s);
        int a1 = q8v(spv * (float)x.y, s);
        int a2 = q8v(spv * (float)x.z, s);
        int a3 = q8v(spv * (float)x.w, s);
        unsigned pa = (unsigned)(uint8_t)(int8_t)a0
                    | ((unsigned)(uint8_t)(int8_t)a1 << 8)
                    | ((unsigned)(uint8_t)(int8_t)a2 << 16)
                    | ((unsigned)(uint8_t)(int8_t)a3 << 24);
        *(unsigned*)(q + v * 4) = pa;
    }
    if (blockIdx.x == 0 && threadIdx.x == 0) slots[9 << 5] = __float_as_uint(amax);
}

extern "C" void kernel_launch(void* const* d_in, const int* in_sizes, int n_in,
                              void* d_out, int out_size, void* d_ws, size_t ws_size,
                              hipStream_t stream) {
    (void)in_sizes; (void)n_in; (void)out_size;
    const float* hid = (const float*)d_in[0];
    const int* pos = (const int*)d_in[2];
    const float* wqp = (const float*)d_in[3];
    const float* wkp = (const float*)d_in[4];
    const float* wvp = (const float*)d_in[5];
    const float* wop = (const float*)d_in[6];
    float* out = (float*)d_out;
    char* ws = (char*)d_ws;

    size_t o = 0;
    auto alloc = [&](size_t sz) { size_t r = o; o += (sz + 255) & ~(size_t)255; return r; };
    unsigned* slots = (unsigned*)(ws + alloc(2048));
    float* P0 = (float*)(ws + alloc(2048 * 4));      // absmax5 partials
    float* P1 = (float*)(ws + alloc(512 * 4));       // gemm1 Q-rope partials
    float* P2 = (float*)(ws + alloc(128 * 4));       // gemm2 K-rope partials
    float* P3 = (float*)(ws + alloc(128 * 4));       // gemm2 V partials
    int8_t* Xq   = (int8_t*)(ws + alloc((size_t)SEQ * HID));      // later reused as AOq
    int8_t* Wqq  = (int8_t*)(ws + alloc((size_t)HID * HID));      // later reused as Woq
    int8_t* Wkvq = (int8_t*)(ws + alloc((size_t)KVCAT * HID));
    float*  Qf   = (float*)(ws + alloc((size_t)SEQ * HID * 4));   // later reused as AOint
    float*  KVf  = (float*)(ws + alloc((size_t)SEQ * KVCAT * 4));
    int8_t* Qq   = (int8_t*)(ws + alloc((size_t)SEQ * HID));
    int8_t* Kq   = (int8_t*)(ws + alloc((size_t)SEQ * KVDIM));
    int8_t* Vtq  = (int8_t*)(ws + alloc((size_t)KVDIM * SEQ));
    float*  ctab = (float*)(ws + alloc((size_t)SEQ * 64 * 4));
    float*  stab = (float*)(ws + alloc((size_t)SEQ * 64 * 4));
    if (ws_size < o) return;
    int8_t* Woq = Wqq;
    int*    AOint = (int*)Qf;
    int8_t* AOq = Xq;

    hipMemsetAsync(slots, 0, 2048, stream);
    k_ropetab<<<SEQ * 64 / 256, 256, 0, stream>>>(pos, ctab, stab);
    k_absmax5<<<2048, 256, 0, stream>>>(hid, wqp, wkp, wvp, wop, P0);
    k_reduceA<<<1, 256, 0, stream>>>(P0, slots);
    k_quant4<<<2048, 256, 0, stream>>>(hid, wqp, wkp, wvp,
                                       Xq, Wqq, Wkvq, Wkvq + (size_t)KVDIM * HID, slots);
    k_gemm_i8<<<512, 256, 0, stream>>>(Xq, Wqq, Qf, SEQ, HID, HID, slots,
                                       0, 1, 1, 1 << 30, P1, nullptr, nullptr, 1, ctab, stab);
    k_gemm_i8<<<256, 256, 0, stream>>>(Xq, Wkvq, KVf, SEQ, KVCAT, HID, slots,
                                       0, 2, 3, KVDIM, nullptr, P2, P3, 2, ctab, stab);
    const long CALL = 0x3FFFFFFFL;
    k_quant<<<2048, 256, 0, stream>>>(wop, Woq, (long)HID * HID / 4, 40, CALL, 0, slots, 4);
    k_reduceB<<<1, 256, 0, stream>>>(P1, P2, P3, slots);
    k_quant<<<2048, 256, 0, stream>>>(Qf, Qq, (long)SEQ * HID / 4, 40, CALL, 0, slots, 5);
    k_quant<<<512, 256, 0, stream>>>(KVf, Kq, (long)SEQ * KVDIM / 4, 8, 255, KVCAT, slots, 6);
    k_transq<<<dim3(32, 64), 256, 0, stream>>>(KVf + KVDIM, KVCAT, Vtq, SEQ, slots, 7);
    k_attn<<<1024, 256, 0, stream>>>(Qq, Kq, Vtq, AOint, slots);
    k_quant_ao<<<2048, 256, 0, stream>>>(AOint, AOq, slots);
    k_gemm_i8<<<512, 256, 0, stream>>>(AOq, Woq, out, SEQ, HID, HID, slots,
                                       9, 4, 4, 1 << 30, nullptr, nullptr, nullptr, 0,
                                       nullptr, nullptr);
}

// Round 10
// 285.822 us; speedup vs baseline: 1.1534x; 1.0530x over previous
//
#include <hip/hip_runtime.h>
#include <hip/hip_fp16.h>
#include <stdint.h>

#define SEQ   2048
#define HID   4096
#define NH    32
#define NKV   8
#define KVDIM 1024   // NKV*HD
#define KVCAT 2048   // KVDIM*2

typedef int v4i __attribute__((ext_vector_type(4)));

#define VMCNT0 asm volatile("s_waitcnt vmcnt(0)" ::: "memory")

// async global->LDS 16B: per-lane global source, wave-uniform LDS base + lane*16
__device__ __forceinline__ void gload16(const void* g, void* l) {
    __builtin_amdgcn_global_load_lds(
        (const __attribute__((address_space(1))) void*)(uintptr_t)g,
        (__attribute__((address_space(3))) void*)(uintptr_t)l, 16, 0, 0);
}

__device__ __forceinline__ float slot_scale(const unsigned* slots, int slot) {
    return fmaxf(__uint_as_float(slots[slot << 5]) / 127.0f, 1e-8f);
}

__device__ __forceinline__ int q8v(float x, float s) {
    int v = (int)rintf(x / s);
    return v < -127 ? -127 : (v > 127 ? 127 : v);
}

__device__ __forceinline__ unsigned pk4(float a, float b, float c, float d, float s) {
    return (unsigned)(uint8_t)(int8_t)q8v(a, s)
         | ((unsigned)(uint8_t)(int8_t)q8v(b, s) << 8)
         | ((unsigned)(uint8_t)(int8_t)q8v(c, s) << 16)
         | ((unsigned)(uint8_t)(int8_t)q8v(d, s) << 24);
}

__device__ __forceinline__ float fexp2(float x) {
    float r; asm("v_exp_f32 %0, %1" : "=v"(r) : "v"(x)); return r;
}

__device__ __forceinline__ float fmax4a(float4 x) {
    return fmaxf(fmaxf(fabsf(x.x), fabsf(x.y)), fmaxf(fabsf(x.z), fabsf(x.w)));
}

// block-level reduce (4 waves), ONE plain store (no atomic contention)
__device__ __forceinline__ void block_amax_part(float m, float* dst) {
    __shared__ float sm[4];
    int lane = threadIdx.x & 63, w = threadIdx.x >> 6;
    for (int off = 32; off; off >>= 1) m = fmaxf(m, __shfl_xor(m, off, 64));
    if (lane == 0) sm[w] = m;
    __syncthreads();
    if (threadIdx.x == 0)
        *dst = fmaxf(fmaxf(sm[0], sm[1]), fmaxf(sm[2], sm[3]));
    __syncthreads();
}

// ---------------- fused absmax: blocks partitioned per tensor, batched loads ----------------
#define NV0 ((long)SEQ * HID / 4)     // 2M vecs
#define NV1 ((long)HID * HID / 4)     // 4M vecs
#define NV2 ((long)KVDIM * HID / 4)   // 1M vecs
__global__ void k_absmax5(const float* __restrict__ a0, const float* __restrict__ a1,
                          const float* __restrict__ a2, const float* __restrict__ a3,
                          const float* __restrict__ a4, float* __restrict__ part) {
    int b = blockIdx.x;
    const float* p; long n; int lb, nb;
    if (b < 342)       { p = a0; n = NV0; lb = b;        nb = 342; }
    else if (b < 1025) { p = a1; n = NV1; lb = b - 342;  nb = 683; }
    else if (b < 1196) { p = a2; n = NV2; lb = b - 1025; nb = 171; }
    else if (b < 1367) { p = a3; n = NV2; lb = b - 1196; nb = 171; }
    else               { p = a4; n = NV1; lb = b - 1367; nb = 681; }
    long str = (long)nb * 256;
    float mm[8] = {0.f, 0.f, 0.f, 0.f, 0.f, 0.f, 0.f, 0.f};
    long v = (long)lb * 256 + threadIdx.x;
    for (; v + 7 * str < n; v += 8 * str) {
        float4 t[8];
        #pragma unroll
        for (int j = 0; j < 8; j++) t[j] = *(const float4*)(p + (v + j * str) * 4);
        #pragma unroll
        for (int j = 0; j < 8; j++) mm[j] = fmaxf(mm[j], fmax4a(t[j]));
    }
    for (; v < n; v += str) mm[0] = fmaxf(mm[0], fmax4a(*(const float4*)(p + v * 4)));
    float m = fmaxf(fmaxf(fmaxf(mm[0], mm[1]), fmaxf(mm[2], mm[3])),
                    fmaxf(fmaxf(mm[4], mm[5]), fmaxf(mm[6], mm[7])));
    block_amax_part(m, part + blockIdx.x);
}

// ---------------- reduce partials -> slots 0..4 ----------------
__global__ void k_reduceA(const float* __restrict__ part, unsigned* slots) {
    __shared__ float sm[4];
    const int lo[5] = {0, 342, 1025, 1196, 1367};
    const int hi[5] = {342, 1025, 1196, 1367, 2048};
    int t = threadIdx.x, lane = t & 63, w = t >> 6;
    for (int s = 0; s < 5; s++) {
        float m = 0.f;
        for (int i = lo[s] + t; i < hi[s]; i += 256) m = fmaxf(m, part[i]);
        for (int off = 32; off; off >>= 1) m = fmaxf(m, __shfl_xor(m, off, 64));
        if (lane == 0) sm[w] = m;
        __syncthreads();
        if (t == 0)
            slots[s << 5] = __float_as_uint(fmaxf(fmaxf(sm[0], sm[1]), fmaxf(sm[2], sm[3])));
        __syncthreads();
    }
}

// ---------------- reduce partials -> slots 5 (q), 6 (k), 7 (v) ----------------
__global__ void k_reduceB(const float* __restrict__ p1, const float* __restrict__ p2,
                          const float* __restrict__ p3, unsigned* slots) {
    __shared__ float sm[4];
    int t = threadIdx.x, lane = t & 63, w = t >> 6;
    const float* ps[3] = {p1, p2, p3};
    const int cnt[3] = {512, 128, 128};
    const int sl[3] = {5, 6, 7};
    for (int s = 0; s < 3; s++) {
        float m = 0.f;
        for (int i = t; i < cnt[s]; i += 256) m = fmaxf(m, ps[s][i]);
        for (int off = 32; off; off >>= 1) m = fmaxf(m, __shfl_xor(m, off, 64));
        if (lane == 0) sm[w] = m;
        __syncthreads();
        if (t == 0)
            slots[sl[s] << 5] = __float_as_uint(fmaxf(fmaxf(sm[0], sm[1]), fmaxf(sm[2], sm[3])));
        __syncthreads();
    }
}

// ---------------- fused quantize of hid, wq, wk, wv (16-elem units, packed writes) ------
#define NU0 ((long)SEQ * HID / 16)
#define NU1 ((long)HID * HID / 16)
#define NU2 ((long)KVDIM * HID / 16)
__global__ void k_quant4(const float* __restrict__ a0, const float* __restrict__ a1,
                         const float* __restrict__ a2, const float* __restrict__ a3,
                         int8_t* __restrict__ d0, int8_t* __restrict__ d1,
                         int8_t* __restrict__ d2, int8_t* __restrict__ d3,
                         const unsigned* __restrict__ slots) {
    int b = blockIdx.x;
    const float* p; int8_t* d; long n; int slot, lb, nb;
    if (b < 512)       { p = a0; d = d0; n = NU0; slot = 0; lb = b;        nb = 512; }
    else if (b < 1536) { p = a1; d = d1; n = NU1; slot = 1; lb = b - 512;  nb = 1024; }
    else if (b < 1792) { p = a2; d = d2; n = NU2; slot = 2; lb = b - 1536; nb = 256; }
    else               { p = a3; d = d3; n = NU2; slot = 3; lb = b - 1792; nb = 256; }
    float s = slot_scale(slots, slot);
    long str = (long)nb * 256;
    for (long u = (long)lb * 256 + threadIdx.x; u < n; u += str) {
        const float4* src = (const float4*)(p + u * 16);
        float4 t0 = src[0], t1 = src[1], t2 = src[2], t3 = src[3];
        int4 o;
        o.x = (int)pk4(t0.x, t0.y, t0.z, t0.w, s);
        o.y = (int)pk4(t1.x, t1.y, t1.z, t1.w, s);
        o.z = (int)pk4(t2.x, t2.y, t2.z, t2.w, s);
        o.w = (int)pk4(t3.x, t3.y, t3.z, t3.w, s);
        *(int4*)(d + u * 16) = o;
    }
}

// ---------------- f32 -> int8 contiguous (wo), packed ----------------
__global__ void k_quantw(const float* __restrict__ x, int8_t* __restrict__ q, long nu,
                         const unsigned* __restrict__ slots, int slot) {
    float s = slot_scale(slots, slot);
    long gs = (long)gridDim.x * blockDim.x;
    for (long u = blockIdx.x * (long)blockDim.x + threadIdx.x; u < nu; u += gs) {
        const float4* src = (const float4*)(x + u * 16);
        float4 t0 = src[0], t1 = src[1], t2 = src[2], t3 = src[3];
        int4 o;
        o.x = (int)pk4(t0.x, t0.y, t0.z, t0.w, s);
        o.y = (int)pk4(t1.x, t1.y, t1.z, t1.w, s);
        o.z = (int)pk4(t2.x, t2.y, t2.z, t2.w, s);
        o.w = (int)pk4(t3.x, t3.y, t3.z, t3.w, s);
        *(int4*)(q + u * 16) = o;
    }
}

// ---------------- f16 -> int8 (16-half units; strided-capable), packed ----------------
__device__ __forceinline__ unsigned pk4h(unsigned h2a, unsigned h2b, float s) {
    __half2 a = *(__half2*)&h2a, b = *(__half2*)&h2b;
    return pk4(__low2float(a), __high2float(a), __low2float(b), __high2float(b), s);
}
__global__ void k_quanth(const __half* __restrict__ x, int8_t* __restrict__ q, long nu,
                         int rshift, long cmask, long ld,
                         const unsigned* __restrict__ slots, int slot) {
    float s = slot_scale(slots, slot);
    long gs = (long)gridDim.x * blockDim.x;
    for (long u = blockIdx.x * (long)blockDim.x + threadIdx.x; u < nu; u += gs) {
        long row = u >> rshift;
        long cu = u & cmask;
        const int4* src = (const int4*)(x + row * ld + cu * 16);
        int4 a = src[0], b = src[1];
        int4 o;
        o.x = (int)pk4h((unsigned)a.x, (unsigned)a.y, s);
        o.y = (int)pk4h((unsigned)a.z, (unsigned)a.w, s);
        o.z = (int)pk4h((unsigned)b.x, (unsigned)b.y, s);
        o.w = (int)pk4h((unsigned)b.z, (unsigned)b.w, s);
        *(int4*)(q + u * 16) = o;
    }
}

// ---------------- rope cos/sin table ----------------
__global__ void k_ropetab(const int* __restrict__ pos, float* __restrict__ ct,
                          float* __restrict__ st) {
    int tid = blockIdx.x * blockDim.x + threadIdx.x;
    if (tid >= SEQ * 64) return;
    int i = tid & 63, s = tid >> 6;
    double inv = 1.0 / pow(10000.0, (double)((float)(2 * i) * (1.0f / 128.0f)));
    float invf = (float)inv;
    float angf = (float)pos[s] * invf;
    double a = (double)angf;
    ct[tid] = (float)cos(a);
    st[tid] = (float)sin(a);
}

// ---------------- transpose + quantize (V f16 -> V^T int8) ----------------
__global__ void k_transq(const __half* __restrict__ src, long lds_, int8_t* __restrict__ dst,
                         long ldd, const unsigned* __restrict__ slots, int slot) {
    __shared__ float t[32][33];
    float s = slot_scale(slots, slot);
    int bx = blockIdx.x, by = blockIdx.y;
    int tid = threadIdx.x;
    int c = tid & 31, r0 = tid >> 5;
    #pragma unroll
    for (int j = 0; j < 4; j++) {
        int r = r0 + j * 8;
        t[r][c] = __half2float(src[(long)(by * 32 + r) * lds_ + bx * 32 + c]);
    }
    __syncthreads();
    int d = tid >> 3, k4 = (tid & 7) * 4;
    unsigned pa = 0;
    #pragma unroll
    for (int j = 0; j < 4; j++) {
        int iv = q8v(t[k4 + j][d], s);
        pa |= ((unsigned)(uint8_t)(int8_t)iv) << (8 * j);
    }
    *(unsigned*)(dst + (long)(bx * 32 + d) * ldd + by * 32 + k4) = pa;
}

// ---------------- int8 GEMM 128x128 + fused RoPE/absmax epilogue ----------------
// ropemode: 0 = plain f32 store; 1 = rope all cols (Q, f16 out), partial->pQ[blockIdx];
//           2 = KV f16 out: bn<8 rope (K)->pK, bn>=8 absmax (V)->pV
__global__ __launch_bounds__(256) void k_gemm_i8(
    const int8_t* __restrict__ A, const int8_t* __restrict__ B, void* __restrict__ Cv,
    int M, int N, int K, unsigned* slots,
    int slotA, int slotB, int slotB2, int nsplit,
    float* pQ, float* pK, float* pV, int ropemode,
    const float* __restrict__ ct, const float* __restrict__ st) {
    __shared__ int8_t POOL[65536];
    int8_t (*As)[16384] = (int8_t(*)[16384])POOL;
    int8_t (*Bs)[16384] = (int8_t(*)[16384])(POOL + 32768);
    float* Cf = (float*)Cv;
    __half* Ch = (__half*)Cv;
    const v4i vzero = {0, 0, 0, 0};
    int tid = threadIdx.x, lane = tid & 63, wid = tid >> 6;
    int nbx = N >> 7;
    int nwg = gridDim.x, wg = blockIdx.x;
    int cpx = nwg >> 3;
    int swz = (wg & 7) * cpx + (wg >> 3);
    int bm = swz / nbx, bn = swz % nbx;
    long rowA0 = (long)bm * 128, colB0 = (long)bn * 128;
    int wrow = (wid >> 1) * 64, wcol = (wid & 1) * 64;
    int lr = lane >> 3;
    int swc = ((lane & 7) ^ lr) * 16;
    const int8_t* ga = A + (rowA0 + wid * 8 + lr) * (long)K + swc;
    const int8_t* gb = B + (colB0 + wid * 8 + lr) * (long)K + swc;
    v4i acc[4][4];
    #pragma unroll
    for (int m = 0; m < 4; m++)
        #pragma unroll
        for (int n = 0; n < 4; n++) acc[m][n] = vzero;

    auto STAGE = [&](int buf, int kt) {
        #pragma unroll
        for (int i = 0; i < 4; i++) {
            gload16(ga + kt + (long)(i * 32) * K, &As[buf][(wid * 8 + i * 32) * 128]);
            gload16(gb + kt + (long)(i * 32) * K, &Bs[buf][(wid * 8 + i * 32) * 128]);
        }
    };
    auto COMPUTE = [&](int buf) {
        #pragma unroll
        for (int ks = 0; ks < 2; ks++) {
            v4i af[4], bf[4];
            #pragma unroll
            for (int m = 0; m < 4; m++) {
                int row = wrow + m * 16 + (lane & 15);
                af[m] = *(const v4i*)(&As[buf][row * 128 + (((ks * 4 + (lane >> 4)) ^ (row & 7)) * 16)]);
            }
            #pragma unroll
            for (int n = 0; n < 4; n++) {
                int row = wcol + n * 16 + (lane & 15);
                bf[n] = *(const v4i*)(&Bs[buf][row * 128 + (((ks * 4 + (lane >> 4)) ^ (row & 7)) * 16)]);
            }
            #pragma unroll
            for (int m = 0; m < 4; m++)
                #pragma unroll
                for (int n = 0; n < 4; n++)
                    acc[m][n] = __builtin_amdgcn_mfma_i32_16x16x64_i8(af[m], bf[n], acc[m][n], 0, 0, 0);
        }
    };

    STAGE(0, 0);
    VMCNT0;
    __syncthreads();
    int nt = K >> 7, cur = 0;
    for (int t = 0; t < nt - 1; t++) {
        STAGE(cur ^ 1, (t + 1) << 7);
        COMPUTE(cur);
        VMCNT0;
        __syncthreads();
        cur ^= 1;
    }
    COMPUTE(cur);

    float sA = slot_scale(slots, slotA);
    float sB1 = slot_scale(slots, slotB);
    float sB2 = slot_scale(slots, slotB2);
    int qc = lane & 15, rgrp = (lane >> 4) << 2;
    if (ropemode == 1 || (ropemode == 2 && bn < 8)) {
        __syncthreads();                      // As/Bs dead for all waves
        float* EX = (float*)POOL;             // 128x128 f32, XOR-swizzled
        #pragma unroll
        for (int m = 0; m < 4; m++)
            #pragma unroll
            for (int n = 0; n < 4; n++) {
                int coll = wcol + n * 16 + qc;
                #pragma unroll
                for (int r = 0; r < 4; r++) {
                    int rowl = wrow + m * 16 + rgrp + r;
                    EX[rowl * 128 + (coll ^ ((rowl & 1) << 4))] = sA * sB1 * (float)acc[m][n][r];
                }
            }
        __syncthreads();
        float am = 0.f;
        #pragma unroll
        for (int m = 0; m < 4; m++)
            #pragma unroll
            for (int n = 0; n < 4; n++) {
                int coll = wcol + n * 16 + qc;
                #pragma unroll
                for (int r = 0; r < 4; r++) {
                    int rowl = wrow + m * 16 + rgrp + r;
                    long srow = rowA0 + rowl;
                    float self = EX[rowl * 128 + (coll ^ ((rowl & 1) << 4))];
                    float pv = EX[rowl * 128 + ((coll ^ 64) ^ ((rowl & 1) << 4))];
                    float c = ct[srow * 64 + (coll & 63)];
                    float sn = st[srow * 64 + (coll & 63)];
                    float o = (coll < 64) ? self * c - pv * sn : self * c + pv * sn;
                    am = fmaxf(am, fabsf(o));
                    Ch[srow * N + colB0 + coll] = __float2half(o);
                }
            }
        block_amax_part(am, (ropemode == 1) ? pQ + blockIdx.x : pK + bm * 8 + (bn & 7));
    } else if (ropemode == 2) {               // V tile: scale + f16 store + absmax
        float am = 0.f;
        #pragma unroll
        for (int m = 0; m < 4; m++) {
            long row0 = rowA0 + wrow + m * 16 + rgrp;
            #pragma unroll
            for (int n = 0; n < 4; n++) {
                int col = (int)colB0 + wcol + n * 16 + qc;
                float sc = sA * ((col < nsplit) ? sB1 : sB2);
                __half* cp = Ch + row0 * N + col;
                #pragma unroll
                for (int r = 0; r < 4; r++) {
                    float val = sc * (float)acc[m][n][r];
                    cp[(long)r * N] = __float2half(val);
                    am = fmaxf(am, fabsf(val));
                }
            }
        }
        block_amax_part(am, pV + bm * 8 + (bn & 7));
    } else {
        #pragma unroll
        for (int m = 0; m < 4; m++) {
            long row0 = rowA0 + wrow + m * 16 + rgrp;
            #pragma unroll
            for (int n = 0; n < 4; n++) {
                int col = (int)colB0 + wcol + n * 16 + qc;
                float sc = sA * ((col < nsplit) ? sB1 : sB2);
                float* cp = Cf + row0 * N + col;
                #pragma unroll
                for (int r = 0; r < 4; r++) cp[(long)r * N] = sc * (float)acc[m][n][r];
            }
        }
    }
}

// ---------------- two-pass flash attention (dbuf gload, fused-exp softmax, f16 out) -------
__global__ __launch_bounds__(256) void k_attn(
    const int8_t* __restrict__ Qq, const int8_t* __restrict__ Kq, const int8_t* __restrict__ Vtq,
    __half* __restrict__ AO, unsigned* slots) {
    __shared__ int8_t Qs[64 * 128];   // reused as packed-P store in pass 2
    __shared__ int8_t Ks[2][64 * 128];
    __shared__ int8_t Vs[2][128 * 64];
    __shared__ int smx[4];
    const v4i vzero = {0, 0, 0, 0};
    const int NEGS = -(1 << 29);
    const float MAGIC = 12582912.0f;  // 1.5*2^23, RNE rounding
    int tid = threadIdx.x, lane = tid & 63, w = tid >> 6;
    int qlan = lane & 15, g = lane >> 4;
    int idx = blockIdx.x;
    int qb = 31 - (idx >> 5), h = idx & 31, kvh = h >> 2;   // long blocks first
    float sq = slot_scale(slots, 5), sk = slot_scale(slots, 6);
    float spv = slot_scale(slots, 7) * (1.0f / 127.0f);
    float c2 = sq * sk * 0.08838834764831845f * 1.4426950408889634f;
    int lr8 = lane >> 3;
    int swc = ((lane & 7) ^ lr8) * 16;
    int lr4 = lane >> 2;
    int vswc = ((lane & 3) ^ (lr4 & 3)) * 16;
    const int8_t* kbase = Kq + ((long)(w * 8 + lr8)) * KVDIM + kvh * 128 + swc;
    const int8_t* vbase = Vtq + ((long)kvh * 128 + w * 16 + lr4) * SEQ + vswc;
    auto STAGE_K = [&](int buf, int kt) {
        #pragma unroll
        for (int i = 0; i < 2; i++)
            gload16(kbase + ((long)kt * 64 + i * 32) * KVDIM, &Ks[buf][(w * 8 + i * 32) * 128]);
    };
    auto STAGE_V = [&](int buf, int kt) {
        #pragma unroll
        for (int i = 0; i < 2; i++)
            gload16(vbase + (long)(i * 64) * SEQ + kt * 64, &Vs[buf][(w * 16 + i * 64) * 64]);
    };
    {
        const int8_t* qbase = Qq + ((long)qb * 64 + w * 8 + lr8) * HID + h * 128 + swc;
        #pragma unroll
        for (int i = 0; i < 2; i++)
            gload16(qbase + (long)(i * 32) * HID, &Qs[(w * 8 + i * 32) * 128]);
    }
    STAGE_K(0, 0);
    VMCNT0;
    __syncthreads();
    v4i aq[2];
    #pragma unroll
    for (int ks = 0; ks < 2; ks++) {
        int row = w * 16 + qlan;
        aq[ks] = *(const v4i*)(&Qs[row * 128 + (((ks * 4 + g) ^ (row & 7)) * 16)]);
    }
    int mi = -(1 << 30);
    float l = 0.f;
    int buf = 0;
    // ---- pass 1: int row-max + fused-exp denominator ----
    for (int kt = 0; kt <= qb; kt++) {
        if (kt < qb) STAGE_K(buf ^ 1, kt + 1);
        v4i sf[4] = {vzero, vzero, vzero, vzero};
        __builtin_amdgcn_s_setprio(1);
        #pragma unroll
        for (int ks = 0; ks < 2; ks++)
            #pragma unroll
            for (int f = 0; f < 4; f++) {
                int row = f * 16 + qlan;
                v4i bk = *(const v4i*)(&Ks[buf][row * 128 + (((ks * 4 + g) ^ (row & 7)) * 16)]);
                sf[f] = __builtin_amdgcn_mfma_i32_16x16x64_i8(bk, aq[ks], sf[f], 0, 0, 0);
            }
        __builtin_amdgcn_s_setprio(0);
        int sv[16];
        if (kt == qb) {
            int qthr = w * 16 + qlan;
            #pragma unroll
            for (int f = 0; f < 4; f++)
                #pragma unroll
                for (int r = 0; r < 4; r++) {
                    int kl = f * 16 + g * 4 + r;
                    sv[f * 4 + r] = (kl > qthr) ? NEGS : sf[f][r];
                }
        } else {
            #pragma unroll
            for (int f = 0; f < 4; f++)
                #pragma unroll
                for (int r = 0; r < 4; r++) sv[f * 4 + r] = sf[f][r];
        }
        int tm = sv[0];
        #pragma unroll
        for (int e = 1; e < 16; e++) tm = tm > sv[e] ? tm : sv[e];
        tm = max(tm, __shfl_xor(tm, 16, 64));
        tm = max(tm, __shfl_xor(tm, 32, 64));
        int mn = tm > mi ? tm : mi;
        float nb = -c2 * (float)mn;
        float esc = fexp2(fmaf((float)mi, c2, nb));
        float es = 0.f;
        #pragma unroll
        for (int e = 0; e < 16; e++) es += fexp2(fmaf((float)sv[e], c2, nb));
        es += __shfl_xor(es, 16, 64);
        es += __shfl_xor(es, 32, 64);
        l = l * esc + es;
        mi = mn;
        VMCNT0;
        __syncthreads();
        buf ^= 1;
    }
    // fused quant bias: p_q127 = exp2(c2*s - Bq), Bq = c2*m + log2(l) - log2(127)
    float Bq = fmaf(c2, (float)mi, __log2f(l) - 6.9886846867721655f);
    // ---- pass 2 ----
    unsigned* Ps32 = (unsigned*)Qs;
    int pwr = w * 320;
    v4i of[8];
    #pragma unroll
    for (int nf = 0; nf < 8; nf++) of[nf] = vzero;
    STAGE_K(0, 0);
    STAGE_V(0, 0);
    VMCNT0;
    __syncthreads();
    buf = 0;
    for (int kt = 0; kt <= qb; kt++) {
        if (kt < qb) { STAGE_K(buf ^ 1, kt + 1); STAGE_V(buf ^ 1, kt + 1); }
        v4i sf[4] = {vzero, vzero, vzero, vzero};
        __builtin_amdgcn_s_setprio(1);
        #pragma unroll
        for (int ks = 0; ks < 2; ks++)
            #pragma unroll
            for (int f = 0; f < 4; f++) {
                int row = f * 16 + qlan;
                v4i bk = *(const v4i*)(&Ks[buf][row * 128 + (((ks * 4 + g) ^ (row & 7)) * 16)]);
                sf[f] = __builtin_amdgcn_mfma_i32_16x16x64_i8(bk, aq[ks], sf[f], 0, 0, 0);
            }
        __builtin_amdgcn_s_setprio(0);
        if (kt == qb) {
            int qthr = w * 16 + qlan;
            #pragma unroll
            for (int f = 0; f < 4; f++) {
                unsigned pk = 0;
                #pragma unroll
                for (int r = 0; r < 4; r++) {
                    int kl = f * 16 + g * 4 + r;
                    int s = (kl > qthr) ? NEGS : sf[f][r];
                    float t = fexp2(fmaf((float)s, c2, -Bq));
                    unsigned u = __float_as_uint(t + MAGIC) & 127u;
                    pk |= u << (8 * r);
                }
                Ps32[pwr + (4 * f + g) * 20 + qlan] = pk;
            }
        } else {
            #pragma unroll
            for (int f = 0; f < 4; f++) {
                unsigned pk = 0;
                #pragma unroll
                for (int r = 0; r < 4; r++) {
                    float t = fexp2(fmaf((float)sf[f][r], c2, -Bq));
                    unsigned u = __float_as_uint(t + MAGIC) & 127u;
                    pk |= u << (8 * r);
                }
                Ps32[pwr + (4 * f + g) * 20 + qlan] = pk;
            }
        }
        int rb = pwr + 80 * g + qlan;
        v4i ap;
        ap[0] = (int)Ps32[rb];
        ap[1] = (int)Ps32[rb + 20];
        ap[2] = (int)Ps32[rb + 40];
        ap[3] = (int)Ps32[rb + 60];
        __builtin_amdgcn_s_setprio(1);
        #pragma unroll
        for (int nf = 0; nf < 8; nf++) {
            int row = nf * 16 + qlan;
            v4i bv = *(const v4i*)(&Vs[buf][row * 64 + ((g ^ (row & 3)) * 16)]);
            of[nf] = __builtin_amdgcn_mfma_i32_16x16x64_i8(ap, bv, of[nf], 0, 0, 0);
        }
        __builtin_amdgcn_s_setprio(0);
        VMCNT0;
        __syncthreads();
        buf ^= 1;
    }
    int mymax = 0;
    #pragma unroll
    for (int nf = 0; nf < 8; nf++)
        #pragma unroll
        for (int r = 0; r < 4; r++) {
            int val = of[nf][r];
            int av = val < 0 ? -val : val;
            mymax = av > mymax ? av : mymax;
            int qg = qb * 64 + w * 16 + 4 * g + r;
            AO[(long)qg * HID + h * 128 + nf * 16 + qlan] = __float2half(spv * (float)val);
        }
    #pragma unroll
    for (int off = 1; off < 64; off <<= 1) {
        int o2 = __shfl_xor(mymax, off, 64);
        mymax = o2 > mymax ? o2 : mymax;
    }
    if (lane == 0) smx[w] = mymax;
    __syncthreads();
    if (tid == 0) {
        int mm = max(max(smx[0], smx[1]), max(smx[2], smx[3]));
        atomicMax(slots + (8 << 5), (unsigned)mm);   // staggered retirement
    }
}

// ---------------- quantize attn_out (f16 -> int8), packed ----------------
__global__ void k_quant_ao(const __half* __restrict__ a, int8_t* __restrict__ q,
                           unsigned* slots) {
    float sv = slot_scale(slots, 7);
    float spv = (1.0f / 127.0f) * sv;
    float amax = spv * (float)(int)slots[8 << 5];
    float s = fmaxf(amax / 127.0f, 1e-8f);
    long nu = (long)SEQ * HID / 16;
    long gs = (long)gridDim.x * blockDim.x;
    for (long u = blockIdx.x * (long)blockDim.x + threadIdx.x; u < nu; u += gs) {
        const int4* src = (const int4*)(a + u * 16);
        int4 x = src[0], y = src[1];
        int4 o;
        o.x = (int)pk4h((unsigned)x.x, (unsigned)x.y, s);
        o.y = (int)pk4h((unsigned)x.z, (unsigned)x.w, s);
        o.z = (int)pk4h((unsigned)y.x, (unsigned)y.y, s);
        o.w = (int)pk4h((unsigned)y.z, (unsigned)y.w, s);
        *(int4*)(q + u * 16) = o;
    }
    if (blockIdx.x == 0 && threadIdx.x == 0) slots[9 << 5] = __float_as_uint(amax);
}

extern "C" void kernel_launch(void* const* d_in, const int* in_sizes, int n_in,
                              void* d_out, int out_size, void* d_ws, size_t ws_size,
                              hipStream_t stream) {
    (void)in_sizes; (void)n_in; (void)out_size;
    const float* hid = (const float*)d_in[0];
    const int* pos = (const int*)d_in[2];
    const float* wqp = (const float*)d_in[3];
    const float* wkp = (const float*)d_in[4];
    const float* wvp = (const float*)d_in[5];
    const float* wop = (const float*)d_in[6];
    float* out = (float*)d_out;
    char* ws = (char*)d_ws;

    size_t o = 0;
    auto alloc = [&](size_t sz) { size_t r = o; o += (sz + 255) & ~(size_t)255; return r; };
    unsigned* slots = (unsigned*)(ws + alloc(2048));
    float* P0 = (float*)(ws + alloc(2048 * 4));      // absmax5 partials
    float* P1 = (float*)(ws + alloc(512 * 4));       // gemm1 Q-rope partials
    float* P2 = (float*)(ws + alloc(128 * 4));       // gemm2 K-rope partials
    float* P3 = (float*)(ws + alloc(128 * 4));       // gemm2 V partials
    int8_t* Xq   = (int8_t*)(ws + alloc((size_t)SEQ * HID));      // later reused as AOq
    int8_t* Wqq  = (int8_t*)(ws + alloc((size_t)HID * HID));      // later reused as Woq
    int8_t* Wkvq = (int8_t*)(ws + alloc((size_t)KVCAT * HID));
    __half* Qf   = (__half*)(ws + alloc((size_t)SEQ * HID * 2));  // later reused as AOh
    __half* KVf  = (__half*)(ws + alloc((size_t)SEQ * KVCAT * 2));
    int8_t* Qq   = (int8_t*)(ws + alloc((size_t)SEQ * HID));
    int8_t* Kq   = (int8_t*)(ws + alloc((size_t)SEQ * KVDIM));
    int8_t* Vtq  = (int8_t*)(ws + alloc((size_t)KVDIM * SEQ));
    float*  ctab = (float*)(ws + alloc((size_t)SEQ * 64 * 4));
    float*  stab = (float*)(ws + alloc((size_t)SEQ * 64 * 4));
    if (ws_size < o) return;
    int8_t* Woq = Wqq;
    __half* AOh = Qf;
    int8_t* AOq = Xq;

    hipMemsetAsync(slots, 0, 2048, stream);
    k_ropetab<<<SEQ * 64 / 256, 256, 0, stream>>>(pos, ctab, stab);
    k_absmax5<<<2048, 256, 0, stream>>>(hid, wqp, wkp, wvp, wop, P0);
    k_reduceA<<<1, 256, 0, stream>>>(P0, slots);
    k_quant4<<<2048, 256, 0, stream>>>(hid, wqp, wkp, wvp,
                                       Xq, Wqq, Wkvq, Wkvq + (size_t)KVDIM * HID, slots);
    k_gemm_i8<<<512, 256, 0, stream>>>(Xq, Wqq, Qf, SEQ, HID, HID, slots,
                                       0, 1, 1, 1 << 30, P1, nullptr, nullptr, 1, ctab, stab);
    k_gemm_i8<<<256, 256, 0, stream>>>(Xq, Wkvq, KVf, SEQ, KVCAT, HID, slots,
                                       0, 2, 3, KVDIM, nullptr, P2, P3, 2, ctab, stab);
    k_quantw<<<1024, 256, 0, stream>>>(wop, Woq, (long)HID * HID / 16, slots, 4);
    k_reduceB<<<1, 256, 0, stream>>>(P1, P2, P3, slots);
    const long CALL = 0x3FFFFFFFL;
    k_quanth<<<1024, 256, 0, stream>>>(Qf, Qq, (long)SEQ * HID / 16, 40, CALL, 0, slots, 5);
    k_quanth<<<512, 256, 0, stream>>>(KVf, Kq, (long)SEQ * KVDIM / 16, 6, 63, KVCAT, slots, 6);
    k_transq<<<dim3(32, 64), 256, 0, stream>>>(KVf + KVDIM, KVCAT, Vtq, SEQ, slots, 7);
    k_attn<<<1024, 256, 0, stream>>>(Qq, Kq, Vtq, AOh, slots);
    k_quant_ao<<<1024, 256, 0, stream>>>(AOh, AOq, slots);
    k_gemm_i8<<<512, 256, 0, stream>>>(AOq, Woq, out, SEQ, HID, HID, slots,
                                       9, 4, 4, 1 << 30, nullptr, nullptr, nullptr, 0,
                                       nullptr, nullptr);
}